// Round 4
// baseline (1291.625 us; speedup 1.0000x reference)
//
#include <hip/hip_runtime.h>
#include <hip/hip_bf16.h>
#include <math.h>

// ---------------------------------------------------------------------------
// TransformerModel: 12-layer causal linear-attention encoder.
// B=1, S=1024, D_MODEL=512, H=8, Dh=64, FF=2048. All tensors fp32 (x int32).
// Round 13: split-K GEMM. R12's gemm64 was LDS-pipe bound (1:1 ds_read:MFMA,
// barrier every iter, N=512 grids cap at 128 blocks). gemmsk: each of 4 waves
// computes the FULL 64x64 tile over its own K-quarter with 4x4 frags
// (2:1 MFMA:read), private per-wave LDS slabs (80B row pitch, conflict-free),
// double-buffered reg-staging, NO main-loop barriers; one barrier + LDS tree
// reduce of the 4 partials at the end. ffn2/wo additionally split K across
// grid.z=2 (256 blocks); partial sum folded into ln_kernel (X + X2 + resid).
// Y/Y2 partials are CONTIGUOUS so gemmsk addresses Cf + z*1024*N.
// Attention / LN math / embed / transpose unchanged.
// ---------------------------------------------------------------------------

#define S_LEN 1024
#define DM 512
#define NH 8
#define DH 64
#define DFF 2048
#define NLAYER 12
#define CHUNK 64
#define NCH (S_LEN / CHUNK)   // 16

#define ACT_NONE 0
#define ACT_PHI  1
#define ACT_GELU 2

typedef short s16x8 __attribute__((ext_vector_type(8)));
typedef float f32x4 __attribute__((ext_vector_type(4)));

__device__ __forceinline__ short f2bf(float x) {
    __hip_bfloat16 h = __float2bfloat16(x);
    return *reinterpret_cast<short*>(&h);
}

__device__ __forceinline__ void fma4(f32x4& a, float s, const f32x4 v) {
    a.x = fmaf(s, v.x, a.x); a.y = fmaf(s, v.y, a.y);
    a.z = fmaf(s, v.z, a.z); a.w = fmaf(s, v.w, a.w);
}

// ---------------- embedding gather (writes bf16) ----------------
__global__ __launch_bounds__(256) void embed_kernel(
    const int* __restrict__ x,
    const float* __restrict__ t0, const float* __restrict__ t1,
    const float* __restrict__ t2, const float* __restrict__ t3,
    const float* __restrict__ t4, const float* __restrict__ t5,
    short* __restrict__ EMBb)
{
    int s = blockIdx.x;
    __shared__ int xi[6];
    if (threadIdx.x < 6) xi[threadIdx.x] = x[s * 6 + threadIdx.x];
    __syncthreads();
    for (int j = threadIdx.x; j < 768; j += 256) {
        int i, off, width; const float* t; float sc;
        if (j < 32)       { i = 0; off = 0;   t = t0; sc = 5.656854249f;  width = 32;  }
        else if (j < 160) { i = 1; off = 32;  t = t1; sc = 11.3137085f;   width = 128; }
        else if (j < 416) { i = 2; off = 160; t = t2; sc = 16.0f;         width = 256; }
        else if (j < 672) { i = 3; off = 416; t = t3; sc = 16.0f;         width = 256; }
        else if (j < 704) { i = 4; off = 672; t = t4; sc = 5.656854249f;  width = 32;  }
        else              { i = 5; off = 704; t = t5; sc = 8.0f;          width = 64;  }
        EMBb[s * 768 + j] = f2bf(t[xi[i] * width + (j - off)] * sc);
    }
}

// ---------------- weight transpose+convert: f32 [B][K][N] -> bf16 [B][N][K] ----
__global__ __launch_bounds__(256) void transpose_w(
    const float* __restrict__ in, short* __restrict__ out, int K, int N)
{
    __shared__ short t[64][66];
    const int b = blockIdx.z;
    const int n0 = blockIdx.x * 64, k0 = blockIdx.y * 64;
    const float* ip = in + (size_t)b * K * N;
    short* op = out + (size_t)b * K * N;
    const int c = threadIdx.x & 63, r0 = (threadIdx.x >> 6) * 16;
    #pragma unroll
    for (int i = 0; i < 16; ++i)
        t[c][r0 + i] = f2bf(ip[(size_t)(k0 + r0 + i) * N + n0 + c]);
    __syncthreads();
    #pragma unroll
    for (int i = 0; i < 16; ++i)
        op[(size_t)(n0 + r0 + i) * K + k0 + c] = t[r0 + i][c];
}

// ---------------- activation ----------------
__device__ __forceinline__ float apply_act(float v, int act) {
    if (act == ACT_PHI)       return (v > 0.0f) ? (v + 1.0f) : expf(v);
    else if (act == ACT_GELU) return 0.5f * v * (1.0f + erff(v * 0.70710678118654752f));
    return v;
}

// ---------------- split-K GEMM core -----------------------------------------
// Block: 256 thr = 4 waves; tile 64x64; wave w covers K-slice [kw, kw+Kq).
// Per-wave LDS: [2 buf][A,B][64 rows x 40 shorts] (80B pitch, 64B data+16 pad).
// Per K-32 step/wave: 8 global b128 -> regs, 8 ds_write_b128, 8 ds_read_b128
// (4 A-frags + 4 B-frags), 16 MFMA 16x16x32. No barriers in the main loop.
// End: scratch = per-wave 64x64 f32 (col-major, pitch 65) inside own region;
// one barrier; 256 threads sum 4 partials + epilogue.

#define LDSW 2560   // shorts per slab (64 * 40)

__device__ __forceinline__ void sk_gld(const char* gbase, int ldkB, int kbyte,
                                       int lane, s16x8 r[4])
{
    const int rr = lane >> 2, colb = (lane & 3) * 16;
    #pragma unroll
    for (int i = 0; i < 4; ++i)
        r[i] = *(const s16x8*)(gbase + (size_t)(i * 16 + rr) * ldkB + kbyte + colb);
}

__device__ __forceinline__ void sk_dswr(short* buf, int lane, const s16x8 r[4])
{
    const int rr = lane >> 2, colb = (lane & 3) * 16;
    #pragma unroll
    for (int i = 0; i < 4; ++i)
        *(s16x8*)((char*)buf + (i * 16 + rr) * 80 + colb) = r[i];
}

__device__ __forceinline__ void sk_compute(
    const short* bufA, const short* bufB, int l15, int q, f32x4 acc[4][4])
{
    s16x8 a[4], b[4];
    #pragma unroll
    for (int m = 0; m < 4; ++m)
        a[m] = *(const s16x8*)((const char*)bufA + (m * 16 + l15) * 80 + q * 16);
    #pragma unroll
    for (int n = 0; n < 4; ++n)
        b[n] = *(const s16x8*)((const char*)bufB + (n * 16 + l15) * 80 + q * 16);
    #pragma unroll
    for (int m = 0; m < 4; ++m)
        #pragma unroll
        for (int n = 0; n < 4; ++n)
            acc[m][n] = __builtin_amdgcn_mfma_f32_16x16x32_bf16(
                a[m], b[n], acc[m][n], 0, 0, 0);
}

__device__ __forceinline__ void sk_main(
    const short* A, const short* BT, int K, int Kq, int kbase,
    int row0, int col0, short* ldsbase, int tid)
{
    const int w = tid >> 6, lane = tid & 63;
    const int l15 = lane & 15, q = lane >> 4;
    const int kw = kbase + w * Kq;
    const int nt = Kq >> 5;

    const char* gA = (const char*)A + (size_t)row0 * K * 2;
    const char* gB = (const char*)BT + (size_t)col0 * K * 2;
    short* bufA[2] = { ldsbase, ldsbase + 2 * LDSW };
    short* bufB[2] = { ldsbase + LDSW, ldsbase + 3 * LDSW };

    f32x4 acc[4][4] = {};
    s16x8 ra[4], rb[4];

    sk_gld(gA, K * 2, kw * 2, lane, ra);
    sk_gld(gB, K * 2, kw * 2, lane, rb);
    sk_dswr(bufA[0], lane, ra);
    sk_dswr(bufB[0], lane, rb);
    if (nt > 1) {
        sk_gld(gA, K * 2, (kw + 32) * 2, lane, ra);
        sk_gld(gB, K * 2, (kw + 32) * 2, lane, rb);
    }
    for (int t = 0; t < nt; ++t) {
        const int cur = t & 1;
        if (t + 1 < nt) {
            sk_dswr(bufA[cur ^ 1], lane, ra);
            sk_dswr(bufB[cur ^ 1], lane, rb);
        }
        if (t + 2 < nt) {
            sk_gld(gA, K * 2, (kw + (t + 2) * 32) * 2, lane, ra);
            sk_gld(gB, K * 2, (kw + (t + 2) * 32) * 2, lane, rb);
        }
        sk_compute(bufA[cur], bufB[cur], l15, q, acc);
    }

    // write partial acc to this wave's scratch (col-major, pitch 65)
    float* scr = (float*)ldsbase;
    #pragma unroll
    for (int m = 0; m < 4; ++m)
        #pragma unroll
        for (int n = 0; n < 4; ++n) {
            int col = n * 16 + l15, rowb = m * 16 + q * 4;
            *(f32x4*)(scr + col * 65 + rowb) = acc[m][n];
        }
}

// ---------------- generic split-K GEMM ----------------
// grid (N/64, 16, zparts). zparts>1: partial z -> Cf + z*1024*N, bias in z==0.
__global__ __launch_bounds__(256) void gemmsk(
    const short* __restrict__ A, const short* __restrict__ BT,
    const float* __restrict__ bias, const float* __restrict__ resid,
    float* __restrict__ Cf, short* __restrict__ Cbf,
    int N, int K, int act, int add_pe, int zparts)
{
    __shared__ short lds[4][4 * LDSW];   // 80 KB
    const int tid = threadIdx.x;
    const int row0 = blockIdx.y * 64, col0 = blockIdx.x * 64;
    const int z = blockIdx.z;
    const int Kq = K / (4 * zparts);
    const int kbase = z * (K / zparts);

    sk_main(A, BT, K, Kq, kbase, row0, col0, lds[tid >> 6], tid);
    __syncthreads();

    if (zparts > 1 && Cf) Cf += (size_t)z * S_LEN * N;

    const int r = tid >> 2, c0 = (tid & 3) * 16;
    float sum[16];
    #pragma unroll
    for (int j = 0; j < 16; ++j) {
        float s = 0.0f;
        #pragma unroll
        for (int wi = 0; wi < 4; ++wi)
            s += ((const float*)lds[wi])[(c0 + j) * 65 + r];
        sum[j] = s;
    }
    const int gr = row0 + r;
    #pragma unroll
    for (int j = 0; j < 16; ++j) {
        int c = col0 + c0 + j;
        float v = sum[j];
        if (z == 0) v += bias[c];
        v = apply_act(v, act);
        if (resid) v += resid[(size_t)gr * N + c];
        if (add_pe) {
            float freq = expf((float)(c & ~1) * (-9.210340371976184f / 512.0f));
            float ang = (float)gr * freq;
            v += (c & 1) ? cosf(ang) : sinf(ang);
        }
        sum[j] = v;
    }
    if (Cf) {
        float* op = Cf + (size_t)gr * N + col0 + c0;
        #pragma unroll
        for (int j4 = 0; j4 < 4; ++j4)
            *(f32x4*)(op + j4 * 4) = *(f32x4*)(&sum[j4 * 4]);
    }
    if (Cbf) {
        short* op = Cbf + (size_t)gr * N + col0 + c0;
        #pragma unroll
        for (int j4 = 0; j4 < 4; ++j4) {
            short4 o;
            o.x = f2bf(sum[j4 * 4 + 0]); o.y = f2bf(sum[j4 * 4 + 1]);
            o.z = f2bf(sum[j4 * 4 + 2]); o.w = f2bf(sum[j4 * 4 + 3]);
            *reinterpret_cast<short4*>(op + j4 * 4) = o;
        }
    }
}

// ---------------- fused QKV via split-K core: grid (24, 16); phi on Q,K -----
__global__ __launch_bounds__(256) void qkvsk(
    const short* __restrict__ Hb,
    const short* __restrict__ qT, const short* __restrict__ kT, const short* __restrict__ vT,
    const float* __restrict__ bq, const float* __restrict__ bk, const float* __restrict__ bv,
    float* __restrict__ Qb, float* __restrict__ Kb, float* __restrict__ Vb)
{
    __shared__ short lds[4][4 * LDSW];
    const int tid = threadIdx.x;
    const int sel  = blockIdx.x >> 3;              // 0=Q 1=K 2=V
    const int col0 = (blockIdx.x & 7) * 64;
    const int row0 = blockIdx.y * 64;
    const short* BT   = (sel == 0) ? qT : (sel == 1) ? kT : vT;
    const float* bias = (sel == 0) ? bq : (sel == 1) ? bk : bv;
    float* C          = (sel == 0) ? Qb : (sel == 1) ? Kb : Vb;
    const bool phi = (sel < 2);

    sk_main(Hb, BT, DM, DM / 4, 0, row0, col0, lds[tid >> 6], tid);
    __syncthreads();

    const int r = tid >> 2, c0 = (tid & 3) * 16;
    const int gr = row0 + r;
    float* op = C + (size_t)gr * DM + col0 + c0;
    #pragma unroll
    for (int j4 = 0; j4 < 4; ++j4) {
        f32x4 o;
        #pragma unroll
        for (int i = 0; i < 4; ++i) {
            int j = j4 * 4 + i;
            float s = 0.0f;
            #pragma unroll
            for (int wi = 0; wi < 4; ++wi)
                s += ((const float*)lds[wi])[(c0 + j) * 65 + r];
            s += bias[col0 + c0 + j];
            if (phi) s = (s > 0.0f) ? (s + 1.0f) : expf(s);
            o[i] = s;
        }
        *(f32x4*)(op + j4 * 4) = o;
    }
}

// ---------------- chunk stats: per (head, chunk) KV_c = K_c^T V_c, ksum_c ----
__global__ __launch_bounds__(256) void chunk_stats_kernel(
    const float* __restrict__ Kb, const float* __restrict__ Vb,
    float* __restrict__ KVC, float* __restrict__ KSC)
{
    const int h = blockIdx.x >> 4, c = blockIdx.x & 15;
    const int tid = threadIdx.x;
    __shared__ float Ks[64][68];
    __shared__ float Vs[64][68];
    #pragma unroll
    for (int it = 0; it < 4; ++it) {
        int j = tid + it * 256;                 // 0..1023 f32x4 slots
        int r = j >> 4, d0 = (j & 15) * 4;
        size_t g = (size_t)(c * CHUNK + r) * DM + h * 64 + d0;
        *(f32x4*)(&Ks[r][d0]) = *(const f32x4*)(Kb + g);
        *(f32x4*)(&Vs[r][d0]) = *(const f32x4*)(Vb + g);
    }
    __syncthreads();
    const int di = (tid >> 4) * 4, ei = (tid & 15) * 4;
    f32x4 a0 = {}, a1 = {}, a2 = {}, a3 = {}, ks = {};
    #pragma unroll 8
    for (int t = 0; t < 64; ++t) {
        f32x4 kk = *(const f32x4*)(&Ks[t][di]);
        f32x4 vv = *(const f32x4*)(&Vs[t][ei]);
        fma4(a0, kk.x, vv); fma4(a1, kk.y, vv);
        fma4(a2, kk.z, vv); fma4(a3, kk.w, vv);
        ks += kk;
    }
    float* out = KVC + (size_t)(c * NH + h) * 4096;   // [d][e] row-major
    *(f32x4*)(out + (size_t)(di + 0) * 64 + ei) = a0;
    *(f32x4*)(out + (size_t)(di + 1) * 64 + ei) = a1;
    *(f32x4*)(out + (size_t)(di + 2) * 64 + ei) = a2;
    *(f32x4*)(out + (size_t)(di + 3) * 64 + ei) = a3;
    if ((tid & 15) == 0)
        *(f32x4*)(KSC + (size_t)(c * NH + h) * 64 + di) = ks;
}

// ---------------- in-place exclusive prefix scan over chunks ----------------
__global__ __launch_bounds__(256) void scan_kv_kernel(
    float* __restrict__ KVC, float* __restrict__ KSC)
{
    int gid = blockIdx.x * 256 + threadIdx.x;   // 8192 threads
    int h = gid >> 10, e4 = gid & 1023;
    f32x4* p = (f32x4*)KVC;
    f32x4 run = {};
    #pragma unroll
    for (int c = 0; c < NCH; ++c) {
        size_t idx = (size_t)(c * NH + h) * 1024 + e4;
        f32x4 v = p[idx];
        p[idx] = run;
        run += v;
    }
    if (gid < NH * 64) {
        int h2 = gid >> 6, e = gid & 63;
        float r = 0.0f;
        for (int c = 0; c < NCH; ++c) {
            size_t idx = (size_t)(c * NH + h2) * 64 + e;
            float v = KSC[idx];
            KSC[idx] = r;
            r += v;
        }
    }
}

// ---------------- attention output per (head, chunk) ----------------
__global__ __launch_bounds__(256) void attn_out_kernel(
    const float* __restrict__ Qb, const float* __restrict__ Kb,
    const float* __restrict__ Vb, const float* __restrict__ KVC,
    const float* __restrict__ KSC, short* __restrict__ Ab)
{
    const int h = blockIdx.x >> 4, c = blockIdx.x & 15;
    const int tid = threadIdx.x;
    __shared__ float Qt[64][68];   // Qt[d][s]  (transposed)
    __shared__ float Kt[64][68];   // Kt[d][t]  (transposed)
    __shared__ float Vs[64][68];   // Vs[t][e]
    __shared__ float Ms[64][68];   // state: Ms[d][e]
    __shared__ float St[64][68];   // St[t][s]  (S transposed)
    __shared__ float KSs[64];

    const float* ms_src = KVC + (size_t)(c * NH + h) * 4096;
    #pragma unroll
    for (int it = 0; it < 4; ++it) {
        int j = tid + it * 256;                 // 0..1023
        int r = j >> 4, d0 = (j & 15) * 4;
        size_t g = (size_t)(c * CHUNK + r) * DM + h * 64 + d0;
        f32x4 q = *(const f32x4*)(Qb + g);
        f32x4 k = *(const f32x4*)(Kb + g);
        f32x4 v = *(const f32x4*)(Vb + g);
        Qt[d0 + 0][r] = q.x; Qt[d0 + 1][r] = q.y; Qt[d0 + 2][r] = q.z; Qt[d0 + 3][r] = q.w;
        Kt[d0 + 0][r] = k.x; Kt[d0 + 1][r] = k.y; Kt[d0 + 2][r] = k.z; Kt[d0 + 3][r] = k.w;
        *(f32x4*)(&Vs[r][d0]) = v;
        *(f32x4*)(&Ms[r][d0]) = *(const f32x4*)(ms_src + (size_t)j * 4);
    }
    if (tid < 64) KSs[tid] = KSC[(size_t)(c * NH + h) * 64 + tid];
    __syncthreads();

    const int si = tid >> 4, ti = tid & 15;
    const int s0 = si * 4, t0 = ti * 4;         // t0 doubles as e0

    // ---- Phase A: inter-chunk O = Q @ State, den = Q . KSprefix ----
    f32x4 accO0 = {}, accO1 = {}, accO2 = {}, accO3 = {};
    f32x4 den = {};
    #pragma unroll 8
    for (int d = 0; d < 64; ++d) {
        f32x4 qv = *(const f32x4*)(&Qt[d][s0]);
        f32x4 mv = *(const f32x4*)(&Ms[d][t0]);
        float ks = KSs[d];
        fma4(accO0, qv.x, mv); fma4(accO1, qv.y, mv);
        fma4(accO2, qv.z, mv); fma4(accO3, qv.w, mv);
        fma4(den, ks, qv);
    }

    // ---- Phase B: S = Q K^T, causal, staged transposed ----
    f32x4 p0 = {}, p1 = {}, p2 = {}, p3 = {};   // p_r = S[s0+r][t0:t0+4]
    if (ti <= si) {
        #pragma unroll 8
        for (int d = 0; d < 64; ++d) {
            f32x4 qv = *(const f32x4*)(&Qt[d][s0]);
            f32x4 kv = *(const f32x4*)(&Kt[d][t0]);
            fma4(p0, qv.x, kv); fma4(p1, qv.y, kv);
            fma4(p2, qv.z, kv); fma4(p3, qv.w, kv);
        }
        if (ti == si) {                          // diagonal tile: keep t<=r
            p0.y = 0.0f; p0.z = 0.0f; p0.w = 0.0f;
            p1.z = 0.0f; p1.w = 0.0f;
            p2.w = 0.0f;
        }
    }
    St[t0 + 0][s0 + 0] = p0.x; St[t0 + 1][s0 + 0] = p0.y;
    St[t0 + 2][s0 + 0] = p0.z; St[t0 + 3][s0 + 0] = p0.w;
    St[t0 + 0][s0 + 1] = p1.x; St[t0 + 1][s0 + 1] = p1.y;
    St[t0 + 2][s0 + 1] = p1.z; St[t0 + 3][s0 + 1] = p1.w;
    St[t0 + 0][s0 + 2] = p2.x; St[t0 + 1][s0 + 2] = p2.y;
    St[t0 + 2][s0 + 2] = p2.z; St[t0 + 3][s0 + 2] = p2.w;
    St[t0 + 0][s0 + 3] = p3.x; St[t0 + 1][s0 + 3] = p3.y;
    St[t0 + 2][s0 + 3] = p3.z; St[t0 + 3][s0 + 3] = p3.w;
    __syncthreads();

    // ---- Phase C: O += S @ V ; den += rowsum(S) ----
    const int tmax = s0 + 4;                     // exclusive; St zero above diag
    #pragma unroll 4
    for (int t2 = 0; t2 < tmax; ++t2) {
        f32x4 sv = *(const f32x4*)(&St[t2][s0]);
        f32x4 vv = *(const f32x4*)(&Vs[t2][t0]);
        fma4(accO0, sv.x, vv); fma4(accO1, sv.y, vv);
        fma4(accO2, sv.z, vv); fma4(accO3, sv.w, vv);
        den += sv;
    }

    // ---- epilogue: z = 1/(den+eps), bf16 out ----
    short* op = Ab + (size_t)(c * CHUNK + s0) * DM + h * 64 + t0;
    {
        float z = 1.0f / (den.x + 1e-6f);
        short4 o; o.x = f2bf(accO0.x * z); o.y = f2bf(accO0.y * z);
        o.z = f2bf(accO0.z * z); o.w = f2bf(accO0.w * z);
        *reinterpret_cast<short4*>(op) = o;
    }
    {
        float z = 1.0f / (den.y + 1e-6f);
        short4 o; o.x = f2bf(accO1.x * z); o.y = f2bf(accO1.y * z);
        o.z = f2bf(accO1.z * z); o.w = f2bf(accO1.w * z);
        *reinterpret_cast<short4*>(op + DM) = o;
    }
    {
        float z = 1.0f / (den.z + 1e-6f);
        short4 o; o.x = f2bf(accO2.x * z); o.y = f2bf(accO2.y * z);
        o.z = f2bf(accO2.z * z); o.w = f2bf(accO2.w * z);
        *reinterpret_cast<short4*>(op + 2 * DM) = o;
    }
    {
        float z = 1.0f / (den.w + 1e-6f);
        short4 o; o.x = f2bf(accO3.x * z); o.y = f2bf(accO3.y * z);
        o.z = f2bf(accO3.z * z); o.w = f2bf(accO3.w * z);
        *reinterpret_cast<short4*>(op + 3 * DM) = o;
    }
}

// ---------------- layernorm: LN(X + X2? + resid?) -> O (+bf16 mirror) -------
__device__ __forceinline__ float block_reduce_sum(float v, float* smem)
{
    #pragma unroll
    for (int o = 32; o > 0; o >>= 1) v += __shfl_down(v, o, 64);
    int w = threadIdx.x >> 6;
    if ((threadIdx.x & 63) == 0) smem[w] = v;
    __syncthreads();
    v = smem[0] + smem[1] + smem[2] + smem[3];
    __syncthreads();
    return v;
}

__global__ __launch_bounds__(256) void ln_kernel(
    const float* __restrict__ X, const float* __restrict__ X2,
    const float* __restrict__ resid,
    const float* __restrict__ g, const float* __restrict__ b,
    float* __restrict__ O, short* __restrict__ Ob)
{
    __shared__ float red[4];
    const int row = blockIdx.x;
    const size_t base = (size_t)row * DM;
    const int t = threadIdx.x;
    float v0 = X[base + t], v1 = X[base + t + 256];
    if (X2)    { v0 += X2[base + t];    v1 += X2[base + t + 256]; }
    if (resid) { v0 += resid[base + t]; v1 += resid[base + t + 256]; }
    float mean = block_reduce_sum(v0 + v1, red) * (1.0f / 512.0f);
    float d0 = v0 - mean, d1 = v1 - mean;
    float var = block_reduce_sum(d0 * d0 + d1 * d1, red) * (1.0f / 512.0f);
    float rs = 1.0f / sqrtf(var + 1e-5f);
    float o0 = d0 * rs * g[t] + b[t];
    float o1 = d1 * rs * g[t + 256] + b[t + 256];
    O[base + t]       = o0;
    O[base + t + 256] = o1;
    if (Ob) {
        Ob[base + t]       = f2bf(o0);
        Ob[base + t + 256] = f2bf(o1);
    }
}

// ---------------- emotion head: [1024,512] @ [512,8] + b ----------------
__global__ __launch_bounds__(256) void proj_emo_kernel(
    const float* __restrict__ HF, const float* __restrict__ pw,
    const float* __restrict__ pb, float* __restrict__ out)
{
    int idx = blockIdx.x * 256 + threadIdx.x;
    int r = idx >> 3, e = idx & 7;
    float acc = pb[e];
    const float* h = HF + (size_t)r * DM;
    for (int d = 0; d < DM; ++d) acc += h[d] * pw[d * 8 + e];
    out[idx] = acc;
}

// ---------------------------------------------------------------------------
extern "C" void kernel_launch(void* const* d_in, const int* in_sizes, int n_in,
                              void* d_out, int out_size, void* d_ws, size_t ws_size,
                              hipStream_t stream)
{
    const int*   x    = (const int*)d_in[0];
    const float* e0   = (const float*)d_in[1];
    const float* e1   = (const float*)d_in[2];
    const float* e2   = (const float*)d_in[3];
    const float* e3   = (const float*)d_in[4];
    const float* e4   = (const float*)d_in[5];
    const float* e5   = (const float*)d_in[6];
    const float* in_w = (const float*)d_in[7];
    const float* in_b = (const float*)d_in[8];
    const float* wq   = (const float*)d_in[9];
    const float* bq   = (const float*)d_in[10];
    const float* wk   = (const float*)d_in[11];
    const float* bk   = (const float*)d_in[12];
    const float* wv   = (const float*)d_in[13];
    const float* bv   = (const float*)d_in[14];
    const float* wo   = (const float*)d_in[15];
    const float* bo   = (const float*)d_in[16];
    const float* g1   = (const float*)d_in[17];
    const float* be1  = (const float*)d_in[18];
    const float* w1   = (const float*)d_in[19];
    const float* b1   = (const float*)d_in[20];
    const float* w2   = (const float*)d_in[21];
    const float* b2   = (const float*)d_in[22];
    const float* g2   = (const float*)d_in[23];
    const float* be2  = (const float*)d_in[24];
    const float* gf   = (const float*)d_in[25];
    const float* bfin = (const float*)d_in[26];
    const float* pw   = (const float*)d_in[27];
    const float* pb   = (const float*)d_in[28];
    float* outp = (float*)d_out;

    // ---- workspace layout: Y,Y2 contiguous partial arena ----
    float* ws = (float*)d_ws;
    float* H    = ws;                  // 1024x512 f32
    float* Y    = ws + 524288;         // partial 0 (and pre-LN sum input)
    float* Y2   = ws + 1048576;        // partial 1 (contiguous with Y)
    float* Qb   = ws + 1572864;
    float* Kb   = ws + 2097152;
    float* Vb   = ws + 2621440;
    float* KVC  = ws + 3145728;        // 16*8*4096 = 524288
    float* KSC  = ws + 3670016;        // 8192 (ends 3678208)
    short* sb   = (short*)(ws + 3678208);
    short* Hb   = sb;                  // 1024x512
    short* Ab   = sb + 524288;         // 1024x512
    short* FFb  = sb + 1048576;        // 1024x2048
    short* EMBb = FFb;                 // 1024x768 (alias: dead before ffn1)
    // bf16 W^T arena [N][K]
    short* inT  = sb + 3145728;        // [512][768]
    short* qT   = inT + 393216;        // [12][512][512]
    short* kT   = qT + 3145728;
    short* vT   = kT + 3145728;
    short* oT   = vT + 3145728;
    short* w1T  = oT + 3145728;        // [12][2048][512]
    short* w2T  = w1T + 12582912;      // [12][512][2048]

    const dim3 blk256(256);

    // ---- weight transpose+convert ----
    transpose_w<<<dim3(8, 12, 1),  blk256, 0, stream>>>(in_w, inT, 768, DM);
    transpose_w<<<dim3(8, 8, 12),  blk256, 0, stream>>>(wq, qT, DM, DM);
    transpose_w<<<dim3(8, 8, 12),  blk256, 0, stream>>>(wk, kT, DM, DM);
    transpose_w<<<dim3(8, 8, 12),  blk256, 0, stream>>>(wv, vT, DM, DM);
    transpose_w<<<dim3(8, 8, 12),  blk256, 0, stream>>>(wo, oT, DM, DM);
    transpose_w<<<dim3(32, 8, 12), blk256, 0, stream>>>(w1, w1T, DM, DFF);
    transpose_w<<<dim3(8, 32, 12), blk256, 0, stream>>>(w2, w2T, DFF, DM);

    embed_kernel<<<S_LEN, blk256, 0, stream>>>(x, e0, e1, e2, e3, e4, e5, EMBb);
    // in-proj: EMBb @ in_w + in_b + PE -> H (f32) and Hb (bf16); K=768, z=1
    gemmsk<<<dim3(8, 16, 1), blk256, 0, stream>>>(EMBb, inT, in_b, nullptr,
                                                  H, Hb, DM, 768, ACT_NONE, 1, 1);

    for (int l = 0; l < NLAYER; ++l) {
        const short* qT_l = qT + (size_t)l * DM * DM;
        const short* kT_l = kT + (size_t)l * DM * DM;
        const short* vT_l = vT + (size_t)l * DM * DM;
        const short* oT_l = oT + (size_t)l * DM * DM;
        const short* w1T_l = w1T + (size_t)l * DM * DFF;
        const short* w2T_l = w2T + (size_t)l * DM * DFF;
        const float* bq_l = bq + l * DM;  const float* bk_l = bk + l * DM;
        const float* bv_l = bv + l * DM;  const float* bo_l = bo + l * DM;
        const float* b1_l = b1 + l * DFF; const float* b2_l = b2 + l * DM;

        qkvsk<<<dim3(24, 16), blk256, 0, stream>>>(Hb, qT_l, kT_l, vT_l,
                                                   bq_l, bk_l, bv_l, Qb, Kb, Vb);

        chunk_stats_kernel<<<NCH * NH, blk256, 0, stream>>>(Kb, Vb, KVC, KSC);
        scan_kv_kernel<<<32, blk256, 0, stream>>>(KVC, KSC);
        attn_out_kernel<<<NCH * NH, blk256, 0, stream>>>(Qb, Kb, Vb, KVC, KSC, Ab);

        // wo: Ab @ wo + bo -> partials Y (z0, +bias), Y2 (z1); LN(Y+Y2+H)
        gemmsk<<<dim3(8, 16, 2), blk256, 0, stream>>>(Ab, oT_l, bo_l, nullptr,
                                                      Y, nullptr, DM, DM, ACT_NONE, 0, 2);
        ln_kernel<<<S_LEN, blk256, 0, stream>>>(Y, Y2, H, g1 + l * DM, be1 + l * DM, H, Hb);

        // ffn1: Hb @ w1 + b1, GELU -> FFb (bf16); z=1
        gemmsk<<<dim3(32, 16, 1), blk256, 0, stream>>>(Hb, w1T_l, b1_l, nullptr,
                                                       nullptr, FFb, DFF, DM, ACT_GELU, 0, 1);
        // ffn2: FFb @ w2 + b2 -> partials Y, Y2; LN(Y+Y2+H)
        gemmsk<<<dim3(8, 16, 2), blk256, 0, stream>>>(FFb, w2T_l, b2_l, nullptr,
                                                      Y, nullptr, DM, DFF, ACT_NONE, 0, 2);
        ln_kernel<<<S_LEN, blk256, 0, stream>>>(Y, Y2, H, g2 + l * DM, be2 + l * DM, H, Hb);
    }

    // final norm -> d_out (f32 h), then emotion head
    ln_kernel<<<S_LEN, blk256, 0, stream>>>(H, nullptr, nullptr, gf, bfin, outp, nullptr);
    proj_emo_kernel<<<8192 / 256, blk256, 0, stream>>>(outp, pw, pb, outp + 524288);
}

// Round 5
// 1111.578 us; speedup vs baseline: 1.1620x; 1.1620x over previous
//
#include <hip/hip_runtime.h>
#include <hip/hip_bf16.h>
#include <math.h>

// ---------------------------------------------------------------------------
// TransformerModel: 12-layer causal linear-attention encoder.
// B=1, S=1024, D_MODEL=512, H=8, Dh=64, FF=2048. All tensors fp32 (x int32).
// Round 14: R12 core restored (R13 split-K regressed: 80KB LDS -> 2 blk/CU).
// Additive deltas: (1) scan_kv folded into attn_out (inline prefix over KVC,
// -12 dispatches); (2) ffn2 split-K z=2 on the R12 gemm64 core, partials
// summed in ln_kernel(X+X2+resid); (3) proj_emo stages pw in LDS + f32x4.
// ---------------------------------------------------------------------------

#define S_LEN 1024
#define DM 512
#define NH 8
#define DH 64
#define DFF 2048
#define NLAYER 12
#define CHUNK 64
#define NCH (S_LEN / CHUNK)   // 16

#define ACT_NONE 0
#define ACT_PHI  1
#define ACT_GELU 2

typedef short s16x8 __attribute__((ext_vector_type(8)));
typedef float f32x4 __attribute__((ext_vector_type(4)));

__device__ __forceinline__ short f2bf(float x) {
    __hip_bfloat16 h = __float2bfloat16(x);
    return *reinterpret_cast<short*>(&h);
}

__device__ __forceinline__ void fma4(f32x4& a, float s, const f32x4 v) {
    a.x = fmaf(s, v.x, a.x); a.y = fmaf(s, v.y, a.y);
    a.z = fmaf(s, v.z, a.z); a.w = fmaf(s, v.w, a.w);
}

// ---------------- embedding gather (writes bf16) ----------------
__global__ __launch_bounds__(256) void embed_kernel(
    const int* __restrict__ x,
    const float* __restrict__ t0, const float* __restrict__ t1,
    const float* __restrict__ t2, const float* __restrict__ t3,
    const float* __restrict__ t4, const float* __restrict__ t5,
    short* __restrict__ EMBb)
{
    int s = blockIdx.x;
    __shared__ int xi[6];
    if (threadIdx.x < 6) xi[threadIdx.x] = x[s * 6 + threadIdx.x];
    __syncthreads();
    for (int j = threadIdx.x; j < 768; j += 256) {
        int i, off, width; const float* t; float sc;
        if (j < 32)       { i = 0; off = 0;   t = t0; sc = 5.656854249f;  width = 32;  }
        else if (j < 160) { i = 1; off = 32;  t = t1; sc = 11.3137085f;   width = 128; }
        else if (j < 416) { i = 2; off = 160; t = t2; sc = 16.0f;         width = 256; }
        else if (j < 672) { i = 3; off = 416; t = t3; sc = 16.0f;         width = 256; }
        else if (j < 704) { i = 4; off = 672; t = t4; sc = 5.656854249f;  width = 32;  }
        else              { i = 5; off = 704; t = t5; sc = 8.0f;          width = 64;  }
        EMBb[s * 768 + j] = f2bf(t[xi[i] * width + (j - off)] * sc);
    }
}

// ---------------- weight transpose+convert: f32 [B][K][N] -> bf16 [B][N][K] ----
__global__ __launch_bounds__(256) void transpose_w(
    const float* __restrict__ in, short* __restrict__ out, int K, int N)
{
    __shared__ short t[64][66];
    const int b = blockIdx.z;
    const int n0 = blockIdx.x * 64, k0 = blockIdx.y * 64;
    const float* ip = in + (size_t)b * K * N;
    short* op = out + (size_t)b * K * N;
    const int c = threadIdx.x & 63, r0 = (threadIdx.x >> 6) * 16;
    #pragma unroll
    for (int i = 0; i < 16; ++i)
        t[c][r0 + i] = f2bf(ip[(size_t)(k0 + r0 + i) * N + n0 + c]);
    __syncthreads();
    #pragma unroll
    for (int i = 0; i < 16; ++i)
        op[(size_t)(n0 + r0 + i) * K + k0 + c] = t[r0 + i][c];
}

// ---------------- activation ----------------
__device__ __forceinline__ float apply_act(float v, int act) {
    if (act == ACT_PHI)       return (v > 0.0f) ? (v + 1.0f) : expf(v);
    else if (act == ACT_GELU) return 0.5f * v * (1.0f + erff(v * 0.70710678118654752f));
    return v;
}

// ---------------- 64x64-tile MFMA GEMM core (R12, proven) ------------------
// LDS tile: [64 rows][64 k] bf16 = 8KB, double-buffered for A and B (32KB).
// Bank swizzle: byte col ^= (row&7)<<4 on BOTH ds_write and ds_read.

__device__ __forceinline__ void ldswr64(short* lds, int srow, int scolb,
                                        const s16x8 r[2])
{
    const int bc = scolb ^ ((srow & 7) << 4);
    #pragma unroll
    for (int p = 0; p < 2; ++p)
        *(s16x8*)((char*)lds + (p * 32 + srow) * 128 + bc) = r[p];
}

__device__ __forceinline__ void compute64(
    const short* __restrict__ As, const short* __restrict__ Bs,
    int wr, int wc, int l15, int q, f32x4 acc[2][2])
{
    #pragma unroll
    for (int kh = 0; kh < 2; ++kh) {
        const int kb = kh * 64 + q * 16;
        s16x8 a[2], b[2];
        #pragma unroll
        for (int m = 0; m < 2; ++m) {
            int row = wr * 32 + m * 16 + l15;
            a[m] = *(const s16x8*)((const char*)As + row * 128 + (kb ^ ((row & 7) << 4)));
        }
        #pragma unroll
        for (int n = 0; n < 2; ++n) {
            int row = wc * 32 + n * 16 + l15;
            b[n] = *(const s16x8*)((const char*)Bs + row * 128 + (kb ^ ((row & 7) << 4)));
        }
        #pragma unroll
        for (int m = 0; m < 2; ++m)
            #pragma unroll
            for (int n = 0; n < 2; ++n)
                acc[m][n] = __builtin_amdgcn_mfma_f32_16x16x32_bf16(
                    a[m], b[n], acc[m][n], 0, 0, 0);
    }
}

// ---------------- generic GEMM: C[1024][N] = A[1024][K] @ BT[N][K]^T -------
// zparts>1: block z covers K-slice [z*K/zparts, (z+1)*K/zparts); partial
// written to Cf + z*1024*N; bias only in z==0; resid/act/pe only for z==0 use.
__global__ __launch_bounds__(256) void gemm64(
    const short* __restrict__ A, const short* __restrict__ BT,
    const float* __restrict__ bias, const float* __restrict__ resid,
    float* __restrict__ Cf, short* __restrict__ Cbf,
    int N, int K, int act, int add_pe, int zparts)
{
    __shared__ short As[2][4096];
    __shared__ short Bs[2][4096];
    const int tid = threadIdx.x;
    const int row0 = blockIdx.y * 64, col0 = blockIdx.x * 64;
    const int z = blockIdx.z;
    const int Kz = K / zparts;
    const int kbase = z * Kz;
    const int w = tid >> 6, lane = tid & 63, q = lane >> 4, l15 = lane & 15;
    const int wr = w >> 1, wc = w & 1;
    const int nt = Kz >> 6;

    const int srow = tid >> 3;              // 0..31
    const int scolb = (tid & 7) * 16;       // 0..112 bytes
    const char* gA = (const char*)(A  + (size_t)(row0 + srow) * K + kbase) + scolb;
    const char* gB = (const char*)(BT + (size_t)(col0 + srow) * K + kbase) + scolb;
    const size_t rstep = (size_t)32 * K * 2;   // +32 rows, bytes

    s16x8 ra[2], rb[2];
    #pragma unroll
    for (int p = 0; p < 2; ++p) {
        ra[p] = *(const s16x8*)(gA + p * rstep);
        rb[p] = *(const s16x8*)(gB + p * rstep);
    }
    ldswr64(As[0], srow, scolb, ra);
    ldswr64(Bs[0], srow, scolb, rb);
    if (nt > 1) {
        #pragma unroll
        for (int p = 0; p < 2; ++p) {
            ra[p] = *(const s16x8*)(gA + p * rstep + 128);
            rb[p] = *(const s16x8*)(gB + p * rstep + 128);
        }
    }
    __syncthreads();

    f32x4 acc[2][2] = {};
    int cur = 0;
    for (int t = 0; t < nt; ++t) {
        if (t + 1 < nt) {                         // regs hold tile t+1
            ldswr64(As[cur ^ 1], srow, scolb, ra);
            ldswr64(Bs[cur ^ 1], srow, scolb, rb);
        }
        if (t + 2 < nt) {                         // prefetch tile t+2
            size_t ko = (size_t)(t + 2) * 128;
            #pragma unroll
            for (int p = 0; p < 2; ++p) {
                ra[p] = *(const s16x8*)(gA + p * rstep + ko);
                rb[p] = *(const s16x8*)(gB + p * rstep + ko);
            }
        }
        compute64(As[cur], Bs[cur], wr, wc, l15, q, acc);
        __syncthreads();
        cur ^= 1;
    }

    if (zparts > 1 && Cf) Cf += (size_t)z * S_LEN * N;

    const int rbase = row0 + wr * 32 + q * 4;
    const int cbase = col0 + wc * 32 + l15;
    #pragma unroll
    for (int n = 0; n < 2; ++n) {
        int c = cbase + n * 16;
        float bia = (z == 0) ? bias[c] : 0.0f;
        #pragma unroll
        for (int m = 0; m < 2; ++m) {
            #pragma unroll
            for (int rg = 0; rg < 4; ++rg) {
                int r = rbase + m * 16 + rg;
                float v = apply_act(acc[m][n][rg] + bia, act);
                if (resid) v += resid[(size_t)r * N + c];
                if (add_pe) {
                    float freq = expf((float)(c & ~1) * (-9.210340371976184f / 512.0f));
                    float ang = (float)r * freq;
                    v += (c & 1) ? cosf(ang) : sinf(ang);
                }
                if (Cf)  Cf[(size_t)r * N + c] = v;
                if (Cbf) Cbf[(size_t)r * N + c] = f2bf(v);
            }
        }
    }
}

// ---------------- fused QKV: grid (24, 16); phi on Q,K ----------------
__global__ __launch_bounds__(256) void qkv64(
    const short* __restrict__ Hb,
    const short* __restrict__ qT, const short* __restrict__ kT, const short* __restrict__ vT,
    const float* __restrict__ bq, const float* __restrict__ bk, const float* __restrict__ bv,
    float* __restrict__ Qb, float* __restrict__ Kb, float* __restrict__ Vb)
{
    __shared__ short As[2][4096];
    __shared__ short Bs[2][4096];
    const int sel  = blockIdx.x >> 3;              // 0=Q 1=K 2=V
    const int col0 = (blockIdx.x & 7) * 64;
    const int row0 = blockIdx.y * 64;
    const short* BT   = (sel == 0) ? qT : (sel == 1) ? kT : vT;
    const float* bias = (sel == 0) ? bq : (sel == 1) ? bk : bv;
    float* C          = (sel == 0) ? Qb : (sel == 1) ? Kb : Vb;
    const bool phi = (sel < 2);

    const int tid = threadIdx.x;
    const int w = tid >> 6, lane = tid & 63, q = lane >> 4, l15 = lane & 15;
    const int wr = w >> 1, wc = w & 1;

    const int srow = tid >> 3;
    const int scolb = (tid & 7) * 16;
    const char* gA = (const char*)(Hb + (size_t)(row0 + srow) * DM) + scolb;
    const char* gB = (const char*)(BT + (size_t)(col0 + srow) * DM) + scolb;
    const size_t rstep = (size_t)32 * DM * 2;

    s16x8 ra[2], rb[2];
    #pragma unroll
    for (int p = 0; p < 2; ++p) {
        ra[p] = *(const s16x8*)(gA + p * rstep);
        rb[p] = *(const s16x8*)(gB + p * rstep);
    }
    ldswr64(As[0], srow, scolb, ra);
    ldswr64(Bs[0], srow, scolb, rb);
    #pragma unroll
    for (int p = 0; p < 2; ++p) {
        ra[p] = *(const s16x8*)(gA + p * rstep + 128);
        rb[p] = *(const s16x8*)(gB + p * rstep + 128);
    }
    __syncthreads();

    f32x4 acc[2][2] = {};
    int cur = 0;
    for (int t = 0; t < 8; ++t) {                  // K = 512 -> 8 tiles
        if (t + 1 < 8) {
            ldswr64(As[cur ^ 1], srow, scolb, ra);
            ldswr64(Bs[cur ^ 1], srow, scolb, rb);
        }
        if (t + 2 < 8) {
            size_t ko = (size_t)(t + 2) * 128;
            #pragma unroll
            for (int p = 0; p < 2; ++p) {
                ra[p] = *(const s16x8*)(gA + p * rstep + ko);
                rb[p] = *(const s16x8*)(gB + p * rstep + ko);
            }
        }
        compute64(As[cur], Bs[cur], wr, wc, l15, q, acc);
        __syncthreads();
        cur ^= 1;
    }

    const int rbase = row0 + wr * 32 + q * 4;
    const int cbase = col0 + wc * 32 + l15;
    #pragma unroll
    for (int n = 0; n < 2; ++n) {
        int c = cbase + n * 16;
        float bia = bias[c];
        #pragma unroll
        for (int m = 0; m < 2; ++m) {
            #pragma unroll
            for (int rg = 0; rg < 4; ++rg) {
                int r = rbase + m * 16 + rg;
                float v = acc[m][n][rg] + bia;
                if (phi) v = (v > 0.0f) ? (v + 1.0f) : expf(v);
                C[(size_t)r * DM + c] = v;
            }
        }
    }
}

// ---------------- chunk stats: per (head, chunk) KV_c = K_c^T V_c, ksum_c ----
__global__ __launch_bounds__(256) void chunk_stats_kernel(
    const float* __restrict__ Kb, const float* __restrict__ Vb,
    float* __restrict__ KVC, float* __restrict__ KSC)
{
    const int h = blockIdx.x >> 4, c = blockIdx.x & 15;
    const int tid = threadIdx.x;
    __shared__ float Ks[64][68];
    __shared__ float Vs[64][68];
    #pragma unroll
    for (int it = 0; it < 4; ++it) {
        int j = tid + it * 256;                 // 0..1023 f32x4 slots
        int r = j >> 4, d0 = (j & 15) * 4;
        size_t g = (size_t)(c * CHUNK + r) * DM + h * 64 + d0;
        *(f32x4*)(&Ks[r][d0]) = *(const f32x4*)(Kb + g);
        *(f32x4*)(&Vs[r][d0]) = *(const f32x4*)(Vb + g);
    }
    __syncthreads();
    const int di = (tid >> 4) * 4, ei = (tid & 15) * 4;
    f32x4 a0 = {}, a1 = {}, a2 = {}, a3 = {}, ks = {};
    #pragma unroll 8
    for (int t = 0; t < 64; ++t) {
        f32x4 kk = *(const f32x4*)(&Ks[t][di]);
        f32x4 vv = *(const f32x4*)(&Vs[t][ei]);
        fma4(a0, kk.x, vv); fma4(a1, kk.y, vv);
        fma4(a2, kk.z, vv); fma4(a3, kk.w, vv);
        ks += kk;
    }
    float* out = KVC + (size_t)(c * NH + h) * 4096;   // [d][e] row-major
    *(f32x4*)(out + (size_t)(di + 0) * 64 + ei) = a0;
    *(f32x4*)(out + (size_t)(di + 1) * 64 + ei) = a1;
    *(f32x4*)(out + (size_t)(di + 2) * 64 + ei) = a2;
    *(f32x4*)(out + (size_t)(di + 3) * 64 + ei) = a3;
    if ((tid & 15) == 0)
        *(f32x4*)(KSC + (size_t)(c * NH + h) * 64 + di) = ks;
}

// ---------------- attention output per (head, chunk) ----------------
// Inline exclusive prefix over per-chunk states (KVC/KSC are per-chunk,
// NOT pre-scanned): block (h,c) register-accumulates sum_{c'<c} KVC[c'].
__global__ __launch_bounds__(256) void attn_out_kernel(
    const float* __restrict__ Qb, const float* __restrict__ Kb,
    const float* __restrict__ Vb, const float* __restrict__ KVC,
    const float* __restrict__ KSC, short* __restrict__ Ab)
{
    const int h = blockIdx.x >> 4, c = blockIdx.x & 15;
    const int tid = threadIdx.x;
    __shared__ float Qt[64][68];   // Qt[d][s]  (transposed)
    __shared__ float Kt[64][68];   // Kt[d][t]  (transposed)
    __shared__ float Vs[64][68];   // Vs[t][e]
    __shared__ float Ms[64][68];   // state: Ms[d][e]
    __shared__ float St[64][68];   // St[t][s]  (S transposed)
    __shared__ float KSs[64];

    // inline prefix: Ms = sum_{c'<c} KVC[c',h]
    {
        f32x4 macc[4] = {};
        for (int cp = 0; cp < c; ++cp) {
            const float* src = KVC + (size_t)(cp * NH + h) * 4096;
            #pragma unroll
            for (int it = 0; it < 4; ++it)
                macc[it] += *(const f32x4*)(src + (size_t)(tid + it * 256) * 4);
        }
        #pragma unroll
        for (int it = 0; it < 4; ++it) {
            int j = tid + it * 256;
            *(f32x4*)(&Ms[j >> 4][(j & 15) * 4]) = macc[it];
        }
        if (tid < 64) {
            float s = 0.0f;
            for (int cp = 0; cp < c; ++cp)
                s += KSC[(size_t)(cp * NH + h) * 64 + tid];
            KSs[tid] = s;
        }
    }
    #pragma unroll
    for (int it = 0; it < 4; ++it) {
        int j = tid + it * 256;                 // 0..1023
        int r = j >> 4, d0 = (j & 15) * 4;
        size_t g = (size_t)(c * CHUNK + r) * DM + h * 64 + d0;
        f32x4 q = *(const f32x4*)(Qb + g);
        f32x4 k = *(const f32x4*)(Kb + g);
        f32x4 v = *(const f32x4*)(Vb + g);
        Qt[d0 + 0][r] = q.x; Qt[d0 + 1][r] = q.y; Qt[d0 + 2][r] = q.z; Qt[d0 + 3][r] = q.w;
        Kt[d0 + 0][r] = k.x; Kt[d0 + 1][r] = k.y; Kt[d0 + 2][r] = k.z; Kt[d0 + 3][r] = k.w;
        *(f32x4*)(&Vs[r][d0]) = v;
    }
    __syncthreads();

    const int si = tid >> 4, ti = tid & 15;
    const int s0 = si * 4, t0 = ti * 4;         // t0 doubles as e0

    // ---- Phase A: inter-chunk O = Q @ State, den = Q . KSprefix ----
    f32x4 accO0 = {}, accO1 = {}, accO2 = {}, accO3 = {};
    f32x4 den = {};
    #pragma unroll 8
    for (int d = 0; d < 64; ++d) {
        f32x4 qv = *(const f32x4*)(&Qt[d][s0]);
        f32x4 mv = *(const f32x4*)(&Ms[d][t0]);
        float ks = KSs[d];
        fma4(accO0, qv.x, mv); fma4(accO1, qv.y, mv);
        fma4(accO2, qv.z, mv); fma4(accO3, qv.w, mv);
        fma4(den, ks, qv);
    }

    // ---- Phase B: S = Q K^T, causal, staged transposed ----
    f32x4 p0 = {}, p1 = {}, p2 = {}, p3 = {};   // p_r = S[s0+r][t0:t0+4]
    if (ti <= si) {
        #pragma unroll 8
        for (int d = 0; d < 64; ++d) {
            f32x4 qv = *(const f32x4*)(&Qt[d][s0]);
            f32x4 kv = *(const f32x4*)(&Kt[d][t0]);
            fma4(p0, qv.x, kv); fma4(p1, qv.y, kv);
            fma4(p2, qv.z, kv); fma4(p3, qv.w, kv);
        }
        if (ti == si) {                          // diagonal tile: keep t<=r
            p0.y = 0.0f; p0.z = 0.0f; p0.w = 0.0f;
            p1.z = 0.0f; p1.w = 0.0f;
            p2.w = 0.0f;
        }
    }
    St[t0 + 0][s0 + 0] = p0.x; St[t0 + 1][s0 + 0] = p0.y;
    St[t0 + 2][s0 + 0] = p0.z; St[t0 + 3][s0 + 0] = p0.w;
    St[t0 + 0][s0 + 1] = p1.x; St[t0 + 1][s0 + 1] = p1.y;
    St[t0 + 2][s0 + 1] = p1.z; St[t0 + 3][s0 + 1] = p1.w;
    St[t0 + 0][s0 + 2] = p2.x; St[t0 + 1][s0 + 2] = p2.y;
    St[t0 + 2][s0 + 2] = p2.z; St[t0 + 3][s0 + 2] = p2.w;
    St[t0 + 0][s0 + 3] = p3.x; St[t0 + 1][s0 + 3] = p3.y;
    St[t0 + 2][s0 + 3] = p3.z; St[t0 + 3][s0 + 3] = p3.w;
    __syncthreads();

    // ---- Phase C: O += S @ V ; den += rowsum(S) ----
    const int tmax = s0 + 4;                     // exclusive; St zero above diag
    #pragma unroll 4
    for (int t2 = 0; t2 < tmax; ++t2) {
        f32x4 sv = *(const f32x4*)(&St[t2][s0]);
        f32x4 vv = *(const f32x4*)(&Vs[t2][t0]);
        fma4(accO0, sv.x, vv); fma4(accO1, sv.y, vv);
        fma4(accO2, sv.z, vv); fma4(accO3, sv.w, vv);
        den += sv;
    }

    // ---- epilogue: z = 1/(den+eps), bf16 out ----
    short* op = Ab + (size_t)(c * CHUNK + s0) * DM + h * 64 + t0;
    {
        float z = 1.0f / (den.x + 1e-6f);
        short4 o; o.x = f2bf(accO0.x * z); o.y = f2bf(accO0.y * z);
        o.z = f2bf(accO0.z * z); o.w = f2bf(accO0.w * z);
        *reinterpret_cast<short4*>(op) = o;
    }
    {
        float z = 1.0f / (den.y + 1e-6f);
        short4 o; o.x = f2bf(accO1.x * z); o.y = f2bf(accO1.y * z);
        o.z = f2bf(accO1.z * z); o.w = f2bf(accO1.w * z);
        *reinterpret_cast<short4*>(op + DM) = o;
    }
    {
        float z = 1.0f / (den.z + 1e-6f);
        short4 o; o.x = f2bf(accO2.x * z); o.y = f2bf(accO2.y * z);
        o.z = f2bf(accO2.z * z); o.w = f2bf(accO2.w * z);
        *reinterpret_cast<short4*>(op + 2 * DM) = o;
    }
    {
        float z = 1.0f / (den.w + 1e-6f);
        short4 o; o.x = f2bf(accO3.x * z); o.y = f2bf(accO3.y * z);
        o.z = f2bf(accO3.z * z); o.w = f2bf(accO3.w * z);
        *reinterpret_cast<short4*>(op + 3 * DM) = o;
    }
}

// ---------------- layernorm: LN(X + X2? + resid?) -> O (+bf16 mirror) -------
__device__ __forceinline__ float block_reduce_sum(float v, float* smem)
{
    #pragma unroll
    for (int o = 32; o > 0; o >>= 1) v += __shfl_down(v, o, 64);
    int w = threadIdx.x >> 6;
    if ((threadIdx.x & 63) == 0) smem[w] = v;
    __syncthreads();
    v = smem[0] + smem[1] + smem[2] + smem[3];
    __syncthreads();
    return v;
}

__global__ __launch_bounds__(256) void ln_kernel(
    const float* __restrict__ X, const float* __restrict__ X2,
    const float* __restrict__ resid,
    const float* __restrict__ g, const float* __restrict__ b,
    float* __restrict__ O, short* __restrict__ Ob)
{
    __shared__ float red[4];
    const int row = blockIdx.x;
    const size_t base = (size_t)row * DM;
    const int t = threadIdx.x;
    float v0 = X[base + t], v1 = X[base + t + 256];
    if (X2)    { v0 += X2[base + t];    v1 += X2[base + t + 256]; }
    if (resid) { v0 += resid[base + t]; v1 += resid[base + t + 256]; }
    float mean = block_reduce_sum(v0 + v1, red) * (1.0f / 512.0f);
    float d0 = v0 - mean, d1 = v1 - mean;
    float var = block_reduce_sum(d0 * d0 + d1 * d1, red) * (1.0f / 512.0f);
    float rs = 1.0f / sqrtf(var + 1e-5f);
    float o0 = d0 * rs * g[t] + b[t];
    float o1 = d1 * rs * g[t + 256] + b[t + 256];
    O[base + t]       = o0;
    O[base + t + 256] = o1;
    if (Ob) {
        Ob[base + t]       = f2bf(o0);
        Ob[base + t + 256] = f2bf(o1);
    }
}

// ---------------- emotion head: [1024,512] @ [512,8] + b ----------------
__global__ __launch_bounds__(256) void proj_emo_kernel(
    const float* __restrict__ HF, const float* __restrict__ pw,
    const float* __restrict__ pb, float* __restrict__ out)
{
    __shared__ float pws[4096];
    for (int i = threadIdx.x; i < 4096; i += 256) pws[i] = pw[i];
    __syncthreads();
    int idx = blockIdx.x * 256 + threadIdx.x;
    int r = idx >> 3, e = idx & 7;
    float acc = pb[e];
    const float* h = HF + (size_t)r * DM;
    for (int d = 0; d < DM; d += 4) {
        f32x4 hv = *(const f32x4*)(h + d);
        acc += hv.x * pws[(d + 0) * 8 + e] + hv.y * pws[(d + 1) * 8 + e]
             + hv.z * pws[(d + 2) * 8 + e] + hv.w * pws[(d + 3) * 8 + e];
    }
    out[idx] = acc;
}

// ---------------------------------------------------------------------------
extern "C" void kernel_launch(void* const* d_in, const int* in_sizes, int n_in,
                              void* d_out, int out_size, void* d_ws, size_t ws_size,
                              hipStream_t stream)
{
    const int*   x    = (const int*)d_in[0];
    const float* e0   = (const float*)d_in[1];
    const float* e1   = (const float*)d_in[2];
    const float* e2   = (const float*)d_in[3];
    const float* e3   = (const float*)d_in[4];
    const float* e4   = (const float*)d_in[5];
    const float* e5   = (const float*)d_in[6];
    const float* in_w = (const float*)d_in[7];
    const float* in_b = (const float*)d_in[8];
    const float* wq   = (const float*)d_in[9];
    const float* bq   = (const float*)d_in[10];
    const float* wk   = (const float*)d_in[11];
    const float* bk   = (const float*)d_in[12];
    const float* wv   = (const float*)d_in[13];
    const float* bv   = (const float*)d_in[14];
    const float* wo   = (const float*)d_in[15];
    const float* bo   = (const float*)d_in[16];
    const float* g1   = (const float*)d_in[17];
    const float* be1  = (const float*)d_in[18];
    const float* w1   = (const float*)d_in[19];
    const float* b1   = (const float*)d_in[20];
    const float* w2   = (const float*)d_in[21];
    const float* b2   = (const float*)d_in[22];
    const float* g2   = (const float*)d_in[23];
    const float* be2  = (const float*)d_in[24];
    const float* gf   = (const float*)d_in[25];
    const float* bfin = (const float*)d_in[26];
    const float* pw   = (const float*)d_in[27];
    const float* pb   = (const float*)d_in[28];
    float* outp = (float*)d_out;

    // ---- workspace layout: Y,Y2 contiguous partial arena ----
    float* ws = (float*)d_ws;
    float* H    = ws;                  // 1024x512 f32
    float* Y    = ws + 524288;         // partial 0 (and pre-LN sum input)
    float* Y2   = ws + 1048576;        // partial 1 (contiguous with Y)
    float* Qb   = ws + 1572864;
    float* Kb   = ws + 2097152;
    float* Vb   = ws + 2621440;
    float* KVC  = ws + 3145728;        // 16*8*4096 = 524288
    float* KSC  = ws + 3670016;        // 8192 (ends 3678208)
    short* sb   = (short*)(ws + 3678208);
    short* Hb   = sb;                  // 1024x512
    short* Ab   = sb + 524288;         // 1024x512
    short* FFb  = sb + 1048576;        // 1024x2048
    short* EMBb = FFb;                 // 1024x768 (alias: dead before ffn1)
    // bf16 W^T arena [N][K]
    short* inT  = sb + 3145728;        // [512][768]
    short* qT   = inT + 393216;        // [12][512][512]
    short* kT   = qT + 3145728;
    short* vT   = kT + 3145728;
    short* oT   = vT + 3145728;
    short* w1T  = oT + 3145728;        // [12][2048][512]
    short* w2T  = w1T + 12582912;      // [12][512][2048]

    const dim3 blk256(256);

    // ---- weight transpose+convert ----
    transpose_w<<<dim3(8, 12, 1),  blk256, 0, stream>>>(in_w, inT, 768, DM);
    transpose_w<<<dim3(8, 8, 12),  blk256, 0, stream>>>(wq, qT, DM, DM);
    transpose_w<<<dim3(8, 8, 12),  blk256, 0, stream>>>(wk, kT, DM, DM);
    transpose_w<<<dim3(8, 8, 12),  blk256, 0, stream>>>(wv, vT, DM, DM);
    transpose_w<<<dim3(8, 8, 12),  blk256, 0, stream>>>(wo, oT, DM, DM);
    transpose_w<<<dim3(32, 8, 12), blk256, 0, stream>>>(w1, w1T, DM, DFF);
    transpose_w<<<dim3(8, 32, 12), blk256, 0, stream>>>(w2, w2T, DFF, DM);

    embed_kernel<<<S_LEN, blk256, 0, stream>>>(x, e0, e1, e2, e3, e4, e5, EMBb);
    // in-proj: EMBb @ in_w + in_b + PE -> H (f32) and Hb (bf16)
    gemm64<<<dim3(8, 16, 1), blk256, 0, stream>>>(EMBb, inT, in_b, nullptr,
                                                  H, Hb, DM, 768, ACT_NONE, 1, 1);

    for (int l = 0; l < NLAYER; ++l) {
        const short* qT_l = qT + (size_t)l * DM * DM;
        const short* kT_l = kT + (size_t)l * DM * DM;
        const short* vT_l = vT + (size_t)l * DM * DM;
        const short* oT_l = oT + (size_t)l * DM * DM;
        const short* w1T_l = w1T + (size_t)l * DM * DFF;
        const short* w2T_l = w2T + (size_t)l * DM * DFF;
        const float* bq_l = bq + l * DM;  const float* bk_l = bk + l * DM;
        const float* bv_l = bv + l * DM;  const float* bo_l = bo + l * DM;
        const float* b1_l = b1 + l * DFF; const float* b2_l = b2 + l * DM;

        qkv64<<<dim3(24, 16), blk256, 0, stream>>>(Hb, qT_l, kT_l, vT_l,
                                                   bq_l, bk_l, bv_l, Qb, Kb, Vb);

        chunk_stats_kernel<<<NCH * NH, blk256, 0, stream>>>(Kb, Vb, KVC, KSC);
        attn_out_kernel<<<NCH * NH, blk256, 0, stream>>>(Qb, Kb, Vb, KVC, KSC, Ab);

        // wo: Ab @ wo + bo + resid(H) -> Y (f32); then LN -> H, Hb
        gemm64<<<dim3(8, 16, 1), blk256, 0, stream>>>(Ab, oT_l, bo_l, H,
                                                      Y, nullptr, DM, DM, ACT_NONE, 0, 1);
        ln_kernel<<<S_LEN, blk256, 0, stream>>>(Y, nullptr, nullptr,
                                                g1 + l * DM, be1 + l * DM, H, Hb);

        // ffn1: Hb @ w1 + b1, GELU -> FFb (bf16)
        gemm64<<<dim3(32, 16, 1), blk256, 0, stream>>>(Hb, w1T_l, b1_l, nullptr,
                                                       nullptr, FFb, DFF, DM, ACT_GELU, 0, 1);
        // ffn2 split-K z=2: partials Y (z0,+bias), Y2 (z1); LN(Y+Y2+H)
        gemm64<<<dim3(8, 16, 2), blk256, 0, stream>>>(FFb, w2T_l, b2_l, nullptr,
                                                      Y, nullptr, DM, DFF, ACT_NONE, 0, 2);
        ln_kernel<<<S_LEN, blk256, 0, stream>>>(Y, Y2, H,
                                                g2 + l * DM, be2 + l * DM, H, Hb);
    }

    // final norm -> d_out (f32 h), then emotion head
    ln_kernel<<<S_LEN, blk256, 0, stream>>>(H, nullptr, nullptr, gf, bfin, outp, nullptr);
    proj_emo_kernel<<<8192 / 256, blk256, 0, stream>>>(outp, pw, pb, outp + 524288);
}

// Round 6
// 1057.478 us; speedup vs baseline: 1.2214x; 1.0512x over previous
//
#include <hip/hip_runtime.h>
#include <hip/hip_bf16.h>
#include <math.h>

// ---------------------------------------------------------------------------
// TransformerModel: 12-layer causal linear-attention encoder.
// B=1, S=1024, D_MODEL=512, H=8, Dh=64, FF=2048. All tensors fp32 (x int32).
// Round 15: kill the per-iteration vmem drain. __syncthreads() emits
// s_waitcnt vmcnt(0) before s_barrier, forcing the t+2 global prefetch to
// COMPLETE every K-iteration (m97-ceiling analysis). Replaced in the gemm
// main loops with lgkmcnt(0)-only + raw s_barrier (catalog T4 / 2-phase
// recipe): prefetch loads stay in flight across the barrier. Also: wo
// split-K z=2 (ffn2-proven pattern), resid folded into ln(Y,Y2,H).
// Everything else identical to R14 (1112us).
// ---------------------------------------------------------------------------

#define S_LEN 1024
#define DM 512
#define NH 8
#define DH 64
#define DFF 2048
#define NLAYER 12
#define CHUNK 64
#define NCH (S_LEN / CHUNK)   // 16

#define ACT_NONE 0
#define ACT_PHI  1
#define ACT_GELU 2

typedef short s16x8 __attribute__((ext_vector_type(8)));
typedef float f32x4 __attribute__((ext_vector_type(4)));

__device__ __forceinline__ short f2bf(float x) {
    __hip_bfloat16 h = __float2bfloat16(x);
    return *reinterpret_cast<short*>(&h);
}

__device__ __forceinline__ void fma4(f32x4& a, float s, const f32x4 v) {
    a.x = fmaf(s, v.x, a.x); a.y = fmaf(s, v.y, a.y);
    a.z = fmaf(s, v.z, a.z); a.w = fmaf(s, v.w, a.w);
}

// LDS-only barrier: drains DS ops, leaves global->reg prefetch in flight.
// Trailing empty asm blocks LDS-read hoisting across the raw s_barrier.
__device__ __forceinline__ void tile_barrier() {
    asm volatile("s_waitcnt lgkmcnt(0)" ::: "memory");
    __builtin_amdgcn_s_barrier();
    asm volatile("" ::: "memory");
}

// ---------------- embedding gather (writes bf16) ----------------
__global__ __launch_bounds__(256) void embed_kernel(
    const int* __restrict__ x,
    const float* __restrict__ t0, const float* __restrict__ t1,
    const float* __restrict__ t2, const float* __restrict__ t3,
    const float* __restrict__ t4, const float* __restrict__ t5,
    short* __restrict__ EMBb)
{
    int s = blockIdx.x;
    __shared__ int xi[6];
    if (threadIdx.x < 6) xi[threadIdx.x] = x[s * 6 + threadIdx.x];
    __syncthreads();
    for (int j = threadIdx.x; j < 768; j += 256) {
        int i, off, width; const float* t; float sc;
        if (j < 32)       { i = 0; off = 0;   t = t0; sc = 5.656854249f;  width = 32;  }
        else if (j < 160) { i = 1; off = 32;  t = t1; sc = 11.3137085f;   width = 128; }
        else if (j < 416) { i = 2; off = 160; t = t2; sc = 16.0f;         width = 256; }
        else if (j < 672) { i = 3; off = 416; t = t3; sc = 16.0f;         width = 256; }
        else if (j < 704) { i = 4; off = 672; t = t4; sc = 5.656854249f;  width = 32;  }
        else              { i = 5; off = 704; t = t5; sc = 8.0f;          width = 64;  }
        EMBb[s * 768 + j] = f2bf(t[xi[i] * width + (j - off)] * sc);
    }
}

// ---------------- weight transpose+convert: f32 [B][K][N] -> bf16 [B][N][K] ----
__global__ __launch_bounds__(256) void transpose_w(
    const float* __restrict__ in, short* __restrict__ out, int K, int N)
{
    __shared__ short t[64][66];
    const int b = blockIdx.z;
    const int n0 = blockIdx.x * 64, k0 = blockIdx.y * 64;
    const float* ip = in + (size_t)b * K * N;
    short* op = out + (size_t)b * K * N;
    const int c = threadIdx.x & 63, r0 = (threadIdx.x >> 6) * 16;
    #pragma unroll
    for (int i = 0; i < 16; ++i)
        t[c][r0 + i] = f2bf(ip[(size_t)(k0 + r0 + i) * N + n0 + c]);
    __syncthreads();
    #pragma unroll
    for (int i = 0; i < 16; ++i)
        op[(size_t)(n0 + r0 + i) * K + k0 + c] = t[r0 + i][c];
}

// ---------------- activation ----------------
__device__ __forceinline__ float apply_act(float v, int act) {
    if (act == ACT_PHI)       return (v > 0.0f) ? (v + 1.0f) : expf(v);
    else if (act == ACT_GELU) return 0.5f * v * (1.0f + erff(v * 0.70710678118654752f));
    return v;
}

// ---------------- 64x64-tile MFMA GEMM core (R12, proven) ------------------
// LDS tile: [64 rows][64 k] bf16 = 8KB, double-buffered for A and B (32KB).
// Bank swizzle: byte col ^= (row&7)<<4 on BOTH ds_write and ds_read.

__device__ __forceinline__ void ldswr64(short* lds, int srow, int scolb,
                                        const s16x8 r[2])
{
    const int bc = scolb ^ ((srow & 7) << 4);
    #pragma unroll
    for (int p = 0; p < 2; ++p)
        *(s16x8*)((char*)lds + (p * 32 + srow) * 128 + bc) = r[p];
}

__device__ __forceinline__ void compute64(
    const short* __restrict__ As, const short* __restrict__ Bs,
    int wr, int wc, int l15, int q, f32x4 acc[2][2])
{
    #pragma unroll
    for (int kh = 0; kh < 2; ++kh) {
        const int kb = kh * 64 + q * 16;
        s16x8 a[2], b[2];
        #pragma unroll
        for (int m = 0; m < 2; ++m) {
            int row = wr * 32 + m * 16 + l15;
            a[m] = *(const s16x8*)((const char*)As + row * 128 + (kb ^ ((row & 7) << 4)));
        }
        #pragma unroll
        for (int n = 0; n < 2; ++n) {
            int row = wc * 32 + n * 16 + l15;
            b[n] = *(const s16x8*)((const char*)Bs + row * 128 + (kb ^ ((row & 7) << 4)));
        }
        #pragma unroll
        for (int m = 0; m < 2; ++m)
            #pragma unroll
            for (int n = 0; n < 2; ++n)
                acc[m][n] = __builtin_amdgcn_mfma_f32_16x16x32_bf16(
                    a[m], b[n], acc[m][n], 0, 0, 0);
    }
}

// ---------------- generic GEMM: C[1024][N] = A[1024][K] @ BT[N][K]^T -------
// zparts>1: block z covers K-slice [z*K/zparts, (z+1)*K/zparts); partial
// written to Cf + z*1024*N; bias only in z==0.
__global__ __launch_bounds__(256) void gemm64(
    const short* __restrict__ A, const short* __restrict__ BT,
    const float* __restrict__ bias, const float* __restrict__ resid,
    float* __restrict__ Cf, short* __restrict__ Cbf,
    int N, int K, int act, int add_pe, int zparts)
{
    __shared__ short As[2][4096];
    __shared__ short Bs[2][4096];
    const int tid = threadIdx.x;
    const int row0 = blockIdx.y * 64, col0 = blockIdx.x * 64;
    const int z = blockIdx.z;
    const int Kz = K / zparts;
    const int kbase = z * Kz;
    const int w = tid >> 6, lane = tid & 63, q = lane >> 4, l15 = lane & 15;
    const int wr = w >> 1, wc = w & 1;
    const int nt = Kz >> 6;

    const int srow = tid >> 3;              // 0..31
    const int scolb = (tid & 7) * 16;       // 0..112 bytes
    const char* gA = (const char*)(A  + (size_t)(row0 + srow) * K + kbase) + scolb;
    const char* gB = (const char*)(BT + (size_t)(col0 + srow) * K + kbase) + scolb;
    const size_t rstep = (size_t)32 * K * 2;   // +32 rows, bytes

    s16x8 ra[2], rb[2];
    #pragma unroll
    for (int p = 0; p < 2; ++p) {
        ra[p] = *(const s16x8*)(gA + p * rstep);
        rb[p] = *(const s16x8*)(gB + p * rstep);
    }
    ldswr64(As[0], srow, scolb, ra);
    ldswr64(Bs[0], srow, scolb, rb);
    if (nt > 1) {
        #pragma unroll
        for (int p = 0; p < 2; ++p) {
            ra[p] = *(const s16x8*)(gA + p * rstep + 128);
            rb[p] = *(const s16x8*)(gB + p * rstep + 128);
        }
    }
    tile_barrier();

    f32x4 acc[2][2] = {};
    int cur = 0;
    for (int t = 0; t < nt; ++t) {
        if (t + 1 < nt) {                         // regs hold tile t+1
            ldswr64(As[cur ^ 1], srow, scolb, ra);
            ldswr64(Bs[cur ^ 1], srow, scolb, rb);
        }
        if (t + 2 < nt) {                         // prefetch tile t+2 (stays
            size_t ko = (size_t)(t + 2) * 128;    //  in flight across barrier)
            #pragma unroll
            for (int p = 0; p < 2; ++p) {
                ra[p] = *(const s16x8*)(gA + p * rstep + ko);
                rb[p] = *(const s16x8*)(gB + p * rstep + ko);
            }
        }
        compute64(As[cur], Bs[cur], wr, wc, l15, q, acc);
        tile_barrier();
        cur ^= 1;
    }

    if (zparts > 1 && Cf) Cf += (size_t)z * S_LEN * N;

    const int rbase = row0 + wr * 32 + q * 4;
    const int cbase = col0 + wc * 32 + l15;
    #pragma unroll
    for (int n = 0; n < 2; ++n) {
        int c = cbase + n * 16;
        float bia = (z == 0) ? bias[c] : 0.0f;
        #pragma unroll
        for (int m = 0; m < 2; ++m) {
            #pragma unroll
            for (int rg = 0; rg < 4; ++rg) {
                int r = rbase + m * 16 + rg;
                float v = apply_act(acc[m][n][rg] + bia, act);
                if (resid) v += resid[(size_t)r * N + c];
                if (add_pe) {
                    float freq = expf((float)(c & ~1) * (-9.210340371976184f / 512.0f));
                    float ang = (float)r * freq;
                    v += (c & 1) ? cosf(ang) : sinf(ang);
                }
                if (Cf)  Cf[(size_t)r * N + c] = v;
                if (Cbf) Cbf[(size_t)r * N + c] = f2bf(v);
            }
        }
    }
}

// ---------------- fused QKV: grid (24, 16); phi on Q,K ----------------
__global__ __launch_bounds__(256) void qkv64(
    const short* __restrict__ Hb,
    const short* __restrict__ qT, const short* __restrict__ kT, const short* __restrict__ vT,
    const float* __restrict__ bq, const float* __restrict__ bk, const float* __restrict__ bv,
    float* __restrict__ Qb, float* __restrict__ Kb, float* __restrict__ Vb)
{
    __shared__ short As[2][4096];
    __shared__ short Bs[2][4096];
    const int sel  = blockIdx.x >> 3;              // 0=Q 1=K 2=V
    const int col0 = (blockIdx.x & 7) * 64;
    const int row0 = blockIdx.y * 64;
    const short* BT   = (sel == 0) ? qT : (sel == 1) ? kT : vT;
    const float* bias = (sel == 0) ? bq : (sel == 1) ? bk : bv;
    float* C          = (sel == 0) ? Qb : (sel == 1) ? Kb : Vb;
    const bool phi = (sel < 2);

    const int tid = threadIdx.x;
    const int w = tid >> 6, lane = tid & 63, q = lane >> 4, l15 = lane & 15;
    const int wr = w >> 1, wc = w & 1;

    const int srow = tid >> 3;
    const int scolb = (tid & 7) * 16;
    const char* gA = (const char*)(Hb + (size_t)(row0 + srow) * DM) + scolb;
    const char* gB = (const char*)(BT + (size_t)(col0 + srow) * DM) + scolb;
    const size_t rstep = (size_t)32 * DM * 2;

    s16x8 ra[2], rb[2];
    #pragma unroll
    for (int p = 0; p < 2; ++p) {
        ra[p] = *(const s16x8*)(gA + p * rstep);
        rb[p] = *(const s16x8*)(gB + p * rstep);
    }
    ldswr64(As[0], srow, scolb, ra);
    ldswr64(Bs[0], srow, scolb, rb);
    #pragma unroll
    for (int p = 0; p < 2; ++p) {
        ra[p] = *(const s16x8*)(gA + p * rstep + 128);
        rb[p] = *(const s16x8*)(gB + p * rstep + 128);
    }
    tile_barrier();

    f32x4 acc[2][2] = {};
    int cur = 0;
    for (int t = 0; t < 8; ++t) {                  // K = 512 -> 8 tiles
        if (t + 1 < 8) {
            ldswr64(As[cur ^ 1], srow, scolb, ra);
            ldswr64(Bs[cur ^ 1], srow, scolb, rb);
        }
        if (t + 2 < 8) {
            size_t ko = (size_t)(t + 2) * 128;
            #pragma unroll
            for (int p = 0; p < 2; ++p) {
                ra[p] = *(const s16x8*)(gA + p * rstep + ko);
                rb[p] = *(const s16x8*)(gB + p * rstep + ko);
            }
        }
        compute64(As[cur], Bs[cur], wr, wc, l15, q, acc);
        tile_barrier();
        cur ^= 1;
    }

    const int rbase = row0 + wr * 32 + q * 4;
    const int cbase = col0 + wc * 32 + l15;
    #pragma unroll
    for (int n = 0; n < 2; ++n) {
        int c = cbase + n * 16;
        float bia = bias[c];
        #pragma unroll
        for (int m = 0; m < 2; ++m) {
            #pragma unroll
            for (int rg = 0; rg < 4; ++rg) {
                int r = rbase + m * 16 + rg;
                float v = acc[m][n][rg] + bia;
                if (phi) v = (v > 0.0f) ? (v + 1.0f) : expf(v);
                C[(size_t)r * DM + c] = v;
            }
        }
    }
}

// ---------------- chunk stats: per (head, chunk) KV_c = K_c^T V_c, ksum_c ----
__global__ __launch_bounds__(256) void chunk_stats_kernel(
    const float* __restrict__ Kb, const float* __restrict__ Vb,
    float* __restrict__ KVC, float* __restrict__ KSC)
{
    const int h = blockIdx.x >> 4, c = blockIdx.x & 15;
    const int tid = threadIdx.x;
    __shared__ float Ks[64][68];
    __shared__ float Vs[64][68];
    #pragma unroll
    for (int it = 0; it < 4; ++it) {
        int j = tid + it * 256;                 // 0..1023 f32x4 slots
        int r = j >> 4, d0 = (j & 15) * 4;
        size_t g = (size_t)(c * CHUNK + r) * DM + h * 64 + d0;
        *(f32x4*)(&Ks[r][d0]) = *(const f32x4*)(Kb + g);
        *(f32x4*)(&Vs[r][d0]) = *(const f32x4*)(Vb + g);
    }
    __syncthreads();
    const int di = (tid >> 4) * 4, ei = (tid & 15) * 4;
    f32x4 a0 = {}, a1 = {}, a2 = {}, a3 = {}, ks = {};
    #pragma unroll 8
    for (int t = 0; t < 64; ++t) {
        f32x4 kk = *(const f32x4*)(&Ks[t][di]);
        f32x4 vv = *(const f32x4*)(&Vs[t][ei]);
        fma4(a0, kk.x, vv); fma4(a1, kk.y, vv);
        fma4(a2, kk.z, vv); fma4(a3, kk.w, vv);
        ks += kk;
    }
    float* out = KVC + (size_t)(c * NH + h) * 4096;   // [d][e] row-major
    *(f32x4*)(out + (size_t)(di + 0) * 64 + ei) = a0;
    *(f32x4*)(out + (size_t)(di + 1) * 64 + ei) = a1;
    *(f32x4*)(out + (size_t)(di + 2) * 64 + ei) = a2;
    *(f32x4*)(out + (size_t)(di + 3) * 64 + ei) = a3;
    if ((tid & 15) == 0)
        *(f32x4*)(KSC + (size_t)(c * NH + h) * 64 + di) = ks;
}

// ---------------- attention output per (head, chunk) ----------------
// Inline exclusive prefix over per-chunk states (KVC/KSC per-chunk).
__global__ __launch_bounds__(256) void attn_out_kernel(
    const float* __restrict__ Qb, const float* __restrict__ Kb,
    const float* __restrict__ Vb, const float* __restrict__ KVC,
    const float* __restrict__ KSC, short* __restrict__ Ab)
{
    const int h = blockIdx.x >> 4, c = blockIdx.x & 15;
    const int tid = threadIdx.x;
    __shared__ float Qt[64][68];   // Qt[d][s]  (transposed)
    __shared__ float Kt[64][68];   // Kt[d][t]  (transposed)
    __shared__ float Vs[64][68];   // Vs[t][e]
    __shared__ float Ms[64][68];   // state: Ms[d][e]
    __shared__ float St[64][68];   // St[t][s]  (S transposed)
    __shared__ float KSs[64];

    // inline prefix: Ms = sum_{c'<c} KVC[c',h]
    {
        f32x4 macc[4] = {};
        for (int cp = 0; cp < c; ++cp) {
            const float* src = KVC + (size_t)(cp * NH + h) * 4096;
            #pragma unroll
            for (int it = 0; it < 4; ++it)
                macc[it] += *(const f32x4*)(src + (size_t)(tid + it * 256) * 4);
        }
        #pragma unroll
        for (int it = 0; it < 4; ++it) {
            int j = tid + it * 256;
            *(f32x4*)(&Ms[j >> 4][(j & 15) * 4]) = macc[it];
        }
        if (tid < 64) {
            float s = 0.0f;
            for (int cp = 0; cp < c; ++cp)
                s += KSC[(size_t)(cp * NH + h) * 64 + tid];
            KSs[tid] = s;
        }
    }
    #pragma unroll
    for (int it = 0; it < 4; ++it) {
        int j = tid + it * 256;                 // 0..1023
        int r = j >> 4, d0 = (j & 15) * 4;
        size_t g = (size_t)(c * CHUNK + r) * DM + h * 64 + d0;
        f32x4 q = *(const f32x4*)(Qb + g);
        f32x4 k = *(const f32x4*)(Kb + g);
        f32x4 v = *(const f32x4*)(Vb + g);
        Qt[d0 + 0][r] = q.x; Qt[d0 + 1][r] = q.y; Qt[d0 + 2][r] = q.z; Qt[d0 + 3][r] = q.w;
        Kt[d0 + 0][r] = k.x; Kt[d0 + 1][r] = k.y; Kt[d0 + 2][r] = k.z; Kt[d0 + 3][r] = k.w;
        *(f32x4*)(&Vs[r][d0]) = v;
    }
    __syncthreads();

    const int si = tid >> 4, ti = tid & 15;
    const int s0 = si * 4, t0 = ti * 4;         // t0 doubles as e0

    // ---- Phase A: inter-chunk O = Q @ State, den = Q . KSprefix ----
    f32x4 accO0 = {}, accO1 = {}, accO2 = {}, accO3 = {};
    f32x4 den = {};
    #pragma unroll 8
    for (int d = 0; d < 64; ++d) {
        f32x4 qv = *(const f32x4*)(&Qt[d][s0]);
        f32x4 mv = *(const f32x4*)(&Ms[d][t0]);
        float ks = KSs[d];
        fma4(accO0, qv.x, mv); fma4(accO1, qv.y, mv);
        fma4(accO2, qv.z, mv); fma4(accO3, qv.w, mv);
        fma4(den, ks, qv);
    }

    // ---- Phase B: S = Q K^T, causal, staged transposed ----
    f32x4 p0 = {}, p1 = {}, p2 = {}, p3 = {};   // p_r = S[s0+r][t0:t0+4]
    if (ti <= si) {
        #pragma unroll 8
        for (int d = 0; d < 64; ++d) {
            f32x4 qv = *(const f32x4*)(&Qt[d][s0]);
            f32x4 kv = *(const f32x4*)(&Kt[d][t0]);
            fma4(p0, qv.x, kv); fma4(p1, qv.y, kv);
            fma4(p2, qv.z, kv); fma4(p3, qv.w, kv);
        }
        if (ti == si) {                          // diagonal tile: keep t<=r
            p0.y = 0.0f; p0.z = 0.0f; p0.w = 0.0f;
            p1.z = 0.0f; p1.w = 0.0f;
            p2.w = 0.0f;
        }
    }
    St[t0 + 0][s0 + 0] = p0.x; St[t0 + 1][s0 + 0] = p0.y;
    St[t0 + 2][s0 + 0] = p0.z; St[t0 + 3][s0 + 0] = p0.w;
    St[t0 + 0][s0 + 1] = p1.x; St[t0 + 1][s0 + 1] = p1.y;
    St[t0 + 2][s0 + 1] = p1.z; St[t0 + 3][s0 + 1] = p1.w;
    St[t0 + 0][s0 + 2] = p2.x; St[t0 + 1][s0 + 2] = p2.y;
    St[t0 + 2][s0 + 2] = p2.z; St[t0 + 3][s0 + 2] = p2.w;
    St[t0 + 0][s0 + 3] = p3.x; St[t0 + 1][s0 + 3] = p3.y;
    St[t0 + 2][s0 + 3] = p3.z; St[t0 + 3][s0 + 3] = p3.w;
    __syncthreads();

    // ---- Phase C: O += S @ V ; den += rowsum(S) ----
    const int tmax = s0 + 4;                     // exclusive; St zero above diag
    #pragma unroll 4
    for (int t2 = 0; t2 < tmax; ++t2) {
        f32x4 sv = *(const f32x4*)(&St[t2][s0]);
        f32x4 vv = *(const f32x4*)(&Vs[t2][t0]);
        fma4(accO0, sv.x, vv); fma4(accO1, sv.y, vv);
        fma4(accO2, sv.z, vv); fma4(accO3, sv.w, vv);
        den += sv;
    }

    // ---- epilogue: z = 1/(den+eps), bf16 out ----
    short* op = Ab + (size_t)(c * CHUNK + s0) * DM + h * 64 + t0;
    {
        float z = 1.0f / (den.x + 1e-6f);
        short4 o; o.x = f2bf(accO0.x * z); o.y = f2bf(accO0.y * z);
        o.z = f2bf(accO0.z * z); o.w = f2bf(accO0.w * z);
        *reinterpret_cast<short4*>(op) = o;
    }
    {
        float z = 1.0f / (den.y + 1e-6f);
        short4 o; o.x = f2bf(accO1.x * z); o.y = f2bf(accO1.y * z);
        o.z = f2bf(accO1.z * z); o.w = f2bf(accO1.w * z);
        *reinterpret_cast<short4*>(op + DM) = o;
    }
    {
        float z = 1.0f / (den.z + 1e-6f);
        short4 o; o.x = f2bf(accO2.x * z); o.y = f2bf(accO2.y * z);
        o.z = f2bf(accO2.z * z); o.w = f2bf(accO2.w * z);
        *reinterpret_cast<short4*>(op + 2 * DM) = o;
    }
    {
        float z = 1.0f / (den.w + 1e-6f);
        short4 o; o.x = f2bf(accO3.x * z); o.y = f2bf(accO3.y * z);
        o.z = f2bf(accO3.z * z); o.w = f2bf(accO3.w * z);
        *reinterpret_cast<short4*>(op + 3 * DM) = o;
    }
}

// ---------------- layernorm: LN(X + X2? + resid?) -> O (+bf16 mirror) -------
__device__ __forceinline__ float block_reduce_sum(float v, float* smem)
{
    #pragma unroll
    for (int o = 32; o > 0; o >>= 1) v += __shfl_down(v, o, 64);
    int w = threadIdx.x >> 6;
    if ((threadIdx.x & 63) == 0) smem[w] = v;
    __syncthreads();
    v = smem[0] + smem[1] + smem[2] + smem[3];
    __syncthreads();
    return v;
}

__global__ __launch_bounds__(256) void ln_kernel(
    const float* __restrict__ X, const float* __restrict__ X2,
    const float* __restrict__ resid,
    const float* __restrict__ g, const float* __restrict__ b,
    float* __restrict__ O, short* __restrict__ Ob)
{
    __shared__ float red[4];
    const int row = blockIdx.x;
    const size_t base = (size_t)row * DM;
    const int t = threadIdx.x;
    float v0 = X[base + t], v1 = X[base + t + 256];
    if (X2)    { v0 += X2[base + t];    v1 += X2[base + t + 256]; }
    if (resid) { v0 += resid[base + t]; v1 += resid[base + t + 256]; }
    float mean = block_reduce_sum(v0 + v1, red) * (1.0f / 512.0f);
    float d0 = v0 - mean, d1 = v1 - mean;
    float var = block_reduce_sum(d0 * d0 + d1 * d1, red) * (1.0f / 512.0f);
    float rs = 1.0f / sqrtf(var + 1e-5f);
    float o0 = d0 * rs * g[t] + b[t];
    float o1 = d1 * rs * g[t + 256] + b[t + 256];
    O[base + t]       = o0;
    O[base + t + 256] = o1;
    if (Ob) {
        Ob[base + t]       = f2bf(o0);
        Ob[base + t + 256] = f2bf(o1);
    }
}

// ---------------- emotion head: [1024,512] @ [512,8] + b ----------------
__global__ __launch_bounds__(256) void proj_emo_kernel(
    const float* __restrict__ HF, const float* __restrict__ pw,
    const float* __restrict__ pb, float* __restrict__ out)
{
    __shared__ float pws[4096];
    for (int i = threadIdx.x; i < 4096; i += 256) pws[i] = pw[i];
    __syncthreads();
    int idx = blockIdx.x * 256 + threadIdx.x;
    int r = idx >> 3, e = idx & 7;
    float acc = pb[e];
    const float* h = HF + (size_t)r * DM;
    for (int d = 0; d < DM; d += 4) {
        f32x4 hv = *(const f32x4*)(h + d);
        acc += hv.x * pws[(d + 0) * 8 + e] + hv.y * pws[(d + 1) * 8 + e]
             + hv.z * pws[(d + 2) * 8 + e] + hv.w * pws[(d + 3) * 8 + e];
    }
    out[idx] = acc;
}

// ---------------------------------------------------------------------------
extern "C" void kernel_launch(void* const* d_in, const int* in_sizes, int n_in,
                              void* d_out, int out_size, void* d_ws, size_t ws_size,
                              hipStream_t stream)
{
    const int*   x    = (const int*)d_in[0];
    const float* e0   = (const float*)d_in[1];
    const float* e1   = (const float*)d_in[2];
    const float* e2   = (const float*)d_in[3];
    const float* e3   = (const float*)d_in[4];
    const float* e4   = (const float*)d_in[5];
    const float* e5   = (const float*)d_in[6];
    const float* in_w = (const float*)d_in[7];
    const float* in_b = (const float*)d_in[8];
    const float* wq   = (const float*)d_in[9];
    const float* bq   = (const float*)d_in[10];
    const float* wk   = (const float*)d_in[11];
    const float* bk   = (const float*)d_in[12];
    const float* wv   = (const float*)d_in[13];
    const float* bv   = (const float*)d_in[14];
    const float* wo   = (const float*)d_in[15];
    const float* bo   = (const float*)d_in[16];
    const float* g1   = (const float*)d_in[17];
    const float* be1  = (const float*)d_in[18];
    const float* w1   = (const float*)d_in[19];
    const float* b1   = (const float*)d_in[20];
    const float* w2   = (const float*)d_in[21];
    const float* b2   = (const float*)d_in[22];
    const float* g2   = (const float*)d_in[23];
    const float* be2  = (const float*)d_in[24];
    const float* gf   = (const float*)d_in[25];
    const float* bfin = (const float*)d_in[26];
    const float* pw   = (const float*)d_in[27];
    const float* pb   = (const float*)d_in[28];
    float* outp = (float*)d_out;

    // ---- workspace layout: Y,Y2 contiguous partial arena ----
    float* ws = (float*)d_ws;
    float* H    = ws;                  // 1024x512 f32
    float* Y    = ws + 524288;         // partial 0 (and pre-LN sum input)
    float* Y2   = ws + 1048576;        // partial 1 (contiguous with Y)
    float* Qb   = ws + 1572864;
    float* Kb   = ws + 2097152;
    float* Vb   = ws + 2621440;
    float* KVC  = ws + 3145728;        // 16*8*4096 = 524288
    float* KSC  = ws + 3670016;        // 8192 (ends 3678208)
    short* sb   = (short*)(ws + 3678208);
    short* Hb   = sb;                  // 1024x512
    short* Ab   = sb + 524288;         // 1024x512
    short* FFb  = sb + 1048576;        // 1024x2048
    short* EMBb = FFb;                 // 1024x768 (alias: dead before ffn1)
    // bf16 W^T arena [N][K]
    short* inT  = sb + 3145728;        // [512][768]
    short* qT   = inT + 393216;        // [12][512][512]
    short* kT   = qT + 3145728;
    short* vT   = kT + 3145728;
    short* oT   = vT + 3145728;
    short* w1T  = oT + 3145728;        // [12][2048][512]
    short* w2T  = w1T + 12582912;      // [12][512][2048]

    const dim3 blk256(256);

    // ---- weight transpose+convert ----
    transpose_w<<<dim3(8, 12, 1),  blk256, 0, stream>>>(in_w, inT, 768, DM);
    transpose_w<<<dim3(8, 8, 12),  blk256, 0, stream>>>(wq, qT, DM, DM);
    transpose_w<<<dim3(8, 8, 12),  blk256, 0, stream>>>(wk, kT, DM, DM);
    transpose_w<<<dim3(8, 8, 12),  blk256, 0, stream>>>(wv, vT, DM, DM);
    transpose_w<<<dim3(8, 8, 12),  blk256, 0, stream>>>(wo, oT, DM, DM);
    transpose_w<<<dim3(32, 8, 12), blk256, 0, stream>>>(w1, w1T, DM, DFF);
    transpose_w<<<dim3(8, 32, 12), blk256, 0, stream>>>(w2, w2T, DFF, DM);

    embed_kernel<<<S_LEN, blk256, 0, stream>>>(x, e0, e1, e2, e3, e4, e5, EMBb);
    // in-proj: EMBb @ in_w + in_b + PE -> H (f32) and Hb (bf16)
    gemm64<<<dim3(8, 16, 1), blk256, 0, stream>>>(EMBb, inT, in_b, nullptr,
                                                  H, Hb, DM, 768, ACT_NONE, 1, 1);

    for (int l = 0; l < NLAYER; ++l) {
        const short* qT_l = qT + (size_t)l * DM * DM;
        const short* kT_l = kT + (size_t)l * DM * DM;
        const short* vT_l = vT + (size_t)l * DM * DM;
        const short* oT_l = oT + (size_t)l * DM * DM;
        const short* w1T_l = w1T + (size_t)l * DM * DFF;
        const short* w2T_l = w2T + (size_t)l * DM * DFF;
        const float* bq_l = bq + l * DM;  const float* bk_l = bk + l * DM;
        const float* bv_l = bv + l * DM;  const float* bo_l = bo + l * DM;
        const float* b1_l = b1 + l * DFF; const float* b2_l = b2 + l * DM;

        qkv64<<<dim3(24, 16), blk256, 0, stream>>>(Hb, qT_l, kT_l, vT_l,
                                                   bq_l, bk_l, bv_l, Qb, Kb, Vb);

        chunk_stats_kernel<<<NCH * NH, blk256, 0, stream>>>(Kb, Vb, KVC, KSC);
        attn_out_kernel<<<NCH * NH, blk256, 0, stream>>>(Qb, Kb, Vb, KVC, KSC, Ab);

        // wo split-K z=2: partials Y (z0,+bias), Y2 (z1); LN(Y+Y2+H)
        gemm64<<<dim3(8, 16, 2), blk256, 0, stream>>>(Ab, oT_l, bo_l, nullptr,
                                                      Y, nullptr, DM, DM, ACT_NONE, 0, 2);
        ln_kernel<<<S_LEN, blk256, 0, stream>>>(Y, Y2, H,
                                                g1 + l * DM, be1 + l * DM, H, Hb);

        // ffn1: Hb @ w1 + b1, GELU -> FFb (bf16)
        gemm64<<<dim3(32, 16, 1), blk256, 0, stream>>>(Hb, w1T_l, b1_l, nullptr,
                                                       nullptr, FFb, DFF, DM, ACT_GELU, 0, 1);
        // ffn2 split-K z=2: partials Y (z0,+bias), Y2 (z1); LN(Y+Y2+H)
        gemm64<<<dim3(8, 16, 2), blk256, 0, stream>>>(FFb, w2T_l, b2_l, nullptr,
                                                      Y, nullptr, DM, DFF, ACT_NONE, 0, 2);
        ln_kernel<<<S_LEN, blk256, 0, stream>>>(Y, Y2, H,
                                                g2 + l * DM, be2 + l * DM, H, Hb);
    }

    // final norm -> d_out (f32 h), then emotion head
    ln_kernel<<<S_LEN, blk256, 0, stream>>>(H, nullptr, nullptr, gf, bfin, outp, nullptr);
    proj_emo_kernel<<<8192 / 256, blk256, 0, stream>>>(outp, pw, pb, outp + 524288);
}

// Round 7
// 1048.566 us; speedup vs baseline: 1.2318x; 1.0085x over previous
//
#include <hip/hip_runtime.h>
#include <hip/hip_bf16.h>
#include <math.h>

// ---------------------------------------------------------------------------
// TransformerModel: 12-layer causal linear-attention encoder.
// B=1, S=1024, D_MODEL=512, H=8, Dh=64, FF=2048. All tensors fp32 (x int32).
// Round 16 (base R15, 1057us): (1) T14 write-late reorder in gemm/qkv main
// loops -- compute(t) BEFORE ds_write(t+1), vmcnt wait moves after MFMAs,
// final barrier skipped; (2) ln_kernel64: wave-per-row LN, shuffle-only
// reduction, no barriers; (3) transpose4_w batches q/k/v/o weight transposes
// into one dispatch (grid.z=48). Attention / staging / epilogues unchanged.
// ---------------------------------------------------------------------------

#define S_LEN 1024
#define DM 512
#define NH 8
#define DH 64
#define DFF 2048
#define NLAYER 12
#define CHUNK 64
#define NCH (S_LEN / CHUNK)   // 16

#define ACT_NONE 0
#define ACT_PHI  1
#define ACT_GELU 2

typedef short s16x8 __attribute__((ext_vector_type(8)));
typedef float f32x4 __attribute__((ext_vector_type(4)));

__device__ __forceinline__ short f2bf(float x) {
    __hip_bfloat16 h = __float2bfloat16(x);
    return *reinterpret_cast<short*>(&h);
}

__device__ __forceinline__ void fma4(f32x4& a, float s, const f32x4 v) {
    a.x = fmaf(s, v.x, a.x); a.y = fmaf(s, v.y, a.y);
    a.z = fmaf(s, v.z, a.z); a.w = fmaf(s, v.w, a.w);
}

// LDS-only barrier: drains DS ops, leaves global->reg prefetch in flight.
__device__ __forceinline__ void tile_barrier() {
    asm volatile("s_waitcnt lgkmcnt(0)" ::: "memory");
    __builtin_amdgcn_s_barrier();
    asm volatile("" ::: "memory");
}

// ---------------- embedding gather (writes bf16) ----------------
__global__ __launch_bounds__(256) void embed_kernel(
    const int* __restrict__ x,
    const float* __restrict__ t0, const float* __restrict__ t1,
    const float* __restrict__ t2, const float* __restrict__ t3,
    const float* __restrict__ t4, const float* __restrict__ t5,
    short* __restrict__ EMBb)
{
    int s = blockIdx.x;
    __shared__ int xi[6];
    if (threadIdx.x < 6) xi[threadIdx.x] = x[s * 6 + threadIdx.x];
    __syncthreads();
    for (int j = threadIdx.x; j < 768; j += 256) {
        int i, off, width; const float* t; float sc;
        if (j < 32)       { i = 0; off = 0;   t = t0; sc = 5.656854249f;  width = 32;  }
        else if (j < 160) { i = 1; off = 32;  t = t1; sc = 11.3137085f;   width = 128; }
        else if (j < 416) { i = 2; off = 160; t = t2; sc = 16.0f;         width = 256; }
        else if (j < 672) { i = 3; off = 416; t = t3; sc = 16.0f;         width = 256; }
        else if (j < 704) { i = 4; off = 672; t = t4; sc = 5.656854249f;  width = 32;  }
        else              { i = 5; off = 704; t = t5; sc = 8.0f;          width = 64;  }
        EMBb[s * 768 + j] = f2bf(t[xi[i] * width + (j - off)] * sc);
    }
}

// ---------------- weight transpose+convert: f32 [B][K][N] -> bf16 [B][N][K] ----
__global__ __launch_bounds__(256) void transpose_w(
    const float* __restrict__ in, short* __restrict__ out, int K, int N)
{
    __shared__ short t[64][66];
    const int b = blockIdx.z;
    const int n0 = blockIdx.x * 64, k0 = blockIdx.y * 64;
    const float* ip = in + (size_t)b * K * N;
    short* op = out + (size_t)b * K * N;
    const int c = threadIdx.x & 63, r0 = (threadIdx.x >> 6) * 16;
    #pragma unroll
    for (int i = 0; i < 16; ++i)
        t[c][r0 + i] = f2bf(ip[(size_t)(k0 + r0 + i) * N + n0 + c]);
    __syncthreads();
    #pragma unroll
    for (int i = 0; i < 16; ++i)
        op[(size_t)(n0 + r0 + i) * K + k0 + c] = t[r0 + i][c];
}

// Batched 512x512x12 transpose for wq/wk/wv/wo: grid (8,8,48), z -> (which, layer)
__global__ __launch_bounds__(256) void transpose4_w(
    const float* __restrict__ wA, const float* __restrict__ wB,
    const float* __restrict__ wC, const float* __restrict__ wD,
    short* __restrict__ oA, short* __restrict__ oB,
    short* __restrict__ oC, short* __restrict__ oD)
{
    __shared__ short t[64][66];
    const int zz = blockIdx.z;
    const int which = zz & 3, b = zz >> 2;
    const float* in = (which == 0) ? wA : (which == 1) ? wB : (which == 2) ? wC : wD;
    short* out      = (which == 0) ? oA : (which == 1) ? oB : (which == 2) ? oC : oD;
    const int n0 = blockIdx.x * 64, k0 = blockIdx.y * 64;
    const float* ip = in + (size_t)b * DM * DM;
    short* op = out + (size_t)b * DM * DM;
    const int c = threadIdx.x & 63, r0 = (threadIdx.x >> 6) * 16;
    #pragma unroll
    for (int i = 0; i < 16; ++i)
        t[c][r0 + i] = f2bf(ip[(size_t)(k0 + r0 + i) * DM + n0 + c]);
    __syncthreads();
    #pragma unroll
    for (int i = 0; i < 16; ++i)
        op[(size_t)(n0 + r0 + i) * DM + k0 + c] = t[r0 + i][c];
}

// ---------------- activation ----------------
__device__ __forceinline__ float apply_act(float v, int act) {
    if (act == ACT_PHI)       return (v > 0.0f) ? (v + 1.0f) : expf(v);
    else if (act == ACT_GELU) return 0.5f * v * (1.0f + erff(v * 0.70710678118654752f));
    return v;
}

// ---------------- 64x64-tile MFMA GEMM core ------------------
// LDS tile: [64 rows][64 k] bf16 = 8KB, double-buffered for A and B (32KB).
// Bank swizzle: byte col ^= (row&7)<<4 on BOTH ds_write and ds_read.

__device__ __forceinline__ void ldswr64(short* lds, int srow, int scolb,
                                        const s16x8 r[2])
{
    const int bc = scolb ^ ((srow & 7) << 4);
    #pragma unroll
    for (int p = 0; p < 2; ++p)
        *(s16x8*)((char*)lds + (p * 32 + srow) * 128 + bc) = r[p];
}

__device__ __forceinline__ void compute64(
    const short* __restrict__ As, const short* __restrict__ Bs,
    int wr, int wc, int l15, int q, f32x4 acc[2][2])
{
    #pragma unroll
    for (int kh = 0; kh < 2; ++kh) {
        const int kb = kh * 64 + q * 16;
        s16x8 a[2], b[2];
        #pragma unroll
        for (int m = 0; m < 2; ++m) {
            int row = wr * 32 + m * 16 + l15;
            a[m] = *(const s16x8*)((const char*)As + row * 128 + (kb ^ ((row & 7) << 4)));
        }
        #pragma unroll
        for (int n = 0; n < 2; ++n) {
            int row = wc * 32 + n * 16 + l15;
            b[n] = *(const s16x8*)((const char*)Bs + row * 128 + (kb ^ ((row & 7) << 4)));
        }
        #pragma unroll
        for (int m = 0; m < 2; ++m)
            #pragma unroll
            for (int n = 0; n < 2; ++n)
                acc[m][n] = __builtin_amdgcn_mfma_f32_16x16x32_bf16(
                    a[m], b[n], acc[m][n], 0, 0, 0);
    }
}

// ---------------- generic GEMM: C[1024][N] = A[1024][K] @ BT[N][K]^T -------
// zparts>1: block z covers K-slice; partial -> Cf + z*1024*N; bias in z==0.
__global__ __launch_bounds__(256) void gemm64(
    const short* __restrict__ A, const short* __restrict__ BT,
    const float* __restrict__ bias, const float* __restrict__ resid,
    float* __restrict__ Cf, short* __restrict__ Cbf,
    int N, int K, int act, int add_pe, int zparts)
{
    __shared__ short As[2][4096];
    __shared__ short Bs[2][4096];
    const int tid = threadIdx.x;
    const int row0 = blockIdx.y * 64, col0 = blockIdx.x * 64;
    const int z = blockIdx.z;
    const int Kz = K / zparts;
    const int kbase = z * Kz;
    const int w = tid >> 6, lane = tid & 63, q = lane >> 4, l15 = lane & 15;
    const int wr = w >> 1, wc = w & 1;
    const int nt = Kz >> 6;

    const int srow = tid >> 3;              // 0..31
    const int scolb = (tid & 7) * 16;       // 0..112 bytes
    const char* gA = (const char*)(A  + (size_t)(row0 + srow) * K + kbase) + scolb;
    const char* gB = (const char*)(BT + (size_t)(col0 + srow) * K + kbase) + scolb;
    const size_t rstep = (size_t)32 * K * 2;   // +32 rows, bytes

    s16x8 ra[2], rb[2];
    #pragma unroll
    for (int p = 0; p < 2; ++p) {
        ra[p] = *(const s16x8*)(gA + p * rstep);
        rb[p] = *(const s16x8*)(gB + p * rstep);
    }
    ldswr64(As[0], srow, scolb, ra);
    ldswr64(Bs[0], srow, scolb, rb);
    if (nt > 1) {
        #pragma unroll
        for (int p = 0; p < 2; ++p) {
            ra[p] = *(const s16x8*)(gA + p * rstep + 128);
            rb[p] = *(const s16x8*)(gB + p * rstep + 128);
        }
    }
    tile_barrier();

    f32x4 acc[2][2] = {};
    int cur = 0;
    for (int t = 0; t < nt; ++t) {
        // T14 write-late: MFMAs first (no vmcnt dependency), then the
        // ds_write (waits vmcnt for t+1 loads), then prefetch t+2.
        compute64(As[cur], Bs[cur], wr, wc, l15, q, acc);
        if (t + 1 < nt) {
            ldswr64(As[cur ^ 1], srow, scolb, ra);
            ldswr64(Bs[cur ^ 1], srow, scolb, rb);
            if (t + 2 < nt) {
                size_t ko = (size_t)(t + 2) * 128;
                #pragma unroll
                for (int p = 0; p < 2; ++p) {
                    ra[p] = *(const s16x8*)(gA + p * rstep + ko);
                    rb[p] = *(const s16x8*)(gB + p * rstep + ko);
                }
            }
            tile_barrier();
        }
        cur ^= 1;
    }

    if (zparts > 1 && Cf) Cf += (size_t)z * S_LEN * N;

    const int rbase = row0 + wr * 32 + q * 4;
    const int cbase = col0 + wc * 32 + l15;
    #pragma unroll
    for (int n = 0; n < 2; ++n) {
        int c = cbase + n * 16;
        float bia = (z == 0) ? bias[c] : 0.0f;
        #pragma unroll
        for (int m = 0; m < 2; ++m) {
            #pragma unroll
            for (int rg = 0; rg < 4; ++rg) {
                int r = rbase + m * 16 + rg;
                float v = apply_act(acc[m][n][rg] + bia, act);
                if (resid) v += resid[(size_t)r * N + c];
                if (add_pe) {
                    float freq = expf((float)(c & ~1) * (-9.210340371976184f / 512.0f));
                    float ang = (float)r * freq;
                    v += (c & 1) ? cosf(ang) : sinf(ang);
                }
                if (Cf)  Cf[(size_t)r * N + c] = v;
                if (Cbf) Cbf[(size_t)r * N + c] = f2bf(v);
            }
        }
    }
}

// ---------------- fused QKV: grid (24, 16); phi on Q,K ----------------
__global__ __launch_bounds__(256) void qkv64(
    const short* __restrict__ Hb,
    const short* __restrict__ qT, const short* __restrict__ kT, const short* __restrict__ vT,
    const float* __restrict__ bq, const float* __restrict__ bk, const float* __restrict__ bv,
    float* __restrict__ Qb, float* __restrict__ Kb, float* __restrict__ Vb)
{
    __shared__ short As[2][4096];
    __shared__ short Bs[2][4096];
    const int sel  = blockIdx.x >> 3;              // 0=Q 1=K 2=V
    const int col0 = (blockIdx.x & 7) * 64;
    const int row0 = blockIdx.y * 64;
    const short* BT   = (sel == 0) ? qT : (sel == 1) ? kT : vT;
    const float* bias = (sel == 0) ? bq : (sel == 1) ? bk : bv;
    float* C          = (sel == 0) ? Qb : (sel == 1) ? Kb : Vb;
    const bool phi = (sel < 2);

    const int tid = threadIdx.x;
    const int w = tid >> 6, lane = tid & 63, q = lane >> 4, l15 = lane & 15;
    const int wr = w >> 1, wc = w & 1;

    const int srow = tid >> 3;
    const int scolb = (tid & 7) * 16;
    const char* gA = (const char*)(Hb + (size_t)(row0 + srow) * DM) + scolb;
    const char* gB = (const char*)(BT + (size_t)(col0 + srow) * DM) + scolb;
    const size_t rstep = (size_t)32 * DM * 2;

    s16x8 ra[2], rb[2];
    #pragma unroll
    for (int p = 0; p < 2; ++p) {
        ra[p] = *(const s16x8*)(gA + p * rstep);
        rb[p] = *(const s16x8*)(gB + p * rstep);
    }
    ldswr64(As[0], srow, scolb, ra);
    ldswr64(Bs[0], srow, scolb, rb);
    #pragma unroll
    for (int p = 0; p < 2; ++p) {
        ra[p] = *(const s16x8*)(gA + p * rstep + 128);
        rb[p] = *(const s16x8*)(gB + p * rstep + 128);
    }
    tile_barrier();

    f32x4 acc[2][2] = {};
    int cur = 0;
    for (int t = 0; t < 8; ++t) {                  // K = 512 -> 8 tiles
        compute64(As[cur], Bs[cur], wr, wc, l15, q, acc);
        if (t + 1 < 8) {
            ldswr64(As[cur ^ 1], srow, scolb, ra);
            ldswr64(Bs[cur ^ 1], srow, scolb, rb);
            if (t + 2 < 8) {
                size_t ko = (size_t)(t + 2) * 128;
                #pragma unroll
                for (int p = 0; p < 2; ++p) {
                    ra[p] = *(const s16x8*)(gA + p * rstep + ko);
                    rb[p] = *(const s16x8*)(gB + p * rstep + ko);
                }
            }
            tile_barrier();
        }
        cur ^= 1;
    }

    const int rbase = row0 + wr * 32 + q * 4;
    const int cbase = col0 + wc * 32 + l15;
    #pragma unroll
    for (int n = 0; n < 2; ++n) {
        int c = cbase + n * 16;
        float bia = bias[c];
        #pragma unroll
        for (int m = 0; m < 2; ++m) {
            #pragma unroll
            for (int rg = 0; rg < 4; ++rg) {
                int r = rbase + m * 16 + rg;
                float v = acc[m][n][rg] + bia;
                if (phi) v = (v > 0.0f) ? (v + 1.0f) : expf(v);
                C[(size_t)r * DM + c] = v;
            }
        }
    }
}

// ---------------- chunk stats: per (head, chunk) KV_c = K_c^T V_c, ksum_c ----
__global__ __launch_bounds__(256) void chunk_stats_kernel(
    const float* __restrict__ Kb, const float* __restrict__ Vb,
    float* __restrict__ KVC, float* __restrict__ KSC)
{
    const int h = blockIdx.x >> 4, c = blockIdx.x & 15;
    const int tid = threadIdx.x;
    __shared__ float Ks[64][68];
    __shared__ float Vs[64][68];
    #pragma unroll
    for (int it = 0; it < 4; ++it) {
        int j = tid + it * 256;                 // 0..1023 f32x4 slots
        int r = j >> 4, d0 = (j & 15) * 4;
        size_t g = (size_t)(c * CHUNK + r) * DM + h * 64 + d0;
        *(f32x4*)(&Ks[r][d0]) = *(const f32x4*)(Kb + g);
        *(f32x4*)(&Vs[r][d0]) = *(const f32x4*)(Vb + g);
    }
    __syncthreads();
    const int di = (tid >> 4) * 4, ei = (tid & 15) * 4;
    f32x4 a0 = {}, a1 = {}, a2 = {}, a3 = {}, ks = {};
    #pragma unroll 8
    for (int t = 0; t < 64; ++t) {
        f32x4 kk = *(const f32x4*)(&Ks[t][di]);
        f32x4 vv = *(const f32x4*)(&Vs[t][ei]);
        fma4(a0, kk.x, vv); fma4(a1, kk.y, vv);
        fma4(a2, kk.z, vv); fma4(a3, kk.w, vv);
        ks += kk;
    }
    float* out = KVC + (size_t)(c * NH + h) * 4096;   // [d][e] row-major
    *(f32x4*)(out + (size_t)(di + 0) * 64 + ei) = a0;
    *(f32x4*)(out + (size_t)(di + 1) * 64 + ei) = a1;
    *(f32x4*)(out + (size_t)(di + 2) * 64 + ei) = a2;
    *(f32x4*)(out + (size_t)(di + 3) * 64 + ei) = a3;
    if ((tid & 15) == 0)
        *(f32x4*)(KSC + (size_t)(c * NH + h) * 64 + di) = ks;
}

// ---------------- attention output per (head, chunk) ----------------
// Inline exclusive prefix over per-chunk states (KVC/KSC per-chunk).
__global__ __launch_bounds__(256) void attn_out_kernel(
    const float* __restrict__ Qb, const float* __restrict__ Kb,
    const float* __restrict__ Vb, const float* __restrict__ KVC,
    const float* __restrict__ KSC, short* __restrict__ Ab)
{
    const int h = blockIdx.x >> 4, c = blockIdx.x & 15;
    const int tid = threadIdx.x;
    __shared__ float Qt[64][68];   // Qt[d][s]  (transposed)
    __shared__ float Kt[64][68];   // Kt[d][t]  (transposed)
    __shared__ float Vs[64][68];   // Vs[t][e]
    __shared__ float Ms[64][68];   // state: Ms[d][e]
    __shared__ float St[64][68];   // St[t][s]  (S transposed)
    __shared__ float KSs[64];

    // inline prefix: Ms = sum_{c'<c} KVC[c',h]
    {
        f32x4 macc[4] = {};
        for (int cp = 0; cp < c; ++cp) {
            const float* src = KVC + (size_t)(cp * NH + h) * 4096;
            #pragma unroll
            for (int it = 0; it < 4; ++it)
                macc[it] += *(const f32x4*)(src + (size_t)(tid + it * 256) * 4);
        }
        #pragma unroll
        for (int it = 0; it < 4; ++it) {
            int j = tid + it * 256;
            *(f32x4*)(&Ms[j >> 4][(j & 15) * 4]) = macc[it];
        }
        if (tid < 64) {
            float s = 0.0f;
            for (int cp = 0; cp < c; ++cp)
                s += KSC[(size_t)(cp * NH + h) * 64 + tid];
            KSs[tid] = s;
        }
    }
    #pragma unroll
    for (int it = 0; it < 4; ++it) {
        int j = tid + it * 256;                 // 0..1023
        int r = j >> 4, d0 = (j & 15) * 4;
        size_t g = (size_t)(c * CHUNK + r) * DM + h * 64 + d0;
        f32x4 q = *(const f32x4*)(Qb + g);
        f32x4 k = *(const f32x4*)(Kb + g);
        f32x4 v = *(const f32x4*)(Vb + g);
        Qt[d0 + 0][r] = q.x; Qt[d0 + 1][r] = q.y; Qt[d0 + 2][r] = q.z; Qt[d0 + 3][r] = q.w;
        Kt[d0 + 0][r] = k.x; Kt[d0 + 1][r] = k.y; Kt[d0 + 2][r] = k.z; Kt[d0 + 3][r] = k.w;
        *(f32x4*)(&Vs[r][d0]) = v;
    }
    __syncthreads();

    const int si = tid >> 4, ti = tid & 15;
    const int s0 = si * 4, t0 = ti * 4;         // t0 doubles as e0

    // ---- Phase A: inter-chunk O = Q @ State, den = Q . KSprefix ----
    f32x4 accO0 = {}, accO1 = {}, accO2 = {}, accO3 = {};
    f32x4 den = {};
    #pragma unroll 8
    for (int d = 0; d < 64; ++d) {
        f32x4 qv = *(const f32x4*)(&Qt[d][s0]);
        f32x4 mv = *(const f32x4*)(&Ms[d][t0]);
        float ks = KSs[d];
        fma4(accO0, qv.x, mv); fma4(accO1, qv.y, mv);
        fma4(accO2, qv.z, mv); fma4(accO3, qv.w, mv);
        fma4(den, ks, qv);
    }

    // ---- Phase B: S = Q K^T, causal, staged transposed ----
    f32x4 p0 = {}, p1 = {}, p2 = {}, p3 = {};   // p_r = S[s0+r][t0:t0+4]
    if (ti <= si) {
        #pragma unroll 8
        for (int d = 0; d < 64; ++d) {
            f32x4 qv = *(const f32x4*)(&Qt[d][s0]);
            f32x4 kv = *(const f32x4*)(&Kt[d][t0]);
            fma4(p0, qv.x, kv); fma4(p1, qv.y, kv);
            fma4(p2, qv.z, kv); fma4(p3, qv.w, kv);
        }
        if (ti == si) {                          // diagonal tile: keep t<=r
            p0.y = 0.0f; p0.z = 0.0f; p0.w = 0.0f;
            p1.z = 0.0f; p1.w = 0.0f;
            p2.w = 0.0f;
        }
    }
    St[t0 + 0][s0 + 0] = p0.x; St[t0 + 1][s0 + 0] = p0.y;
    St[t0 + 2][s0 + 0] = p0.z; St[t0 + 3][s0 + 0] = p0.w;
    St[t0 + 0][s0 + 1] = p1.x; St[t0 + 1][s0 + 1] = p1.y;
    St[t0 + 2][s0 + 1] = p1.z; St[t0 + 3][s0 + 1] = p1.w;
    St[t0 + 0][s0 + 2] = p2.x; St[t0 + 1][s0 + 2] = p2.y;
    St[t0 + 2][s0 + 2] = p2.z; St[t0 + 3][s0 + 2] = p2.w;
    St[t0 + 0][s0 + 3] = p3.x; St[t0 + 1][s0 + 3] = p3.y;
    St[t0 + 2][s0 + 3] = p3.z; St[t0 + 3][s0 + 3] = p3.w;
    __syncthreads();

    // ---- Phase C: O += S @ V ; den += rowsum(S) ----
    const int tmax = s0 + 4;                     // exclusive; St zero above diag
    #pragma unroll 4
    for (int t2 = 0; t2 < tmax; ++t2) {
        f32x4 sv = *(const f32x4*)(&St[t2][s0]);
        f32x4 vv = *(const f32x4*)(&Vs[t2][t0]);
        fma4(accO0, sv.x, vv); fma4(accO1, sv.y, vv);
        fma4(accO2, sv.z, vv); fma4(accO3, sv.w, vv);
        den += sv;
    }

    // ---- epilogue: z = 1/(den+eps), bf16 out ----
    short* op = Ab + (size_t)(c * CHUNK + s0) * DM + h * 64 + t0;
    {
        float z = 1.0f / (den.x + 1e-6f);
        short4 o; o.x = f2bf(accO0.x * z); o.y = f2bf(accO0.y * z);
        o.z = f2bf(accO0.z * z); o.w = f2bf(accO0.w * z);
        *reinterpret_cast<short4*>(op) = o;
    }
    {
        float z = 1.0f / (den.y + 1e-6f);
        short4 o; o.x = f2bf(accO1.x * z); o.y = f2bf(accO1.y * z);
        o.z = f2bf(accO1.z * z); o.w = f2bf(accO1.w * z);
        *reinterpret_cast<short4*>(op + DM) = o;
    }
    {
        float z = 1.0f / (den.z + 1e-6f);
        short4 o; o.x = f2bf(accO2.x * z); o.y = f2bf(accO2.y * z);
        o.z = f2bf(accO2.z * z); o.w = f2bf(accO2.w * z);
        *reinterpret_cast<short4*>(op + 2 * DM) = o;
    }
    {
        float z = 1.0f / (den.w + 1e-6f);
        short4 o; o.x = f2bf(accO3.x * z); o.y = f2bf(accO3.y * z);
        o.z = f2bf(accO3.z * z); o.w = f2bf(accO3.w * z);
        *reinterpret_cast<short4*>(op + 3 * DM) = o;
    }
}

// ---------------- wave-per-row layernorm: LN(X + X2? + resid?) --------------
// 1024 blocks x 64 threads; butterfly shuffle reductions, no LDS/barriers.
__global__ __launch_bounds__(64) void ln_kernel64(
    const float* __restrict__ X, const float* __restrict__ X2,
    const float* __restrict__ resid,
    const float* __restrict__ g, const float* __restrict__ b,
    float* __restrict__ O, short* __restrict__ Ob)
{
    const int row = blockIdx.x;
    const size_t base = (size_t)row * DM;
    const int t = threadIdx.x;
    const int i0 = 4 * t, i1 = 256 + 4 * t;
    f32x4 v0 = *(const f32x4*)(X + base + i0);
    f32x4 v1 = *(const f32x4*)(X + base + i1);
    if (X2) {
        v0 += *(const f32x4*)(X2 + base + i0);
        v1 += *(const f32x4*)(X2 + base + i1);
    }
    if (resid) {
        v0 += *(const f32x4*)(resid + base + i0);
        v1 += *(const f32x4*)(resid + base + i1);
    }
    float s = v0.x + v0.y + v0.z + v0.w + v1.x + v1.y + v1.z + v1.w;
    #pragma unroll
    for (int m = 1; m < 64; m <<= 1) s += __shfl_xor(s, m, 64);
    float mean = s * (1.0f / 512.0f);
    f32x4 d0 = v0 - mean, d1 = v1 - mean;
    float ss = d0.x * d0.x + d0.y * d0.y + d0.z * d0.z + d0.w * d0.w
             + d1.x * d1.x + d1.y * d1.y + d1.z * d1.z + d1.w * d1.w;
    #pragma unroll
    for (int m = 1; m < 64; m <<= 1) ss += __shfl_xor(ss, m, 64);
    float var = ss * (1.0f / 512.0f);
    float rs = 1.0f / sqrtf(var + 1e-5f);
    f32x4 g0 = *(const f32x4*)(g + i0), g1v = *(const f32x4*)(g + i1);
    f32x4 b0 = *(const f32x4*)(b + i0), b1v = *(const f32x4*)(b + i1);
    f32x4 o0 = d0 * rs * g0 + b0;
    f32x4 o1 = d1 * rs * g1v + b1v;
    *(f32x4*)(O + base + i0) = o0;
    *(f32x4*)(O + base + i1) = o1;
    if (Ob) {
        short4 s0; s0.x = f2bf(o0.x); s0.y = f2bf(o0.y); s0.z = f2bf(o0.z); s0.w = f2bf(o0.w);
        short4 s1; s1.x = f2bf(o1.x); s1.y = f2bf(o1.y); s1.z = f2bf(o1.z); s1.w = f2bf(o1.w);
        *reinterpret_cast<short4*>(Ob + base + i0) = s0;
        *reinterpret_cast<short4*>(Ob + base + i1) = s1;
    }
}

// ---------------- emotion head: [1024,512] @ [512,8] + b ----------------
__global__ __launch_bounds__(256) void proj_emo_kernel(
    const float* __restrict__ HF, const float* __restrict__ pw,
    const float* __restrict__ pb, float* __restrict__ out)
{
    __shared__ float pws[4096];
    for (int i = threadIdx.x; i < 4096; i += 256) pws[i] = pw[i];
    __syncthreads();
    int idx = blockIdx.x * 256 + threadIdx.x;
    int r = idx >> 3, e = idx & 7;
    float acc = pb[e];
    const float* h = HF + (size_t)r * DM;
    for (int d = 0; d < DM; d += 4) {
        f32x4 hv = *(const f32x4*)(h + d);
        acc += hv.x * pws[(d + 0) * 8 + e] + hv.y * pws[(d + 1) * 8 + e]
             + hv.z * pws[(d + 2) * 8 + e] + hv.w * pws[(d + 3) * 8 + e];
    }
    out[idx] = acc;
}

// ---------------------------------------------------------------------------
extern "C" void kernel_launch(void* const* d_in, const int* in_sizes, int n_in,
                              void* d_out, int out_size, void* d_ws, size_t ws_size,
                              hipStream_t stream)
{
    const int*   x    = (const int*)d_in[0];
    const float* e0   = (const float*)d_in[1];
    const float* e1   = (const float*)d_in[2];
    const float* e2   = (const float*)d_in[3];
    const float* e3   = (const float*)d_in[4];
    const float* e4   = (const float*)d_in[5];
    const float* e5   = (const float*)d_in[6];
    const float* in_w = (const float*)d_in[7];
    const float* in_b = (const float*)d_in[8];
    const float* wq   = (const float*)d_in[9];
    const float* bq   = (const float*)d_in[10];
    const float* wk   = (const float*)d_in[11];
    const float* bk   = (const float*)d_in[12];
    const float* wv   = (const float*)d_in[13];
    const float* bv   = (const float*)d_in[14];
    const float* wo   = (const float*)d_in[15];
    const float* bo   = (const float*)d_in[16];
    const float* g1   = (const float*)d_in[17];
    const float* be1  = (const float*)d_in[18];
    const float* w1   = (const float*)d_in[19];
    const float* b1   = (const float*)d_in[20];
    const float* w2   = (const float*)d_in[21];
    const float* b2   = (const float*)d_in[22];
    const float* g2   = (const float*)d_in[23];
    const float* be2  = (const float*)d_in[24];
    const float* gf   = (const float*)d_in[25];
    const float* bfin = (const float*)d_in[26];
    const float* pw   = (const float*)d_in[27];
    const float* pb   = (const float*)d_in[28];
    float* outp = (float*)d_out;

    // ---- workspace layout: Y,Y2 contiguous partial arena ----
    float* ws = (float*)d_ws;
    float* H    = ws;                  // 1024x512 f32
    float* Y    = ws + 524288;         // partial 0 (and pre-LN sum input)
    float* Y2   = ws + 1048576;        // partial 1 (contiguous with Y)
    float* Qb   = ws + 1572864;
    float* Kb   = ws + 2097152;
    float* Vb   = ws + 2621440;
    float* KVC  = ws + 3145728;        // 16*8*4096 = 524288
    float* KSC  = ws + 3670016;        // 8192 (ends 3678208)
    short* sb   = (short*)(ws + 3678208);
    short* Hb   = sb;                  // 1024x512
    short* Ab   = sb + 524288;         // 1024x512
    short* FFb  = sb + 1048576;        // 1024x2048
    short* EMBb = FFb;                 // 1024x768 (alias: dead before ffn1)
    // bf16 W^T arena [N][K]
    short* inT  = sb + 3145728;        // [512][768]
    short* qT   = inT + 393216;        // [12][512][512]
    short* kT   = qT + 3145728;
    short* vT   = kT + 3145728;
    short* oT   = vT + 3145728;
    short* w1T  = oT + 3145728;        // [12][2048][512]
    short* w2T  = w1T + 12582912;      // [12][512][2048]

    const dim3 blk256(256), blk64(64);

    // ---- weight transpose+convert ----
    transpose_w<<<dim3(8, 12, 1),  blk256, 0, stream>>>(in_w, inT, 768, DM);
    transpose4_w<<<dim3(8, 8, 48), blk256, 0, stream>>>(wq, wk, wv, wo,
                                                        qT, kT, vT, oT);
    transpose_w<<<dim3(32, 8, 12), blk256, 0, stream>>>(w1, w1T, DM, DFF);
    transpose_w<<<dim3(8, 32, 12), blk256, 0, stream>>>(w2, w2T, DFF, DM);

    embed_kernel<<<S_LEN, blk256, 0, stream>>>(x, e0, e1, e2, e3, e4, e5, EMBb);
    // in-proj: EMBb @ in_w + in_b + PE -> H (f32) and Hb (bf16)
    gemm64<<<dim3(8, 16, 1), blk256, 0, stream>>>(EMBb, inT, in_b, nullptr,
                                                  H, Hb, DM, 768, ACT_NONE, 1, 1);

    for (int l = 0; l < NLAYER; ++l) {
        const short* qT_l = qT + (size_t)l * DM * DM;
        const short* kT_l = kT + (size_t)l * DM * DM;
        const short* vT_l = vT + (size_t)l * DM * DM;
        const short* oT_l = oT + (size_t)l * DM * DM;
        const short* w1T_l = w1T + (size_t)l * DM * DFF;
        const short* w2T_l = w2T + (size_t)l * DM * DFF;
        const float* bq_l = bq + l * DM;  const float* bk_l = bk + l * DM;
        const float* bv_l = bv + l * DM;  const float* bo_l = bo + l * DM;
        const float* b1_l = b1 + l * DFF; const float* b2_l = b2 + l * DM;

        qkv64<<<dim3(24, 16), blk256, 0, stream>>>(Hb, qT_l, kT_l, vT_l,
                                                   bq_l, bk_l, bv_l, Qb, Kb, Vb);

        chunk_stats_kernel<<<NCH * NH, blk256, 0, stream>>>(Kb, Vb, KVC, KSC);
        attn_out_kernel<<<NCH * NH, blk256, 0, stream>>>(Qb, Kb, Vb, KVC, KSC, Ab);

        // wo split-K z=2: partials Y (z0,+bias), Y2 (z1); LN(Y+Y2+H)
        gemm64<<<dim3(8, 16, 2), blk256, 0, stream>>>(Ab, oT_l, bo_l, nullptr,
                                                      Y, nullptr, DM, DM, ACT_NONE, 0, 2);
        ln_kernel64<<<S_LEN, blk64, 0, stream>>>(Y, Y2, H,
                                                 g1 + l * DM, be1 + l * DM, H, Hb);

        // ffn1: Hb @ w1 + b1, GELU -> FFb (bf16)
        gemm64<<<dim3(32, 16, 1), blk256, 0, stream>>>(Hb, w1T_l, b1_l, nullptr,
                                                       nullptr, FFb, DFF, DM, ACT_GELU, 0, 1);
        // ffn2 split-K z=2: partials Y (z0,+bias), Y2 (z1); LN(Y+Y2+H)
        gemm64<<<dim3(8, 16, 2), blk256, 0, stream>>>(FFb, w2T_l, b2_l, nullptr,
                                                      Y, nullptr, DM, DFF, ACT_NONE, 0, 2);
        ln_kernel64<<<S_LEN, blk64, 0, stream>>>(Y, Y2, H,
                                                 g2 + l * DM, be2 + l * DM, H, Hb);
    }

    // final norm -> d_out (f32 h), then emotion head
    ln_kernel64<<<S_LEN, blk64, 0, stream>>>(H, nullptr, nullptr, gf, bfin, outp, nullptr);
    proj_emo_kernel<<<8192 / 256, blk256, 0, stream>>>(outp, pw, pb, outp + 524288);
}

// Round 8
// 1014.932 us; speedup vs baseline: 1.2726x; 1.0331x over previous
//
#include <hip/hip_runtime.h>
#include <hip/hip_bf16.h>
#include <math.h>

// ---------------------------------------------------------------------------
// TransformerModel: 12-layer causal linear-attention encoder.
// B=1, S=1024, D_MODEL=512, H=8, Dh=64, FF=2048. All tensors fp32 (x int32).
// Round 17 (base R16, 1048us): dispatch-count attack.
// (1) qkv_fused: grid(16,16); x<8 = Q tile; x>=8 = KV block computing K and V
//     tiles for (chunk,head) with shared-A K-loop (6 LDS reads : 16 MFMA),
//     then in-block chunk stats (KVC/KSC) from LDS -- chunk_stats dispatch
//     deleted (-12 dispatches, -2MB/layer re-reads).
// (2) ln_final_proj: final LN + emotion head in one 1024x64 kernel.
// gemm64 / attn_out / ln_kernel64 / transposes / embed unchanged.
// ---------------------------------------------------------------------------

#define S_LEN 1024
#define DM 512
#define NH 8
#define DH 64
#define DFF 2048
#define NLAYER 12
#define CHUNK 64
#define NCH (S_LEN / CHUNK)   // 16

#define ACT_NONE 0
#define ACT_PHI  1
#define ACT_GELU 2

typedef short s16x8 __attribute__((ext_vector_type(8)));
typedef float f32x4 __attribute__((ext_vector_type(4)));

__device__ __forceinline__ short f2bf(float x) {
    __hip_bfloat16 h = __float2bfloat16(x);
    return *reinterpret_cast<short*>(&h);
}

__device__ __forceinline__ void fma4(f32x4& a, float s, const f32x4 v) {
    a.x = fmaf(s, v.x, a.x); a.y = fmaf(s, v.y, a.y);
    a.z = fmaf(s, v.z, a.z); a.w = fmaf(s, v.w, a.w);
}

// LDS-only barrier: drains DS ops, leaves global->reg prefetch in flight.
__device__ __forceinline__ void tile_barrier() {
    asm volatile("s_waitcnt lgkmcnt(0)" ::: "memory");
    __builtin_amdgcn_s_barrier();
    asm volatile("" ::: "memory");
}

// ---------------- embedding gather (writes bf16) ----------------
__global__ __launch_bounds__(256) void embed_kernel(
    const int* __restrict__ x,
    const float* __restrict__ t0, const float* __restrict__ t1,
    const float* __restrict__ t2, const float* __restrict__ t3,
    const float* __restrict__ t4, const float* __restrict__ t5,
    short* __restrict__ EMBb)
{
    int s = blockIdx.x;
    __shared__ int xi[6];
    if (threadIdx.x < 6) xi[threadIdx.x] = x[s * 6 + threadIdx.x];
    __syncthreads();
    for (int j = threadIdx.x; j < 768; j += 256) {
        int i, off, width; const float* t; float sc;
        if (j < 32)       { i = 0; off = 0;   t = t0; sc = 5.656854249f;  width = 32;  }
        else if (j < 160) { i = 1; off = 32;  t = t1; sc = 11.3137085f;   width = 128; }
        else if (j < 416) { i = 2; off = 160; t = t2; sc = 16.0f;         width = 256; }
        else if (j < 672) { i = 3; off = 416; t = t3; sc = 16.0f;         width = 256; }
        else if (j < 704) { i = 4; off = 672; t = t4; sc = 5.656854249f;  width = 32;  }
        else              { i = 5; off = 704; t = t5; sc = 8.0f;          width = 64;  }
        EMBb[s * 768 + j] = f2bf(t[xi[i] * width + (j - off)] * sc);
    }
}

// ---------------- weight transpose+convert: f32 [B][K][N] -> bf16 [B][N][K] ----
__global__ __launch_bounds__(256) void transpose_w(
    const float* __restrict__ in, short* __restrict__ out, int K, int N)
{
    __shared__ short t[64][66];
    const int b = blockIdx.z;
    const int n0 = blockIdx.x * 64, k0 = blockIdx.y * 64;
    const float* ip = in + (size_t)b * K * N;
    short* op = out + (size_t)b * K * N;
    const int c = threadIdx.x & 63, r0 = (threadIdx.x >> 6) * 16;
    #pragma unroll
    for (int i = 0; i < 16; ++i)
        t[c][r0 + i] = f2bf(ip[(size_t)(k0 + r0 + i) * N + n0 + c]);
    __syncthreads();
    #pragma unroll
    for (int i = 0; i < 16; ++i)
        op[(size_t)(n0 + r0 + i) * K + k0 + c] = t[r0 + i][c];
}

// Batched 512x512x12 transpose for wq/wk/wv/wo: grid (8,8,48)
__global__ __launch_bounds__(256) void transpose4_w(
    const float* __restrict__ wA, const float* __restrict__ wB,
    const float* __restrict__ wC, const float* __restrict__ wD,
    short* __restrict__ oA, short* __restrict__ oB,
    short* __restrict__ oC, short* __restrict__ oD)
{
    __shared__ short t[64][66];
    const int zz = blockIdx.z;
    const int which = zz & 3, b = zz >> 2;
    const float* in = (which == 0) ? wA : (which == 1) ? wB : (which == 2) ? wC : wD;
    short* out      = (which == 0) ? oA : (which == 1) ? oB : (which == 2) ? oC : oD;
    const int n0 = blockIdx.x * 64, k0 = blockIdx.y * 64;
    const float* ip = in + (size_t)b * DM * DM;
    short* op = out + (size_t)b * DM * DM;
    const int c = threadIdx.x & 63, r0 = (threadIdx.x >> 6) * 16;
    #pragma unroll
    for (int i = 0; i < 16; ++i)
        t[c][r0 + i] = f2bf(ip[(size_t)(k0 + r0 + i) * DM + n0 + c]);
    __syncthreads();
    #pragma unroll
    for (int i = 0; i < 16; ++i)
        op[(size_t)(n0 + r0 + i) * DM + k0 + c] = t[r0 + i][c];
}

// ---------------- activation ----------------
__device__ __forceinline__ float apply_act(float v, int act) {
    if (act == ACT_PHI)       return (v > 0.0f) ? (v + 1.0f) : expf(v);
    else if (act == ACT_GELU) return 0.5f * v * (1.0f + erff(v * 0.70710678118654752f));
    return v;
}

// ---------------- 64x64-tile MFMA GEMM core ------------------
// LDS tile: [64 rows][64 k] bf16 = 8KB, double-buffered (A,B = 32KB).
// Bank swizzle: byte col ^= (row&7)<<4 on BOTH ds_write and ds_read.

__device__ __forceinline__ void ldswr64(short* lds, int srow, int scolb,
                                        const s16x8 r[2])
{
    const int bc = scolb ^ ((srow & 7) << 4);
    #pragma unroll
    for (int p = 0; p < 2; ++p)
        *(s16x8*)((char*)lds + (p * 32 + srow) * 128 + bc) = r[p];
}

__device__ __forceinline__ void compute64(
    const short* __restrict__ As, const short* __restrict__ Bs,
    int wr, int wc, int l15, int q, f32x4 acc[2][2])
{
    #pragma unroll
    for (int kh = 0; kh < 2; ++kh) {
        const int kb = kh * 64 + q * 16;
        s16x8 a[2], b[2];
        #pragma unroll
        for (int m = 0; m < 2; ++m) {
            int row = wr * 32 + m * 16 + l15;
            a[m] = *(const s16x8*)((const char*)As + row * 128 + (kb ^ ((row & 7) << 4)));
        }
        #pragma unroll
        for (int n = 0; n < 2; ++n) {
            int row = wc * 32 + n * 16 + l15;
            b[n] = *(const s16x8*)((const char*)Bs + row * 128 + (kb ^ ((row & 7) << 4)));
        }
        #pragma unroll
        for (int m = 0; m < 2; ++m)
            #pragma unroll
            for (int n = 0; n < 2; ++n)
                acc[m][n] = __builtin_amdgcn_mfma_f32_16x16x32_bf16(
                    a[m], b[n], acc[m][n], 0, 0, 0);
    }
}

// shared-A dual-B compute: 6 LDS reads, 16 MFMA per K-64 tile
__device__ __forceinline__ void compute64x2(
    const short* __restrict__ As, const short* __restrict__ Bs0,
    const short* __restrict__ Bs1,
    int wr, int wc, int l15, int q, f32x4 acc0[2][2], f32x4 acc1[2][2])
{
    #pragma unroll
    for (int kh = 0; kh < 2; ++kh) {
        const int kb = kh * 64 + q * 16;
        s16x8 a[2], b0[2], b1[2];
        #pragma unroll
        for (int m = 0; m < 2; ++m) {
            int row = wr * 32 + m * 16 + l15;
            a[m] = *(const s16x8*)((const char*)As + row * 128 + (kb ^ ((row & 7) << 4)));
        }
        #pragma unroll
        for (int n = 0; n < 2; ++n) {
            int row = wc * 32 + n * 16 + l15;
            int off = row * 128 + (kb ^ ((row & 7) << 4));
            b0[n] = *(const s16x8*)((const char*)Bs0 + off);
            b1[n] = *(const s16x8*)((const char*)Bs1 + off);
        }
        #pragma unroll
        for (int m = 0; m < 2; ++m)
            #pragma unroll
            for (int n = 0; n < 2; ++n) {
                acc0[m][n] = __builtin_amdgcn_mfma_f32_16x16x32_bf16(
                    a[m], b0[n], acc0[m][n], 0, 0, 0);
                acc1[m][n] = __builtin_amdgcn_mfma_f32_16x16x32_bf16(
                    a[m], b1[n], acc1[m][n], 0, 0, 0);
            }
    }
}

// ---------------- generic GEMM: C[1024][N] = A[1024][K] @ BT[N][K]^T -------
// zparts>1: block z covers K-slice; partial -> Cf + z*1024*N; bias in z==0.
__global__ __launch_bounds__(256) void gemm64(
    const short* __restrict__ A, const short* __restrict__ BT,
    const float* __restrict__ bias, const float* __restrict__ resid,
    float* __restrict__ Cf, short* __restrict__ Cbf,
    int N, int K, int act, int add_pe, int zparts)
{
    __shared__ short As[2][4096];
    __shared__ short Bs[2][4096];
    const int tid = threadIdx.x;
    const int row0 = blockIdx.y * 64, col0 = blockIdx.x * 64;
    const int z = blockIdx.z;
    const int Kz = K / zparts;
    const int kbase = z * Kz;
    const int w = tid >> 6, lane = tid & 63, q = lane >> 4, l15 = lane & 15;
    const int wr = w >> 1, wc = w & 1;
    const int nt = Kz >> 6;

    const int srow = tid >> 3;              // 0..31
    const int scolb = (tid & 7) * 16;       // 0..112 bytes
    const char* gA = (const char*)(A  + (size_t)(row0 + srow) * K + kbase) + scolb;
    const char* gB = (const char*)(BT + (size_t)(col0 + srow) * K + kbase) + scolb;
    const size_t rstep = (size_t)32 * K * 2;   // +32 rows, bytes

    s16x8 ra[2], rb[2];
    #pragma unroll
    for (int p = 0; p < 2; ++p) {
        ra[p] = *(const s16x8*)(gA + p * rstep);
        rb[p] = *(const s16x8*)(gB + p * rstep);
    }
    ldswr64(As[0], srow, scolb, ra);
    ldswr64(Bs[0], srow, scolb, rb);
    if (nt > 1) {
        #pragma unroll
        for (int p = 0; p < 2; ++p) {
            ra[p] = *(const s16x8*)(gA + p * rstep + 128);
            rb[p] = *(const s16x8*)(gB + p * rstep + 128);
        }
    }
    tile_barrier();

    f32x4 acc[2][2] = {};
    int cur = 0;
    for (int t = 0; t < nt; ++t) {
        compute64(As[cur], Bs[cur], wr, wc, l15, q, acc);
        if (t + 1 < nt) {
            ldswr64(As[cur ^ 1], srow, scolb, ra);
            ldswr64(Bs[cur ^ 1], srow, scolb, rb);
            if (t + 2 < nt) {
                size_t ko = (size_t)(t + 2) * 128;
                #pragma unroll
                for (int p = 0; p < 2; ++p) {
                    ra[p] = *(const s16x8*)(gA + p * rstep + ko);
                    rb[p] = *(const s16x8*)(gB + p * rstep + ko);
                }
            }
            tile_barrier();
        }
        cur ^= 1;
    }

    if (zparts > 1 && Cf) Cf += (size_t)z * S_LEN * N;

    const int rbase = row0 + wr * 32 + q * 4;
    const int cbase = col0 + wc * 32 + l15;
    #pragma unroll
    for (int n = 0; n < 2; ++n) {
        int c = cbase + n * 16;
        float bia = (z == 0) ? bias[c] : 0.0f;
        #pragma unroll
        for (int m = 0; m < 2; ++m) {
            #pragma unroll
            for (int rg = 0; rg < 4; ++rg) {
                int r = rbase + m * 16 + rg;
                float v = apply_act(acc[m][n][rg] + bia, act);
                if (resid) v += resid[(size_t)r * N + c];
                if (add_pe) {
                    float freq = expf((float)(c & ~1) * (-9.210340371976184f / 512.0f));
                    float ang = (float)r * freq;
                    v += (c & 1) ? cosf(ang) : sinf(ang);
                }
                if (Cf)  Cf[(size_t)r * N + c] = v;
                if (Cbf) Cbf[(size_t)r * N + c] = f2bf(v);
            }
        }
    }
}

// ---------------- fused QKV + chunk stats: grid (16, 16) -------------------
// x<8: Q tile (col0=x*64). x>=8: KV block for (chunk c=blockIdx.y, head h=x-8)
// computing K and V 64x64 tiles (shared-A loop), then in-block stats.
__global__ __launch_bounds__(256) void qkv_fused(
    const short* __restrict__ Hb,
    const short* __restrict__ qT, const short* __restrict__ kT, const short* __restrict__ vT,
    const float* __restrict__ bq, const float* __restrict__ bk, const float* __restrict__ bv,
    float* __restrict__ Qb, float* __restrict__ Kb, float* __restrict__ Vb,
    float* __restrict__ KVC, float* __restrict__ KSC)
{
    __shared__ char smem[49152];            // staging (48KB) / stats (34KB) union
    short* As  = (short*)smem;              // [2][4096]
    short* Bs0 = (short*)(smem + 16384);    // [2][4096]
    short* Bs1 = (short*)(smem + 32768);    // [2][4096] (KV only)

    const int tid = threadIdx.x;
    const bool isKV = blockIdx.x >= 8;
    const int colb = blockIdx.x & 7;
    const int col0 = colb * 64;
    const int row0 = blockIdx.y * 64;
    const int w = tid >> 6, lane = tid & 63, q = lane >> 4, l15 = lane & 15;
    const int wr = w >> 1, wc = w & 1;

    const int srow = tid >> 3;
    const int scolb = (tid & 7) * 16;
    const char* gA = (const char*)(Hb + (size_t)(row0 + srow) * DM) + scolb;
    const size_t rstep = (size_t)32 * DM * 2;

    if (!isKV) {
        // ---- Q path (identical structure to old qkv64 sel=0) ----
        const char* gB = (const char*)(qT + (size_t)(col0 + srow) * DM) + scolb;
        s16x8 ra[2], rb[2];
        #pragma unroll
        for (int p = 0; p < 2; ++p) {
            ra[p] = *(const s16x8*)(gA + p * rstep);
            rb[p] = *(const s16x8*)(gB + p * rstep);
        }
        ldswr64(As, srow, scolb, ra);
        ldswr64(Bs0, srow, scolb, rb);
        #pragma unroll
        for (int p = 0; p < 2; ++p) {
            ra[p] = *(const s16x8*)(gA + p * rstep + 128);
            rb[p] = *(const s16x8*)(gB + p * rstep + 128);
        }
        tile_barrier();

        f32x4 acc[2][2] = {};
        int cur = 0;
        for (int t = 0; t < 8; ++t) {
            compute64(As + cur * 4096, Bs0 + cur * 4096, wr, wc, l15, q, acc);
            if (t + 1 < 8) {
                ldswr64(As + (cur ^ 1) * 4096, srow, scolb, ra);
                ldswr64(Bs0 + (cur ^ 1) * 4096, srow, scolb, rb);
                if (t + 2 < 8) {
                    size_t ko = (size_t)(t + 2) * 128;
                    #pragma unroll
                    for (int p = 0; p < 2; ++p) {
                        ra[p] = *(const s16x8*)(gA + p * rstep + ko);
                        rb[p] = *(const s16x8*)(gB + p * rstep + ko);
                    }
                }
                tile_barrier();
            }
            cur ^= 1;
        }

        const int rbase = row0 + wr * 32 + q * 4;
        const int cbase = col0 + wc * 32 + l15;
        #pragma unroll
        for (int n = 0; n < 2; ++n) {
            int c = cbase + n * 16;
            float bia = bq[c];
            #pragma unroll
            for (int m = 0; m < 2; ++m) {
                #pragma unroll
                for (int rg = 0; rg < 4; ++rg) {
                    int r = rbase + m * 16 + rg;
                    float v = acc[m][n][rg] + bia;
                    v = (v > 0.0f) ? (v + 1.0f) : expf(v);
                    Qb[(size_t)r * DM + c] = v;
                }
            }
        }
        return;
    }

    // ---- KV path: shared-A, dual-B ----
    const char* gBk = (const char*)(kT + (size_t)(col0 + srow) * DM) + scolb;
    const char* gBv = (const char*)(vT + (size_t)(col0 + srow) * DM) + scolb;
    s16x8 ra[2], rbk[2], rbv[2];
    #pragma unroll
    for (int p = 0; p < 2; ++p) {
        ra[p]  = *(const s16x8*)(gA + p * rstep);
        rbk[p] = *(const s16x8*)(gBk + p * rstep);
        rbv[p] = *(const s16x8*)(gBv + p * rstep);
    }
    ldswr64(As, srow, scolb, ra);
    ldswr64(Bs0, srow, scolb, rbk);
    ldswr64(Bs1, srow, scolb, rbv);
    #pragma unroll
    for (int p = 0; p < 2; ++p) {
        ra[p]  = *(const s16x8*)(gA + p * rstep + 128);
        rbk[p] = *(const s16x8*)(gBk + p * rstep + 128);
        rbv[p] = *(const s16x8*)(gBv + p * rstep + 128);
    }
    tile_barrier();

    f32x4 acck[2][2] = {}, accv[2][2] = {};
    int cur = 0;
    for (int t = 0; t < 8; ++t) {
        compute64x2(As + cur * 4096, Bs0 + cur * 4096, Bs1 + cur * 4096,
                    wr, wc, l15, q, acck, accv);
        if (t + 1 < 8) {
            ldswr64(As + (cur ^ 1) * 4096, srow, scolb, ra);
            ldswr64(Bs0 + (cur ^ 1) * 4096, srow, scolb, rbk);
            ldswr64(Bs1 + (cur ^ 1) * 4096, srow, scolb, rbv);
            if (t + 2 < 8) {
                size_t ko = (size_t)(t + 2) * 128;
                #pragma unroll
                for (int p = 0; p < 2; ++p) {
                    ra[p]  = *(const s16x8*)(gA + p * rstep + ko);
                    rbk[p] = *(const s16x8*)(gBk + p * rstep + ko);
                    rbv[p] = *(const s16x8*)(gBv + p * rstep + ko);
                }
            }
            tile_barrier();
        }
        cur ^= 1;
    }

    // epilogue: bias, phi(K); write global; stage f32 K,V into LDS for stats
    __syncthreads();                        // all waves done reading As/Bs
    float* Ksf = (float*)smem;              // [64][68]
    float* Vsf = (float*)(smem + 17408);    // [64][68]
    {
        const int lrb = wr * 32 + q * 4;    // local row base
        const int lcb = wc * 32 + l15;      // local col base
        #pragma unroll
        for (int n = 0; n < 2; ++n) {
            int lc = lcb + n * 16;
            int c = col0 + lc;
            float bk_ = bk[c], bv_ = bv[c];
            #pragma unroll
            for (int m = 0; m < 2; ++m) {
                #pragma unroll
                for (int rg = 0; rg < 4; ++rg) {
                    int lr = lrb + m * 16 + rg;
                    int r = row0 + lr;
                    float kv = acck[m][n][rg] + bk_;
                    kv = (kv > 0.0f) ? (kv + 1.0f) : expf(kv);
                    float vv = accv[m][n][rg] + bv_;
                    Kb[(size_t)r * DM + c] = kv;
                    Vb[(size_t)r * DM + c] = vv;
                    Ksf[lr * 68 + lc] = kv;
                    Vsf[lr * 68 + lc] = vv;
                }
            }
        }
    }
    __syncthreads();

    // in-block chunk stats (identical math to old chunk_stats_kernel)
    const int c = blockIdx.y, h = colb;
    const int di = (tid >> 4) * 4, ei = (tid & 15) * 4;
    f32x4 a0 = {}, a1 = {}, a2 = {}, a3 = {}, ks = {};
    #pragma unroll 8
    for (int t = 0; t < 64; ++t) {
        f32x4 kk = *(const f32x4*)(Ksf + t * 68 + di);
        f32x4 vv = *(const f32x4*)(Vsf + t * 68 + ei);
        fma4(a0, kk.x, vv); fma4(a1, kk.y, vv);
        fma4(a2, kk.z, vv); fma4(a3, kk.w, vv);
        ks += kk;
    }
    float* out = KVC + (size_t)(c * NH + h) * 4096;   // [d][e] row-major
    *(f32x4*)(out + (size_t)(di + 0) * 64 + ei) = a0;
    *(f32x4*)(out + (size_t)(di + 1) * 64 + ei) = a1;
    *(f32x4*)(out + (size_t)(di + 2) * 64 + ei) = a2;
    *(f32x4*)(out + (size_t)(di + 3) * 64 + ei) = a3;
    if ((tid & 15) == 0)
        *(f32x4*)(KSC + (size_t)(c * NH + h) * 64 + di) = ks;
}

// ---------------- attention output per (head, chunk) ----------------
// Inline exclusive prefix over per-chunk states (KVC/KSC per-chunk).
__global__ __launch_bounds__(256) void attn_out_kernel(
    const float* __restrict__ Qb, const float* __restrict__ Kb,
    const float* __restrict__ Vb, const float* __restrict__ KVC,
    const float* __restrict__ KSC, short* __restrict__ Ab)
{
    const int h = blockIdx.x >> 4, c = blockIdx.x & 15;
    const int tid = threadIdx.x;
    __shared__ float Qt[64][68];   // Qt[d][s]  (transposed)
    __shared__ float Kt[64][68];   // Kt[d][t]  (transposed)
    __shared__ float Vs[64][68];   // Vs[t][e]
    __shared__ float Ms[64][68];   // state: Ms[d][e]
    __shared__ float St[64][68];   // St[t][s]  (S transposed)
    __shared__ float KSs[64];

    // inline prefix: Ms = sum_{c'<c} KVC[c',h]
    {
        f32x4 macc[4] = {};
        for (int cp = 0; cp < c; ++cp) {
            const float* src = KVC + (size_t)(cp * NH + h) * 4096;
            #pragma unroll
            for (int it = 0; it < 4; ++it)
                macc[it] += *(const f32x4*)(src + (size_t)(tid + it * 256) * 4);
        }
        #pragma unroll
        for (int it = 0; it < 4; ++it) {
            int j = tid + it * 256;
            *(f32x4*)(&Ms[j >> 4][(j & 15) * 4]) = macc[it];
        }
        if (tid < 64) {
            float s = 0.0f;
            for (int cp = 0; cp < c; ++cp)
                s += KSC[(size_t)(cp * NH + h) * 64 + tid];
            KSs[tid] = s;
        }
    }
    #pragma unroll
    for (int it = 0; it < 4; ++it) {
        int j = tid + it * 256;                 // 0..1023
        int r = j >> 4, d0 = (j & 15) * 4;
        size_t g = (size_t)(c * CHUNK + r) * DM + h * 64 + d0;
        f32x4 q = *(const f32x4*)(Qb + g);
        f32x4 k = *(const f32x4*)(Kb + g);
        f32x4 v = *(const f32x4*)(Vb + g);
        Qt[d0 + 0][r] = q.x; Qt[d0 + 1][r] = q.y; Qt[d0 + 2][r] = q.z; Qt[d0 + 3][r] = q.w;
        Kt[d0 + 0][r] = k.x; Kt[d0 + 1][r] = k.y; Kt[d0 + 2][r] = k.z; Kt[d0 + 3][r] = k.w;
        *(f32x4*)(&Vs[r][d0]) = v;
    }
    __syncthreads();

    const int si = tid >> 4, ti = tid & 15;
    const int s0 = si * 4, t0 = ti * 4;         // t0 doubles as e0

    // ---- Phase A: inter-chunk O = Q @ State, den = Q . KSprefix ----
    f32x4 accO0 = {}, accO1 = {}, accO2 = {}, accO3 = {};
    f32x4 den = {};
    #pragma unroll 8
    for (int d = 0; d < 64; ++d) {
        f32x4 qv = *(const f32x4*)(&Qt[d][s0]);
        f32x4 mv = *(const f32x4*)(&Ms[d][t0]);
        float ks = KSs[d];
        fma4(accO0, qv.x, mv); fma4(accO1, qv.y, mv);
        fma4(accO2, qv.z, mv); fma4(accO3, qv.w, mv);
        fma4(den, ks, qv);
    }

    // ---- Phase B: S = Q K^T, causal, staged transposed ----
    f32x4 p0 = {}, p1 = {}, p2 = {}, p3 = {};   // p_r = S[s0+r][t0:t0+4]
    if (ti <= si) {
        #pragma unroll 8
        for (int d = 0; d < 64; ++d) {
            f32x4 qv = *(const f32x4*)(&Qt[d][s0]);
            f32x4 kv = *(const f32x4*)(&Kt[d][t0]);
            fma4(p0, qv.x, kv); fma4(p1, qv.y, kv);
            fma4(p2, qv.z, kv); fma4(p3, qv.w, kv);
        }
        if (ti == si) {                          // diagonal tile: keep t<=r
            p0.y = 0.0f; p0.z = 0.0f; p0.w = 0.0f;
            p1.z = 0.0f; p1.w = 0.0f;
            p2.w = 0.0f;
        }
    }
    St[t0 + 0][s0 + 0] = p0.x; St[t0 + 1][s0 + 0] = p0.y;
    St[t0 + 2][s0 + 0] = p0.z; St[t0 + 3][s0 + 0] = p0.w;
    St[t0 + 0][s0 + 1] = p1.x; St[t0 + 1][s0 + 1] = p1.y;
    St[t0 + 2][s0 + 1] = p1.z; St[t0 + 3][s0 + 1] = p1.w;
    St[t0 + 0][s0 + 2] = p2.x; St[t0 + 1][s0 + 2] = p2.y;
    St[t0 + 2][s0 + 2] = p2.z; St[t0 + 3][s0 + 2] = p2.w;
    St[t0 + 0][s0 + 3] = p3.x; St[t0 + 1][s0 + 3] = p3.y;
    St[t0 + 2][s0 + 3] = p3.z; St[t0 + 3][s0 + 3] = p3.w;
    __syncthreads();

    // ---- Phase C: O += S @ V ; den += rowsum(S) ----
    const int tmax = s0 + 4;                     // exclusive; St zero above diag
    #pragma unroll 4
    for (int t2 = 0; t2 < tmax; ++t2) {
        f32x4 sv = *(const f32x4*)(&St[t2][s0]);
        f32x4 vv = *(const f32x4*)(&Vs[t2][t0]);
        fma4(accO0, sv.x, vv); fma4(accO1, sv.y, vv);
        fma4(accO2, sv.z, vv); fma4(accO3, sv.w, vv);
        den += sv;
    }

    // ---- epilogue: z = 1/(den+eps), bf16 out ----
    short* op = Ab + (size_t)(c * CHUNK + s0) * DM + h * 64 + t0;
    {
        float z = 1.0f / (den.x + 1e-6f);
        short4 o; o.x = f2bf(accO0.x * z); o.y = f2bf(accO0.y * z);
        o.z = f2bf(accO0.z * z); o.w = f2bf(accO0.w * z);
        *reinterpret_cast<short4*>(op) = o;
    }
    {
        float z = 1.0f / (den.y + 1e-6f);
        short4 o; o.x = f2bf(accO1.x * z); o.y = f2bf(accO1.y * z);
        o.z = f2bf(accO1.z * z); o.w = f2bf(accO1.w * z);
        *reinterpret_cast<short4*>(op + DM) = o;
    }
    {
        float z = 1.0f / (den.z + 1e-6f);
        short4 o; o.x = f2bf(accO2.x * z); o.y = f2bf(accO2.y * z);
        o.z = f2bf(accO2.z * z); o.w = f2bf(accO2.w * z);
        *reinterpret_cast<short4*>(op + 2 * DM) = o;
    }
    {
        float z = 1.0f / (den.w + 1e-6f);
        short4 o; o.x = f2bf(accO3.x * z); o.y = f2bf(accO3.y * z);
        o.z = f2bf(accO3.z * z); o.w = f2bf(accO3.w * z);
        *reinterpret_cast<short4*>(op + 3 * DM) = o;
    }
}

// ---------------- wave-per-row layernorm: LN(X + X2? + resid?) --------------
__global__ __launch_bounds__(64) void ln_kernel64(
    const float* __restrict__ X, const float* __restrict__ X2,
    const float* __restrict__ resid,
    const float* __restrict__ g, const float* __restrict__ b,
    float* __restrict__ O, short* __restrict__ Ob)
{
    const int row = blockIdx.x;
    const size_t base = (size_t)row * DM;
    const int t = threadIdx.x;
    const int i0 = 4 * t, i1 = 256 + 4 * t;
    f32x4 v0 = *(const f32x4*)(X + base + i0);
    f32x4 v1 = *(const f32x4*)(X + base + i1);
    if (X2) {
        v0 += *(const f32x4*)(X2 + base + i0);
        v1 += *(const f32x4*)(X2 + base + i1);
    }
    if (resid) {
        v0 += *(const f32x4*)(resid + base + i0);
        v1 += *(const f32x4*)(resid + base + i1);
    }
    float s = v0.x + v0.y + v0.z + v0.w + v1.x + v1.y + v1.z + v1.w;
    #pragma unroll
    for (int m = 1; m < 64; m <<= 1) s += __shfl_xor(s, m, 64);
    float mean = s * (1.0f / 512.0f);
    f32x4 d0 = v0 - mean, d1 = v1 - mean;
    float ss = d0.x * d0.x + d0.y * d0.y + d0.z * d0.z + d0.w * d0.w
             + d1.x * d1.x + d1.y * d1.y + d1.z * d1.z + d1.w * d1.w;
    #pragma unroll
    for (int m = 1; m < 64; m <<= 1) ss += __shfl_xor(ss, m, 64);
    float var = ss * (1.0f / 512.0f);
    float rs = 1.0f / sqrtf(var + 1e-5f);
    f32x4 g0 = *(const f32x4*)(g + i0), g1v = *(const f32x4*)(g + i1);
    f32x4 b0 = *(const f32x4*)(b + i0), b1v = *(const f32x4*)(b + i1);
    f32x4 o0 = d0 * rs * g0 + b0;
    f32x4 o1 = d1 * rs * g1v + b1v;
    *(f32x4*)(O + base + i0) = o0;
    *(f32x4*)(O + base + i1) = o1;
    if (Ob) {
        short4 s0; s0.x = f2bf(o0.x); s0.y = f2bf(o0.y); s0.z = f2bf(o0.z); s0.w = f2bf(o0.w);
        short4 s1; s1.x = f2bf(o1.x); s1.y = f2bf(o1.y); s1.z = f2bf(o1.z); s1.w = f2bf(o1.w);
        *reinterpret_cast<short4*>(Ob + base + i0) = s0;
        *reinterpret_cast<short4*>(Ob + base + i1) = s1;
    }
}

// ---------------- final LN + emotion head, fused (1024 x 64) ----------------
__global__ __launch_bounds__(64) void ln_final_proj(
    const float* __restrict__ X,
    const float* __restrict__ g, const float* __restrict__ b,
    const float* __restrict__ pw, const float* __restrict__ pb,
    float* __restrict__ Hout, float* __restrict__ Eout)
{
    __shared__ float hrow[512];
    const int row = blockIdx.x;
    const size_t base = (size_t)row * DM;
    const int t = threadIdx.x;
    const int i0 = 4 * t, i1 = 256 + 4 * t;
    f32x4 v0 = *(const f32x4*)(X + base + i0);
    f32x4 v1 = *(const f32x4*)(X + base + i1);
    float s = v0.x + v0.y + v0.z + v0.w + v1.x + v1.y + v1.z + v1.w;
    #pragma unroll
    for (int m = 1; m < 64; m <<= 1) s += __shfl_xor(s, m, 64);
    float mean = s * (1.0f / 512.0f);
    f32x4 d0 = v0 - mean, d1 = v1 - mean;
    float ss = d0.x * d0.x + d0.y * d0.y + d0.z * d0.z + d0.w * d0.w
             + d1.x * d1.x + d1.y * d1.y + d1.z * d1.z + d1.w * d1.w;
    #pragma unroll
    for (int m = 1; m < 64; m <<= 1) ss += __shfl_xor(ss, m, 64);
    float var = ss * (1.0f / 512.0f);
    float rs = 1.0f / sqrtf(var + 1e-5f);
    f32x4 g0 = *(const f32x4*)(g + i0), g1v = *(const f32x4*)(g + i1);
    f32x4 b0 = *(const f32x4*)(b + i0), b1v = *(const f32x4*)(b + i1);
    f32x4 o0 = d0 * rs * g0 + b0;
    f32x4 o1 = d1 * rs * g1v + b1v;
    *(f32x4*)(Hout + base + i0) = o0;
    *(f32x4*)(Hout + base + i1) = o1;
    *(f32x4*)(&hrow[i0]) = o0;
    *(f32x4*)(&hrow[i1]) = o1;
    __syncthreads();

    // proj: 8 lane-groups, e = t&7, segment seg = t>>3 (64 elems each)
    const int e = t & 7, seg = t >> 3;
    float acc = 0.0f;
    #pragma unroll 16
    for (int d = seg * 64; d < seg * 64 + 64; ++d)
        acc = fmaf(hrow[d], pw[d * 8 + e], acc);
    acc += __shfl_xor(acc, 8, 64);
    acc += __shfl_xor(acc, 16, 64);
    acc += __shfl_xor(acc, 32, 64);
    if (t < 8) Eout[(size_t)row * 8 + t] = acc + pb[t];
}

// ---------------------------------------------------------------------------
extern "C" void kernel_launch(void* const* d_in, const int* in_sizes, int n_in,
                              void* d_out, int out_size, void* d_ws, size_t ws_size,
                              hipStream_t stream)
{
    const int*   x    = (const int*)d_in[0];
    const float* e0   = (const float*)d_in[1];
    const float* e1   = (const float*)d_in[2];
    const float* e2   = (const float*)d_in[3];
    const float* e3   = (const float*)d_in[4];
    const float* e4   = (const float*)d_in[5];
    const float* e5   = (const float*)d_in[6];
    const float* in_w = (const float*)d_in[7];
    const float* in_b = (const float*)d_in[8];
    const float* wq   = (const float*)d_in[9];
    const float* bq   = (const float*)d_in[10];
    const float* wk   = (const float*)d_in[11];
    const float* bk   = (const float*)d_in[12];
    const float* wv   = (const float*)d_in[13];
    const float* bv   = (const float*)d_in[14];
    const float* wo   = (const float*)d_in[15];
    const float* bo   = (const float*)d_in[16];
    const float* g1   = (const float*)d_in[17];
    const float* be1  = (const float*)d_in[18];
    const float* w1   = (const float*)d_in[19];
    const float* b1   = (const float*)d_in[20];
    const float* w2   = (const float*)d_in[21];
    const float* b2   = (const float*)d_in[22];
    const float* g2   = (const float*)d_in[23];
    const float* be2  = (const float*)d_in[24];
    const float* gf   = (const float*)d_in[25];
    const float* bfin = (const float*)d_in[26];
    const float* pw   = (const float*)d_in[27];
    const float* pb   = (const float*)d_in[28];
    float* outp = (float*)d_out;

    // ---- workspace layout: Y,Y2 contiguous partial arena ----
    float* ws = (float*)d_ws;
    float* H    = ws;                  // 1024x512 f32
    float* Y    = ws + 524288;         // partial 0 (and pre-LN sum input)
    float* Y2   = ws + 1048576;        // partial 1 (contiguous with Y)
    float* Qb   = ws + 1572864;
    float* Kb   = ws + 2097152;
    float* Vb   = ws + 2621440;
    float* KVC  = ws + 3145728;        // 16*8*4096 = 524288
    float* KSC  = ws + 3670016;        // 8192 (ends 3678208)
    short* sb   = (short*)(ws + 3678208);
    short* Hb   = sb;                  // 1024x512
    short* Ab   = sb + 524288;         // 1024x512
    short* FFb  = sb + 1048576;        // 1024x2048
    short* EMBb = FFb;                 // 1024x768 (alias: dead before ffn1)
    // bf16 W^T arena [N][K]
    short* inT  = sb + 3145728;        // [512][768]
    short* qT   = inT + 393216;        // [12][512][512]
    short* kT   = qT + 3145728;
    short* vT   = kT + 3145728;
    short* oT   = vT + 3145728;
    short* w1T  = oT + 3145728;        // [12][2048][512]
    short* w2T  = w1T + 12582912;      // [12][512][2048]

    const dim3 blk256(256), blk64(64);

    // ---- weight transpose+convert ----
    transpose_w<<<dim3(8, 12, 1),  blk256, 0, stream>>>(in_w, inT, 768, DM);
    transpose4_w<<<dim3(8, 8, 48), blk256, 0, stream>>>(wq, wk, wv, wo,
                                                        qT, kT, vT, oT);
    transpose_w<<<dim3(32, 8, 12), blk256, 0, stream>>>(w1, w1T, DM, DFF);
    transpose_w<<<dim3(8, 32, 12), blk256, 0, stream>>>(w2, w2T, DFF, DM);

    embed_kernel<<<S_LEN, blk256, 0, stream>>>(x, e0, e1, e2, e3, e4, e5, EMBb);
    // in-proj: EMBb @ in_w + in_b + PE -> H (f32) and Hb (bf16)
    gemm64<<<dim3(8, 16, 1), blk256, 0, stream>>>(EMBb, inT, in_b, nullptr,
                                                  H, Hb, DM, 768, ACT_NONE, 1, 1);

    for (int l = 0; l < NLAYER; ++l) {
        const short* qT_l = qT + (size_t)l * DM * DM;
        const short* kT_l = kT + (size_t)l * DM * DM;
        const short* vT_l = vT + (size_t)l * DM * DM;
        const short* oT_l = oT + (size_t)l * DM * DM;
        const short* w1T_l = w1T + (size_t)l * DM * DFF;
        const short* w2T_l = w2T + (size_t)l * DM * DFF;
        const float* bq_l = bq + l * DM;  const float* bk_l = bk + l * DM;
        const float* bv_l = bv + l * DM;  const float* bo_l = bo + l * DM;
        const float* b1_l = b1 + l * DFF; const float* b2_l = b2 + l * DM;

        // fused QKV + chunk stats (one dispatch, 256 blocks)
        qkv_fused<<<dim3(16, 16), blk256, 0, stream>>>(Hb, qT_l, kT_l, vT_l,
                                                       bq_l, bk_l, bv_l,
                                                       Qb, Kb, Vb, KVC, KSC);

        attn_out_kernel<<<NCH * NH, blk256, 0, stream>>>(Qb, Kb, Vb, KVC, KSC, Ab);

        // wo split-K z=2: partials Y (z0,+bias), Y2 (z1); LN(Y+Y2+H)
        gemm64<<<dim3(8, 16, 2), blk256, 0, stream>>>(Ab, oT_l, bo_l, nullptr,
                                                      Y, nullptr, DM, DM, ACT_NONE, 0, 2);
        ln_kernel64<<<S_LEN, blk64, 0, stream>>>(Y, Y2, H,
                                                 g1 + l * DM, be1 + l * DM, H, Hb);

        // ffn1: Hb @ w1 + b1, GELU -> FFb (bf16)
        gemm64<<<dim3(32, 16, 1), blk256, 0, stream>>>(Hb, w1T_l, b1_l, nullptr,
                                                       nullptr, FFb, DFF, DM, ACT_GELU, 0, 1);
        // ffn2 split-K z=2: partials Y (z0,+bias), Y2 (z1); LN(Y+Y2+H)
        gemm64<<<dim3(8, 16, 2), blk256, 0, stream>>>(FFb, w2T_l, b2_l, nullptr,
                                                      Y, nullptr, DM, DFF, ACT_NONE, 0, 2);
        ln_kernel64<<<S_LEN, blk64, 0, stream>>>(Y, Y2, H,
                                                 g2 + l * DM, be2 + l * DM, H, Hb);
    }

    // final norm + emotion head (fused)
    ln_final_proj<<<S_LEN, blk64, 0, stream>>>(H, gf, bfin, pw, pb,
                                               outp, outp + 524288);
}

// Round 9
// 998.639 us; speedup vs baseline: 1.2934x; 1.0163x over previous
//
#include <hip/hip_runtime.h>
#include <hip/hip_bf16.h>
#include <math.h>

// ---------------------------------------------------------------------------
// TransformerModel: 12-layer causal linear-attention encoder.
// B=1, S=1024, D_MODEL=512, H=8, Dh=64, FF=2048. All tensors fp32 (x int32).
// Round 18 (base R17, 1015us): occupancy attack on standalone GEMMs.
// gemm64x8: 512 threads = 8 waves = TWO 4-wave K-groups, each computing the
// same 64x64 tile over half the K-slice with private double-buffered LDS
// slabs (64KB total); partials combined via 16KB LDS scratch (aliases dead
// staging). 2 waves/SIMD (vs 1) -> latency hiding; serial K-chain halves.
// Applied to in-proj/wo/ffn1/ffn2. qkv_fused / attn_out unchanged.
// ---------------------------------------------------------------------------

#define S_LEN 1024
#define DM 512
#define NH 8
#define DH 64
#define DFF 2048
#define NLAYER 12
#define CHUNK 64
#define NCH (S_LEN / CHUNK)   // 16

#define ACT_NONE 0
#define ACT_PHI  1
#define ACT_GELU 2

typedef short s16x8 __attribute__((ext_vector_type(8)));
typedef float f32x4 __attribute__((ext_vector_type(4)));

__device__ __forceinline__ short f2bf(float x) {
    __hip_bfloat16 h = __float2bfloat16(x);
    return *reinterpret_cast<short*>(&h);
}

__device__ __forceinline__ void fma4(f32x4& a, float s, const f32x4 v) {
    a.x = fmaf(s, v.x, a.x); a.y = fmaf(s, v.y, a.y);
    a.z = fmaf(s, v.z, a.z); a.w = fmaf(s, v.w, a.w);
}

// LDS-only barrier: drains DS ops, leaves global->reg prefetch in flight.
__device__ __forceinline__ void tile_barrier() {
    asm volatile("s_waitcnt lgkmcnt(0)" ::: "memory");
    __builtin_amdgcn_s_barrier();
    asm volatile("" ::: "memory");
}

// ---------------- embedding gather (writes bf16) ----------------
__global__ __launch_bounds__(256) void embed_kernel(
    const int* __restrict__ x,
    const float* __restrict__ t0, const float* __restrict__ t1,
    const float* __restrict__ t2, const float* __restrict__ t3,
    const float* __restrict__ t4, const float* __restrict__ t5,
    short* __restrict__ EMBb)
{
    int s = blockIdx.x;
    __shared__ int xi[6];
    if (threadIdx.x < 6) xi[threadIdx.x] = x[s * 6 + threadIdx.x];
    __syncthreads();
    for (int j = threadIdx.x; j < 768; j += 256) {
        int i, off, width; const float* t; float sc;
        if (j < 32)       { i = 0; off = 0;   t = t0; sc = 5.656854249f;  width = 32;  }
        else if (j < 160) { i = 1; off = 32;  t = t1; sc = 11.3137085f;   width = 128; }
        else if (j < 416) { i = 2; off = 160; t = t2; sc = 16.0f;         width = 256; }
        else if (j < 672) { i = 3; off = 416; t = t3; sc = 16.0f;         width = 256; }
        else if (j < 704) { i = 4; off = 672; t = t4; sc = 5.656854249f;  width = 32;  }
        else              { i = 5; off = 704; t = t5; sc = 8.0f;          width = 64;  }
        EMBb[s * 768 + j] = f2bf(t[xi[i] * width + (j - off)] * sc);
    }
}

// ---------------- weight transpose+convert: f32 [B][K][N] -> bf16 [B][N][K] ----
__global__ __launch_bounds__(256) void transpose_w(
    const float* __restrict__ in, short* __restrict__ out, int K, int N)
{
    __shared__ short t[64][66];
    const int b = blockIdx.z;
    const int n0 = blockIdx.x * 64, k0 = blockIdx.y * 64;
    const float* ip = in + (size_t)b * K * N;
    short* op = out + (size_t)b * K * N;
    const int c = threadIdx.x & 63, r0 = (threadIdx.x >> 6) * 16;
    #pragma unroll
    for (int i = 0; i < 16; ++i)
        t[c][r0 + i] = f2bf(ip[(size_t)(k0 + r0 + i) * N + n0 + c]);
    __syncthreads();
    #pragma unroll
    for (int i = 0; i < 16; ++i)
        op[(size_t)(n0 + r0 + i) * K + k0 + c] = t[r0 + i][c];
}

// Batched 512x512x12 transpose for wq/wk/wv/wo: grid (8,8,48)
__global__ __launch_bounds__(256) void transpose4_w(
    const float* __restrict__ wA, const float* __restrict__ wB,
    const float* __restrict__ wC, const float* __restrict__ wD,
    short* __restrict__ oA, short* __restrict__ oB,
    short* __restrict__ oC, short* __restrict__ oD)
{
    __shared__ short t[64][66];
    const int zz = blockIdx.z;
    const int which = zz & 3, b = zz >> 2;
    const float* in = (which == 0) ? wA : (which == 1) ? wB : (which == 2) ? wC : wD;
    short* out      = (which == 0) ? oA : (which == 1) ? oB : (which == 2) ? oC : oD;
    const int n0 = blockIdx.x * 64, k0 = blockIdx.y * 64;
    const float* ip = in + (size_t)b * DM * DM;
    short* op = out + (size_t)b * DM * DM;
    const int c = threadIdx.x & 63, r0 = (threadIdx.x >> 6) * 16;
    #pragma unroll
    for (int i = 0; i < 16; ++i)
        t[c][r0 + i] = f2bf(ip[(size_t)(k0 + r0 + i) * DM + n0 + c]);
    __syncthreads();
    #pragma unroll
    for (int i = 0; i < 16; ++i)
        op[(size_t)(n0 + r0 + i) * DM + k0 + c] = t[r0 + i][c];
}

// ---------------- activation ----------------
__device__ __forceinline__ float apply_act(float v, int act) {
    if (act == ACT_PHI)       return (v > 0.0f) ? (v + 1.0f) : expf(v);
    else if (act == ACT_GELU) return 0.5f * v * (1.0f + erff(v * 0.70710678118654752f));
    return v;
}

// ---------------- 64x64-tile MFMA GEMM core ------------------
// LDS tile: [64 rows][64 k] bf16 = 8KB. Swizzle: byte col ^= (row&7)<<4.

__device__ __forceinline__ void ldswr64(short* lds, int srow, int scolb,
                                        const s16x8 r[2])
{
    const int bc = scolb ^ ((srow & 7) << 4);
    #pragma unroll
    for (int p = 0; p < 2; ++p)
        *(s16x8*)((char*)lds + (p * 32 + srow) * 128 + bc) = r[p];
}

__device__ __forceinline__ void compute64(
    const short* __restrict__ As, const short* __restrict__ Bs,
    int wr, int wc, int l15, int q, f32x4 acc[2][2])
{
    #pragma unroll
    for (int kh = 0; kh < 2; ++kh) {
        const int kb = kh * 64 + q * 16;
        s16x8 a[2], b[2];
        #pragma unroll
        for (int m = 0; m < 2; ++m) {
            int row = wr * 32 + m * 16 + l15;
            a[m] = *(const s16x8*)((const char*)As + row * 128 + (kb ^ ((row & 7) << 4)));
        }
        #pragma unroll
        for (int n = 0; n < 2; ++n) {
            int row = wc * 32 + n * 16 + l15;
            b[n] = *(const s16x8*)((const char*)Bs + row * 128 + (kb ^ ((row & 7) << 4)));
        }
        #pragma unroll
        for (int m = 0; m < 2; ++m)
            #pragma unroll
            for (int n = 0; n < 2; ++n)
                acc[m][n] = __builtin_amdgcn_mfma_f32_16x16x32_bf16(
                    a[m], b[n], acc[m][n], 0, 0, 0);
    }
}

// shared-A dual-B compute: 6 LDS reads, 16 MFMA per K-64 tile
__device__ __forceinline__ void compute64x2(
    const short* __restrict__ As, const short* __restrict__ Bs0,
    const short* __restrict__ Bs1,
    int wr, int wc, int l15, int q, f32x4 acc0[2][2], f32x4 acc1[2][2])
{
    #pragma unroll
    for (int kh = 0; kh < 2; ++kh) {
        const int kb = kh * 64 + q * 16;
        s16x8 a[2], b0[2], b1[2];
        #pragma unroll
        for (int m = 0; m < 2; ++m) {
            int row = wr * 32 + m * 16 + l15;
            a[m] = *(const s16x8*)((const char*)As + row * 128 + (kb ^ ((row & 7) << 4)));
        }
        #pragma unroll
        for (int n = 0; n < 2; ++n) {
            int row = wc * 32 + n * 16 + l15;
            int off = row * 128 + (kb ^ ((row & 7) << 4));
            b0[n] = *(const s16x8*)((const char*)Bs0 + off);
            b1[n] = *(const s16x8*)((const char*)Bs1 + off);
        }
        #pragma unroll
        for (int m = 0; m < 2; ++m)
            #pragma unroll
            for (int n = 0; n < 2; ++n) {
                acc0[m][n] = __builtin_amdgcn_mfma_f32_16x16x32_bf16(
                    a[m], b0[n], acc0[m][n], 0, 0, 0);
                acc1[m][n] = __builtin_amdgcn_mfma_f32_16x16x32_bf16(
                    a[m], b1[n], acc1[m][n], 0, 0, 0);
            }
    }
}

// ---------------- 8-wave dual-K-group GEMM -------------------------------
// 512 thr = 2 K-groups x 4 waves. Group kg computes the full 64x64 tile over
// K-slice [kbase + kg*Kz/2, +Kz/2), private dbuf LDS slabs; partials summed
// via LDS scratch. zparts as before (partial -> Cf + z*1024*N, bias z==0).
__global__ __launch_bounds__(512) void gemm64x8(
    const short* __restrict__ A, const short* __restrict__ BT,
    const float* __restrict__ bias, const float* __restrict__ resid,
    float* __restrict__ Cf, short* __restrict__ Cbf,
    int N, int K, int act, int add_pe, int zparts)
{
    __shared__ char smem[65536];
    // A slabs: smem + kg*16384 + cur*8192 ; B slabs: +32768 same pattern
    const int tid = threadIdx.x;
    const int kg = tid >> 8, sg = tid & 255;
    const int row0 = blockIdx.y * 64, col0 = blockIdx.x * 64;
    const int z = blockIdx.z;
    const int Kz = K / zparts;
    const int kbase = z * Kz + kg * (Kz >> 1);
    const int w = sg >> 6, lane = tid & 63, q = lane >> 4, l15 = lane & 15;
    const int wr = w >> 1, wc = w & 1;
    const int nt = Kz >> 7;                  // per-group K-64 steps

    const int srow = sg >> 3;                // 0..31
    const int scolb = (sg & 7) * 16;         // 0..112 bytes
    const char* gA = (const char*)(A  + (size_t)(row0 + srow) * K + kbase) + scolb;
    const char* gB = (const char*)(BT + (size_t)(col0 + srow) * K + kbase) + scolb;
    const size_t rstep = (size_t)32 * K * 2;

    short* Aslab = (short*)(smem + kg * 16384);
    short* Bslab = (short*)(smem + 32768 + kg * 16384);

    s16x8 ra[2], rb[2];
    #pragma unroll
    for (int p = 0; p < 2; ++p) {
        ra[p] = *(const s16x8*)(gA + p * rstep);
        rb[p] = *(const s16x8*)(gB + p * rstep);
    }
    ldswr64(Aslab, srow, scolb, ra);
    ldswr64(Bslab, srow, scolb, rb);
    if (nt > 1) {
        #pragma unroll
        for (int p = 0; p < 2; ++p) {
            ra[p] = *(const s16x8*)(gA + p * rstep + 128);
            rb[p] = *(const s16x8*)(gB + p * rstep + 128);
        }
    }
    tile_barrier();

    f32x4 acc[2][2] = {};
    int cur = 0;
    for (int t = 0; t < nt; ++t) {
        compute64(Aslab + cur * 4096, Bslab + cur * 4096, wr, wc, l15, q, acc);
        if (t + 1 < nt) {
            ldswr64(Aslab + (cur ^ 1) * 4096, srow, scolb, ra);
            ldswr64(Bslab + (cur ^ 1) * 4096, srow, scolb, rb);
            if (t + 2 < nt) {
                size_t ko = (size_t)(t + 2) * 128;
                #pragma unroll
                for (int p = 0; p < 2; ++p) {
                    ra[p] = *(const s16x8*)(gA + p * rstep + ko);
                    rb[p] = *(const s16x8*)(gB + p * rstep + ko);
                }
            }
            tile_barrier();
        }
        cur ^= 1;
    }

    // combine the two K-groups via LDS scratch (aliases kg0 A slabs, now dead)
    __syncthreads();
    float* scratch = (float*)smem;           // [256][16] f32 = 16KB
    if (kg == 1) {
        float* s = scratch + sg * 16;
        #pragma unroll
        for (int m = 0; m < 2; ++m)
            #pragma unroll
            for (int n = 0; n < 2; ++n)
                *(f32x4*)(s + (m * 2 + n) * 4) = acc[m][n];
    }
    __syncthreads();
    if (kg == 1) return;

    {
        float* s = scratch + sg * 16;
        #pragma unroll
        for (int m = 0; m < 2; ++m)
            #pragma unroll
            for (int n = 0; n < 2; ++n)
                acc[m][n] += *(const f32x4*)(s + (m * 2 + n) * 4);
    }

    if (zparts > 1 && Cf) Cf += (size_t)z * S_LEN * N;

    const int rbase = row0 + wr * 32 + q * 4;
    const int cbase = col0 + wc * 32 + l15;
    #pragma unroll
    for (int n = 0; n < 2; ++n) {
        int c = cbase + n * 16;
        float bia = (z == 0) ? bias[c] : 0.0f;
        #pragma unroll
        for (int m = 0; m < 2; ++m) {
            #pragma unroll
            for (int rg = 0; rg < 4; ++rg) {
                int r = rbase + m * 16 + rg;
                float v = apply_act(acc[m][n][rg] + bia, act);
                if (resid) v += resid[(size_t)r * N + c];
                if (add_pe) {
                    float freq = expf((float)(c & ~1) * (-9.210340371976184f / 512.0f));
                    float ang = (float)r * freq;
                    v += (c & 1) ? cosf(ang) : sinf(ang);
                }
                if (Cf)  Cf[(size_t)r * N + c] = v;
                if (Cbf) Cbf[(size_t)r * N + c] = f2bf(v);
            }
        }
    }
}

// ---------------- fused QKV + chunk stats: grid (16, 16) -------------------
__global__ __launch_bounds__(256) void qkv_fused(
    const short* __restrict__ Hb,
    const short* __restrict__ qT, const short* __restrict__ kT, const short* __restrict__ vT,
    const float* __restrict__ bq, const float* __restrict__ bk, const float* __restrict__ bv,
    float* __restrict__ Qb, float* __restrict__ Kb, float* __restrict__ Vb,
    float* __restrict__ KVC, float* __restrict__ KSC)
{
    __shared__ char smem[49152];            // staging (48KB) / stats (34KB) union
    short* As  = (short*)smem;              // [2][4096]
    short* Bs0 = (short*)(smem + 16384);    // [2][4096]
    short* Bs1 = (short*)(smem + 32768);    // [2][4096] (KV only)

    const int tid = threadIdx.x;
    const bool isKV = blockIdx.x >= 8;
    const int colb = blockIdx.x & 7;
    const int col0 = colb * 64;
    const int row0 = blockIdx.y * 64;
    const int w = tid >> 6, lane = tid & 63, q = lane >> 4, l15 = lane & 15;
    const int wr = w >> 1, wc = w & 1;

    const int srow = tid >> 3;
    const int scolb = (tid & 7) * 16;
    const char* gA = (const char*)(Hb + (size_t)(row0 + srow) * DM) + scolb;
    const size_t rstep = (size_t)32 * DM * 2;

    if (!isKV) {
        const char* gB = (const char*)(qT + (size_t)(col0 + srow) * DM) + scolb;
        s16x8 ra[2], rb[2];
        #pragma unroll
        for (int p = 0; p < 2; ++p) {
            ra[p] = *(const s16x8*)(gA + p * rstep);
            rb[p] = *(const s16x8*)(gB + p * rstep);
        }
        ldswr64(As, srow, scolb, ra);
        ldswr64(Bs0, srow, scolb, rb);
        #pragma unroll
        for (int p = 0; p < 2; ++p) {
            ra[p] = *(const s16x8*)(gA + p * rstep + 128);
            rb[p] = *(const s16x8*)(gB + p * rstep + 128);
        }
        tile_barrier();

        f32x4 acc[2][2] = {};
        int cur = 0;
        for (int t = 0; t < 8; ++t) {
            compute64(As + cur * 4096, Bs0 + cur * 4096, wr, wc, l15, q, acc);
            if (t + 1 < 8) {
                ldswr64(As + (cur ^ 1) * 4096, srow, scolb, ra);
                ldswr64(Bs0 + (cur ^ 1) * 4096, srow, scolb, rb);
                if (t + 2 < 8) {
                    size_t ko = (size_t)(t + 2) * 128;
                    #pragma unroll
                    for (int p = 0; p < 2; ++p) {
                        ra[p] = *(const s16x8*)(gA + p * rstep + ko);
                        rb[p] = *(const s16x8*)(gB + p * rstep + ko);
                    }
                }
                tile_barrier();
            }
            cur ^= 1;
        }

        const int rbase = row0 + wr * 32 + q * 4;
        const int cbase = col0 + wc * 32 + l15;
        #pragma unroll
        for (int n = 0; n < 2; ++n) {
            int c = cbase + n * 16;
            float bia = bq[c];
            #pragma unroll
            for (int m = 0; m < 2; ++m) {
                #pragma unroll
                for (int rg = 0; rg < 4; ++rg) {
                    int r = rbase + m * 16 + rg;
                    float v = acc[m][n][rg] + bia;
                    v = (v > 0.0f) ? (v + 1.0f) : expf(v);
                    Qb[(size_t)r * DM + c] = v;
                }
            }
        }
        return;
    }

    // ---- KV path: shared-A, dual-B ----
    const char* gBk = (const char*)(kT + (size_t)(col0 + srow) * DM) + scolb;
    const char* gBv = (const char*)(vT + (size_t)(col0 + srow) * DM) + scolb;
    s16x8 ra[2], rbk[2], rbv[2];
    #pragma unroll
    for (int p = 0; p < 2; ++p) {
        ra[p]  = *(const s16x8*)(gA + p * rstep);
        rbk[p] = *(const s16x8*)(gBk + p * rstep);
        rbv[p] = *(const s16x8*)(gBv + p * rstep);
    }
    ldswr64(As, srow, scolb, ra);
    ldswr64(Bs0, srow, scolb, rbk);
    ldswr64(Bs1, srow, scolb, rbv);
    #pragma unroll
    for (int p = 0; p < 2; ++p) {
        ra[p]  = *(const s16x8*)(gA + p * rstep + 128);
        rbk[p] = *(const s16x8*)(gBk + p * rstep + 128);
        rbv[p] = *(const s16x8*)(gBv + p * rstep + 128);
    }
    tile_barrier();

    f32x4 acck[2][2] = {}, accv[2][2] = {};
    int cur = 0;
    for (int t = 0; t < 8; ++t) {
        compute64x2(As + cur * 4096, Bs0 + cur * 4096, Bs1 + cur * 4096,
                    wr, wc, l15, q, acck, accv);
        if (t + 1 < 8) {
            ldswr64(As + (cur ^ 1) * 4096, srow, scolb, ra);
            ldswr64(Bs0 + (cur ^ 1) * 4096, srow, scolb, rbk);
            ldswr64(Bs1 + (cur ^ 1) * 4096, srow, scolb, rbv);
            if (t + 2 < 8) {
                size_t ko = (size_t)(t + 2) * 128;
                #pragma unroll
                for (int p = 0; p < 2; ++p) {
                    ra[p]  = *(const s16x8*)(gA + p * rstep + ko);
                    rbk[p] = *(const s16x8*)(gBk + p * rstep + ko);
                    rbv[p] = *(const s16x8*)(gBv + p * rstep + ko);
                }
            }
            tile_barrier();
        }
        cur ^= 1;
    }

    __syncthreads();                        // all waves done reading As/Bs
    float* Ksf = (float*)smem;              // [64][68]
    float* Vsf = (float*)(smem + 17408);    // [64][68]
    {
        const int lrb = wr * 32 + q * 4;
        const int lcb = wc * 32 + l15;
        #pragma unroll
        for (int n = 0; n < 2; ++n) {
            int lc = lcb + n * 16;
            int c = col0 + lc;
            float bk_ = bk[c], bv_ = bv[c];
            #pragma unroll
            for (int m = 0; m < 2; ++m) {
                #pragma unroll
                for (int rg = 0; rg < 4; ++rg) {
                    int lr = lrb + m * 16 + rg;
                    int r = row0 + lr;
                    float kv = acck[m][n][rg] + bk_;
                    kv = (kv > 0.0f) ? (kv + 1.0f) : expf(kv);
                    float vv = accv[m][n][rg] + bv_;
                    Kb[(size_t)r * DM + c] = kv;
                    Vb[(size_t)r * DM + c] = vv;
                    Ksf[lr * 68 + lc] = kv;
                    Vsf[lr * 68 + lc] = vv;
                }
            }
        }
    }
    __syncthreads();

    const int c = blockIdx.y, h = colb;
    const int di = (tid >> 4) * 4, ei = (tid & 15) * 4;
    f32x4 a0 = {}, a1 = {}, a2 = {}, a3 = {}, ks = {};
    #pragma unroll 8
    for (int t = 0; t < 64; ++t) {
        f32x4 kk = *(const f32x4*)(Ksf + t * 68 + di);
        f32x4 vv = *(const f32x4*)(Vsf + t * 68 + ei);
        fma4(a0, kk.x, vv); fma4(a1, kk.y, vv);
        fma4(a2, kk.z, vv); fma4(a3, kk.w, vv);
        ks += kk;
    }
    float* out = KVC + (size_t)(c * NH + h) * 4096;   // [d][e] row-major
    *(f32x4*)(out + (size_t)(di + 0) * 64 + ei) = a0;
    *(f32x4*)(out + (size_t)(di + 1) * 64 + ei) = a1;
    *(f32x4*)(out + (size_t)(di + 2) * 64 + ei) = a2;
    *(f32x4*)(out + (size_t)(di + 3) * 64 + ei) = a3;
    if ((tid & 15) == 0)
        *(f32x4*)(KSC + (size_t)(c * NH + h) * 64 + di) = ks;
}

// ---------------- attention output per (head, chunk) ----------------
__global__ __launch_bounds__(256) void attn_out_kernel(
    const float* __restrict__ Qb, const float* __restrict__ Kb,
    const float* __restrict__ Vb, const float* __restrict__ KVC,
    const float* __restrict__ KSC, short* __restrict__ Ab)
{
    const int h = blockIdx.x >> 4, c = blockIdx.x & 15;
    const int tid = threadIdx.x;
    __shared__ float Qt[64][68];   // Qt[d][s]  (transposed)
    __shared__ float Kt[64][68];   // Kt[d][t]  (transposed)
    __shared__ float Vs[64][68];   // Vs[t][e]
    __shared__ float Ms[64][68];   // state: Ms[d][e]
    __shared__ float St[64][68];   // St[t][s]  (S transposed)
    __shared__ float KSs[64];

    // inline prefix: Ms = sum_{c'<c} KVC[c',h]
    {
        f32x4 macc[4] = {};
        for (int cp = 0; cp < c; ++cp) {
            const float* src = KVC + (size_t)(cp * NH + h) * 4096;
            #pragma unroll
            for (int it = 0; it < 4; ++it)
                macc[it] += *(const f32x4*)(src + (size_t)(tid + it * 256) * 4);
        }
        #pragma unroll
        for (int it = 0; it < 4; ++it) {
            int j = tid + it * 256;
            *(f32x4*)(&Ms[j >> 4][(j & 15) * 4]) = macc[it];
        }
        if (tid < 64) {
            float s = 0.0f;
            for (int cp = 0; cp < c; ++cp)
                s += KSC[(size_t)(cp * NH + h) * 64 + tid];
            KSs[tid] = s;
        }
    }
    #pragma unroll
    for (int it = 0; it < 4; ++it) {
        int j = tid + it * 256;                 // 0..1023
        int r = j >> 4, d0 = (j & 15) * 4;
        size_t g = (size_t)(c * CHUNK + r) * DM + h * 64 + d0;
        f32x4 q = *(const f32x4*)(Qb + g);
        f32x4 k = *(const f32x4*)(Kb + g);
        f32x4 v = *(const f32x4*)(Vb + g);
        Qt[d0 + 0][r] = q.x; Qt[d0 + 1][r] = q.y; Qt[d0 + 2][r] = q.z; Qt[d0 + 3][r] = q.w;
        Kt[d0 + 0][r] = k.x; Kt[d0 + 1][r] = k.y; Kt[d0 + 2][r] = k.z; Kt[d0 + 3][r] = k.w;
        *(f32x4*)(&Vs[r][d0]) = v;
    }
    __syncthreads();

    const int si = tid >> 4, ti = tid & 15;
    const int s0 = si * 4, t0 = ti * 4;         // t0 doubles as e0

    // ---- Phase A: inter-chunk O = Q @ State, den = Q . KSprefix ----
    f32x4 accO0 = {}, accO1 = {}, accO2 = {}, accO3 = {};
    f32x4 den = {};
    #pragma unroll 8
    for (int d = 0; d < 64; ++d) {
        f32x4 qv = *(const f32x4*)(&Qt[d][s0]);
        f32x4 mv = *(const f32x4*)(&Ms[d][t0]);
        float ks = KSs[d];
        fma4(accO0, qv.x, mv); fma4(accO1, qv.y, mv);
        fma4(accO2, qv.z, mv); fma4(accO3, qv.w, mv);
        fma4(den, ks, qv);
    }

    // ---- Phase B: S = Q K^T, causal, staged transposed ----
    f32x4 p0 = {}, p1 = {}, p2 = {}, p3 = {};   // p_r = S[s0+r][t0:t0+4]
    if (ti <= si) {
        #pragma unroll 8
        for (int d = 0; d < 64; ++d) {
            f32x4 qv = *(const f32x4*)(&Qt[d][s0]);
            f32x4 kv = *(const f32x4*)(&Kt[d][t0]);
            fma4(p0, qv.x, kv); fma4(p1, qv.y, kv);
            fma4(p2, qv.z, kv); fma4(p3, qv.w, kv);
        }
        if (ti == si) {                          // diagonal tile: keep t<=r
            p0.y = 0.0f; p0.z = 0.0f; p0.w = 0.0f;
            p1.z = 0.0f; p1.w = 0.0f;
            p2.w = 0.0f;
        }
    }
    St[t0 + 0][s0 + 0] = p0.x; St[t0 + 1][s0 + 0] = p0.y;
    St[t0 + 2][s0 + 0] = p0.z; St[t0 + 3][s0 + 0] = p0.w;
    St[t0 + 0][s0 + 1] = p1.x; St[t0 + 1][s0 + 1] = p1.y;
    St[t0 + 2][s0 + 1] = p1.z; St[t0 + 3][s0 + 1] = p1.w;
    St[t0 + 0][s0 + 2] = p2.x; St[t0 + 1][s0 + 2] = p2.y;
    St[t0 + 2][s0 + 2] = p2.z; St[t0 + 3][s0 + 2] = p2.w;
    St[t0 + 0][s0 + 3] = p3.x; St[t0 + 1][s0 + 3] = p3.y;
    St[t0 + 2][s0 + 3] = p3.z; St[t0 + 3][s0 + 3] = p3.w;
    __syncthreads();

    // ---- Phase C: O += S @ V ; den += rowsum(S) ----
    const int tmax = s0 + 4;                     // exclusive; St zero above diag
    #pragma unroll 4
    for (int t2 = 0; t2 < tmax; ++t2) {
        f32x4 sv = *(const f32x4*)(&St[t2][s0]);
        f32x4 vv = *(const f32x4*)(&Vs[t2][t0]);
        fma4(accO0, sv.x, vv); fma4(accO1, sv.y, vv);
        fma4(accO2, sv.z, vv); fma4(accO3, sv.w, vv);
        den += sv;
    }

    // ---- epilogue: z = 1/(den+eps), bf16 out ----
    short* op = Ab + (size_t)(c * CHUNK + s0) * DM + h * 64 + t0;
    {
        float z = 1.0f / (den.x + 1e-6f);
        short4 o; o.x = f2bf(accO0.x * z); o.y = f2bf(accO0.y * z);
        o.z = f2bf(accO0.z * z); o.w = f2bf(accO0.w * z);
        *reinterpret_cast<short4*>(op) = o;
    }
    {
        float z = 1.0f / (den.y + 1e-6f);
        short4 o; o.x = f2bf(accO1.x * z); o.y = f2bf(accO1.y * z);
        o.z = f2bf(accO1.z * z); o.w = f2bf(accO1.w * z);
        *reinterpret_cast<short4*>(op + DM) = o;
    }
    {
        float z = 1.0f / (den.z + 1e-6f);
        short4 o; o.x = f2bf(accO2.x * z); o.y = f2bf(accO2.y * z);
        o.z = f2bf(accO2.z * z); o.w = f2bf(accO2.w * z);
        *reinterpret_cast<short4*>(op + 2 * DM) = o;
    }
    {
        float z = 1.0f / (den.w + 1e-6f);
        short4 o; o.x = f2bf(accO3.x * z); o.y = f2bf(accO3.y * z);
        o.z = f2bf(accO3.z * z); o.w = f2bf(accO3.w * z);
        *reinterpret_cast<short4*>(op + 3 * DM) = o;
    }
}

// ---------------- wave-per-row layernorm: LN(X + X2? + resid?) --------------
__global__ __launch_bounds__(64) void ln_kernel64(
    const float* __restrict__ X, const float* __restrict__ X2,
    const float* __restrict__ resid,
    const float* __restrict__ g, const float* __restrict__ b,
    float* __restrict__ O, short* __restrict__ Ob)
{
    const int row = blockIdx.x;
    const size_t base = (size_t)row * DM;
    const int t = threadIdx.x;
    const int i0 = 4 * t, i1 = 256 + 4 * t;
    f32x4 v0 = *(const f32x4*)(X + base + i0);
    f32x4 v1 = *(const f32x4*)(X + base + i1);
    if (X2) {
        v0 += *(const f32x4*)(X2 + base + i0);
        v1 += *(const f32x4*)(X2 + base + i1);
    }
    if (resid) {
        v0 += *(const f32x4*)(resid + base + i0);
        v1 += *(const f32x4*)(resid + base + i1);
    }
    float s = v0.x + v0.y + v0.z + v0.w + v1.x + v1.y + v1.z + v1.w;
    #pragma unroll
    for (int m = 1; m < 64; m <<= 1) s += __shfl_xor(s, m, 64);
    float mean = s * (1.0f / 512.0f);
    f32x4 d0 = v0 - mean, d1 = v1 - mean;
    float ss = d0.x * d0.x + d0.y * d0.y + d0.z * d0.z + d0.w * d0.w
             + d1.x * d1.x + d1.y * d1.y + d1.z * d1.z + d1.w * d1.w;
    #pragma unroll
    for (int m = 1; m < 64; m <<= 1) ss += __shfl_xor(ss, m, 64);
    float var = ss * (1.0f / 512.0f);
    float rs = 1.0f / sqrtf(var + 1e-5f);
    f32x4 g0 = *(const f32x4*)(g + i0), g1v = *(const f32x4*)(g + i1);
    f32x4 b0 = *(const f32x4*)(b + i0), b1v = *(const f32x4*)(b + i1);
    f32x4 o0 = d0 * rs * g0 + b0;
    f32x4 o1 = d1 * rs * g1v + b1v;
    *(f32x4*)(O + base + i0) = o0;
    *(f32x4*)(O + base + i1) = o1;
    if (Ob) {
        short4 s0; s0.x = f2bf(o0.x); s0.y = f2bf(o0.y); s0.z = f2bf(o0.z); s0.w = f2bf(o0.w);
        short4 s1; s1.x = f2bf(o1.x); s1.y = f2bf(o1.y); s1.z = f2bf(o1.z); s1.w = f2bf(o1.w);
        *reinterpret_cast<short4*>(Ob + base + i0) = s0;
        *reinterpret_cast<short4*>(Ob + base + i1) = s1;
    }
}

// ---------------- final LN + emotion head, fused (1024 x 64) ----------------
__global__ __launch_bounds__(64) void ln_final_proj(
    const float* __restrict__ X,
    const float* __restrict__ g, const float* __restrict__ b,
    const float* __restrict__ pw, const float* __restrict__ pb,
    float* __restrict__ Hout, float* __restrict__ Eout)
{
    __shared__ float hrow[512];
    const int row = blockIdx.x;
    const size_t base = (size_t)row * DM;
    const int t = threadIdx.x;
    const int i0 = 4 * t, i1 = 256 + 4 * t;
    f32x4 v0 = *(const f32x4*)(X + base + i0);
    f32x4 v1 = *(const f32x4*)(X + base + i1);
    float s = v0.x + v0.y + v0.z + v0.w + v1.x + v1.y + v1.z + v1.w;
    #pragma unroll
    for (int m = 1; m < 64; m <<= 1) s += __shfl_xor(s, m, 64);
    float mean = s * (1.0f / 512.0f);
    f32x4 d0 = v0 - mean, d1 = v1 - mean;
    float ss = d0.x * d0.x + d0.y * d0.y + d0.z * d0.z + d0.w * d0.w
             + d1.x * d1.x + d1.y * d1.y + d1.z * d1.z + d1.w * d1.w;
    #pragma unroll
    for (int m = 1; m < 64; m <<= 1) ss += __shfl_xor(ss, m, 64);
    float var = ss * (1.0f / 512.0f);
    float rs = 1.0f / sqrtf(var + 1e-5f);
    f32x4 g0 = *(const f32x4*)(g + i0), g1v = *(const f32x4*)(g + i1);
    f32x4 b0 = *(const f32x4*)(b + i0), b1v = *(const f32x4*)(b + i1);
    f32x4 o0 = d0 * rs * g0 + b0;
    f32x4 o1 = d1 * rs * g1v + b1v;
    *(f32x4*)(Hout + base + i0) = o0;
    *(f32x4*)(Hout + base + i1) = o1;
    *(f32x4*)(&hrow[i0]) = o0;
    *(f32x4*)(&hrow[i1]) = o1;
    __syncthreads();

    const int e = t & 7, seg = t >> 3;
    float acc = 0.0f;
    #pragma unroll 16
    for (int d = seg * 64; d < seg * 64 + 64; ++d)
        acc = fmaf(hrow[d], pw[d * 8 + e], acc);
    acc += __shfl_xor(acc, 8, 64);
    acc += __shfl_xor(acc, 16, 64);
    acc += __shfl_xor(acc, 32, 64);
    if (t < 8) Eout[(size_t)row * 8 + t] = acc + pb[t];
}

// ---------------------------------------------------------------------------
extern "C" void kernel_launch(void* const* d_in, const int* in_sizes, int n_in,
                              void* d_out, int out_size, void* d_ws, size_t ws_size,
                              hipStream_t stream)
{
    const int*   x    = (const int*)d_in[0];
    const float* e0   = (const float*)d_in[1];
    const float* e1   = (const float*)d_in[2];
    const float* e2   = (const float*)d_in[3];
    const float* e3   = (const float*)d_in[4];
    const float* e4   = (const float*)d_in[5];
    const float* e5   = (const float*)d_in[6];
    const float* in_w = (const float*)d_in[7];
    const float* in_b = (const float*)d_in[8];
    const float* wq   = (const float*)d_in[9];
    const float* bq   = (const float*)d_in[10];
    const float* wk   = (const float*)d_in[11];
    const float* bk   = (const float*)d_in[12];
    const float* wv   = (const float*)d_in[13];
    const float* bv   = (const float*)d_in[14];
    const float* wo   = (const float*)d_in[15];
    const float* bo   = (const float*)d_in[16];
    const float* g1   = (const float*)d_in[17];
    const float* be1  = (const float*)d_in[18];
    const float* w1   = (const float*)d_in[19];
    const float* b1   = (const float*)d_in[20];
    const float* w2   = (const float*)d_in[21];
    const float* b2   = (const float*)d_in[22];
    const float* g2   = (const float*)d_in[23];
    const float* be2  = (const float*)d_in[24];
    const float* gf   = (const float*)d_in[25];
    const float* bfin = (const float*)d_in[26];
    const float* pw   = (const float*)d_in[27];
    const float* pb   = (const float*)d_in[28];
    float* outp = (float*)d_out;

    // ---- workspace layout: Y,Y2 contiguous partial arena ----
    float* ws = (float*)d_ws;
    float* H    = ws;                  // 1024x512 f32
    float* Y    = ws + 524288;         // partial 0 (and pre-LN sum input)
    float* Y2   = ws + 1048576;        // partial 1 (contiguous with Y)
    float* Qb   = ws + 1572864;
    float* Kb   = ws + 2097152;
    float* Vb   = ws + 2621440;
    float* KVC  = ws + 3145728;        // 16*8*4096 = 524288
    float* KSC  = ws + 3670016;        // 8192 (ends 3678208)
    short* sb   = (short*)(ws + 3678208);
    short* Hb   = sb;                  // 1024x512
    short* Ab   = sb + 524288;         // 1024x512
    short* FFb  = sb + 1048576;        // 1024x2048
    short* EMBb = FFb;                 // 1024x768 (alias: dead before ffn1)
    // bf16 W^T arena [N][K]
    short* inT  = sb + 3145728;        // [512][768]
    short* qT   = inT + 393216;        // [12][512][512]
    short* kT   = qT + 3145728;
    short* vT   = kT + 3145728;
    short* oT   = vT + 3145728;
    short* w1T  = oT + 3145728;        // [12][2048][512]
    short* w2T  = w1T + 12582912;      // [12][512][2048]

    const dim3 blk256(256), blk64(64), blk512(512);

    // ---- weight transpose+convert ----
    transpose_w<<<dim3(8, 12, 1),  blk256, 0, stream>>>(in_w, inT, 768, DM);
    transpose4_w<<<dim3(8, 8, 48), blk256, 0, stream>>>(wq, wk, wv, wo,
                                                        qT, kT, vT, oT);
    transpose_w<<<dim3(32, 8, 12), blk256, 0, stream>>>(w1, w1T, DM, DFF);
    transpose_w<<<dim3(8, 32, 12), blk256, 0, stream>>>(w2, w2T, DFF, DM);

    embed_kernel<<<S_LEN, blk256, 0, stream>>>(x, e0, e1, e2, e3, e4, e5, EMBb);
    // in-proj: EMBb @ in_w + in_b + PE -> H (f32) and Hb (bf16)
    gemm64x8<<<dim3(8, 16, 1), blk512, 0, stream>>>(EMBb, inT, in_b, nullptr,
                                                    H, Hb, DM, 768, ACT_NONE, 1, 1);

    for (int l = 0; l < NLAYER; ++l) {
        const short* qT_l = qT + (size_t)l * DM * DM;
        const short* kT_l = kT + (size_t)l * DM * DM;
        const short* vT_l = vT + (size_t)l * DM * DM;
        const short* oT_l = oT + (size_t)l * DM * DM;
        const short* w1T_l = w1T + (size_t)l * DM * DFF;
        const short* w2T_l = w2T + (size_t)l * DM * DFF;
        const float* bq_l = bq + l * DM;  const float* bk_l = bk + l * DM;
        const float* bv_l = bv + l * DM;  const float* bo_l = bo + l * DM;
        const float* b1_l = b1 + l * DFF; const float* b2_l = b2 + l * DM;

        // fused QKV + chunk stats (one dispatch, 256 blocks)
        qkv_fused<<<dim3(16, 16), blk256, 0, stream>>>(Hb, qT_l, kT_l, vT_l,
                                                       bq_l, bk_l, bv_l,
                                                       Qb, Kb, Vb, KVC, KSC);

        attn_out_kernel<<<NCH * NH, blk256, 0, stream>>>(Qb, Kb, Vb, KVC, KSC, Ab);

        // wo split-K z=2: partials Y (z0,+bias), Y2 (z1); LN(Y+Y2+H)
        gemm64x8<<<dim3(8, 16, 2), blk512, 0, stream>>>(Ab, oT_l, bo_l, nullptr,
                                                        Y, nullptr, DM, DM, ACT_NONE, 0, 2);
        ln_kernel64<<<S_LEN, blk64, 0, stream>>>(Y, Y2, H,
                                                 g1 + l * DM, be1 + l * DM, H, Hb);

        // ffn1: Hb @ w1 + b1, GELU -> FFb (bf16)
        gemm64x8<<<dim3(32, 16, 1), blk512, 0, stream>>>(Hb, w1T_l, b1_l, nullptr,
                                                         nullptr, FFb, DFF, DM, ACT_GELU, 0, 1);
        // ffn2 split-K z=2: partials Y (z0,+bias), Y2 (z1); LN(Y+Y2+H)
        gemm64x8<<<dim3(8, 16, 2), blk512, 0, stream>>>(FFb, w2T_l, b2_l, nullptr,
                                                        Y, nullptr, DM, DFF, ACT_NONE, 0, 2);
        ln_kernel64<<<S_LEN, blk64, 0, stream>>>(Y, Y2, H,
                                                 g2 + l * DM, be2 + l * DM, H, Hb);
    }

    // final norm + emotion head (fused)
    ln_final_proj<<<S_LEN, blk64, 0, stream>>>(H, gf, bfin, pw, pb,
                                               outp, outp + 524288);
}